// Round 1
// baseline (2872.300 us; speedup 1.0000x reference)
//
#include <hip/hip_runtime.h>
#include <cstdint>
#include <cstddef>

// ---------------- problem constants ----------------
#define NNODE      30000
#define FIN        512
#define H1DIM      1024
#define H2DIM      512
#define H3DIM      256
#define HDIM       512          // mu/logvar width
#define HALF_ROWS  15000
#define HALF_ELEMS 7680000u     // 15000*512 (threefry pair offset)
#define POOL_BLOCKS 118         // ceil(15000/128)

// ---------------- threefry2x32 (JAX-exact) ----------------
__device__ __forceinline__ void threefry2x32(uint32_t k0, uint32_t k1,
                                             uint32_t& x0, uint32_t& x1) {
    uint32_t ks0 = k0, ks1 = k1, ks2 = k0 ^ k1 ^ 0x1BD11BDAu;
    const uint32_t R0[4] = {13u, 15u, 26u, 6u};
    const uint32_t R1[4] = {17u, 29u, 16u, 24u};
    x0 += ks0; x1 += ks1;
#pragma unroll
    for (int g = 0; g < 5; ++g) {
        const uint32_t* R = (g & 1) ? R1 : R0;
#pragma unroll
        for (int r = 0; r < 4; ++r) {
            x0 += x1;
            x1 = (x1 << R[r]) | (x1 >> (32u - R[r]));
            x1 ^= x0;
        }
        uint32_t ks_a = (g % 3 == 0) ? ks1 : (g % 3 == 1 ? ks2 : ks0);   // ks[(g+1)%3]
        uint32_t ks_b = (g % 3 == 0) ? ks2 : (g % 3 == 1 ? ks0 : ks1);   // ks[(g+2)%3]
        x0 += ks_a;
        x1 += ks_b + (uint32_t)(g + 1);
    }
}

// JAX normal from one random word: u ~ U[nextafter(-1,0), 1), n = sqrt(2)*erfinv(u)
__device__ __forceinline__ float jax_normal(uint32_t bits) {
    uint32_t fb = (bits >> 9) | 0x3F800000u;
    float f = __uint_as_float(fb) - 1.0f;        // [0,1)
    const float lo = -0.99999994f;               // nextafter(-1,0)
    float u = fmaf(f, 2.0f, lo);                 // (1 - lo) rounds to 2.0f in fp32
    u = fmaxf(u, lo);
    return 1.41421356237f * erfinvf(u);
}

// ---------------- degree / dinv ----------------
__global__ void deg_kernel(const int* __restrict__ row, const float* __restrict__ w,
                           float* __restrict__ deg, int E) {
    int e = blockIdx.x * 256 + threadIdx.x;
    if (e < E) atomicAdd(&deg[row[e]], w[e]);
}

__global__ void dinv_kernel(const float* __restrict__ deg, float* __restrict__ dinv, int n) {
    int i = blockIdx.x * 256 + threadIdx.x;
    if (i < n) dinv[i] = rsqrtf(deg[i] + 1.0f);  // +1 self loop; always > 0
}

// ---------------- SpMM: self-loop init then atomic edge accumulation ----------------
// agg[r][f] = dinv[r]^2 * h[r][f]
__global__ void spmm_self(const float* __restrict__ h, const float* __restrict__ dinv,
                          float* __restrict__ agg, int logF, size_t total) {
    size_t i = (size_t)blockIdx.x * 256 + threadIdx.x;
    if (i < total) {
        int r = (int)(i >> logF);
        float d = dinv[r];
        agg[i] = d * d * h[i];
    }
}

// agg[row[e]][f] += dinv[row]*w*dinv[col] * h[col[e]][f]
__global__ void spmm_edges(const int* __restrict__ row, const int* __restrict__ col,
                           const float* __restrict__ w, const float* __restrict__ dinv,
                           const float* __restrict__ h, float* __restrict__ agg, int F) {
    int e = blockIdx.x;
    int r = row[e], c = col[e];
    float nw = dinv[r] * w[e] * dinv[c];
    const float* hrow = h + (size_t)c * F;
    float* arow = agg + (size_t)r * F;
    for (int f = threadIdx.x; f < F; f += blockDim.x)
        atomicAdd(&arow[f], nw * hrow[f]);
}

// ---------------- fused (optional bias) + L2 norm + ReLU, in place ----------------
__global__ __launch_bounds__(256) void bias_l2norm_relu(float* __restrict__ y,
                                                        const float* __restrict__ bias, int F) {
    int r = blockIdx.x;
    size_t base = (size_t)r * F;
    int cnt = F >> 8;                 // F in {256,512,1024} -> 1,2,4
    float v[4];
    float ss = 0.f;
#pragma unroll 4
    for (int u = 0; u < 4; ++u) {
        if (u < cnt) {
            int f = u * 256 + threadIdx.x;
            float t = y[base + f] + (bias ? bias[f] : 0.f);
            v[u] = t;
            ss += t * t;
        }
    }
#pragma unroll
    for (int o = 32; o; o >>= 1) ss += __shfl_xor(ss, o);
    __shared__ float red[4];
    int lane = threadIdx.x & 63, wid = threadIdx.x >> 6;
    if (lane == 0) red[wid] = ss;
    __syncthreads();
    if (threadIdx.x == 0) {
        float t = red[0] + red[1] + red[2] + red[3];
        red[0] = 1.0f / fmaxf(sqrtf(t), 1e-12f);
    }
    __syncthreads();
    float rinv = red[0];
#pragma unroll 4
    for (int u = 0; u < 4; ++u) {
        if (u < cnt) {
            int f = u * 256 + threadIdx.x;
            y[base + f] = fmaxf(v[u] * rinv, 0.f);
        }
    }
}

// ---------------- fp32 tiled GEMM: C = A[MxK] * B[KxN] (+bias) ----------------
template <bool ADD_BIAS>
__global__ __launch_bounds__(256) void sgemm64(const float* __restrict__ A,
                                               const float* __restrict__ B,
                                               const float* __restrict__ bias,
                                               float* __restrict__ C,
                                               int M, int N, int K) {
    __shared__ float As[16][65];
    __shared__ float Bs[16][64];
    int bm0 = blockIdx.y * 64;
    int bn0 = blockIdx.x * 64;
    int tid = threadIdx.x;
    int ar = tid >> 2;            // 0..63
    int ak = (tid & 3) << 2;      // 0,4,8,12
    int bk = tid >> 4;            // 0..15
    int bc = (tid & 15) << 2;     // 0..60
    int tx = tid & 15, ty = tid >> 4;
    float acc[4][4] = {{0.f}};
    for (int k0 = 0; k0 < K; k0 += 16) {
        int am = bm0 + ar;
        float4 av;
        if (am < M) av = *(const float4*)&A[(size_t)am * K + k0 + ak];
        else        av = make_float4(0.f, 0.f, 0.f, 0.f);
        As[ak + 0][ar] = av.x; As[ak + 1][ar] = av.y;
        As[ak + 2][ar] = av.z; As[ak + 3][ar] = av.w;
        *(float4*)&Bs[bk][bc] = *(const float4*)&B[(size_t)(k0 + bk) * N + bn0 + bc];
        __syncthreads();
#pragma unroll
        for (int k = 0; k < 16; ++k) {
            float a0 = As[k][ty * 4 + 0], a1 = As[k][ty * 4 + 1];
            float a2 = As[k][ty * 4 + 2], a3 = As[k][ty * 4 + 3];
            float b0 = Bs[k][tx * 4 + 0], b1 = Bs[k][tx * 4 + 1];
            float b2 = Bs[k][tx * 4 + 2], b3 = Bs[k][tx * 4 + 3];
            acc[0][0] = fmaf(a0, b0, acc[0][0]); acc[0][1] = fmaf(a0, b1, acc[0][1]);
            acc[0][2] = fmaf(a0, b2, acc[0][2]); acc[0][3] = fmaf(a0, b3, acc[0][3]);
            acc[1][0] = fmaf(a1, b0, acc[1][0]); acc[1][1] = fmaf(a1, b1, acc[1][1]);
            acc[1][2] = fmaf(a1, b2, acc[1][2]); acc[1][3] = fmaf(a1, b3, acc[1][3]);
            acc[2][0] = fmaf(a2, b0, acc[2][0]); acc[2][1] = fmaf(a2, b1, acc[2][1]);
            acc[2][2] = fmaf(a2, b2, acc[2][2]); acc[2][3] = fmaf(a2, b3, acc[2][3]);
            acc[3][0] = fmaf(a3, b0, acc[3][0]); acc[3][1] = fmaf(a3, b1, acc[3][1]);
            acc[3][2] = fmaf(a3, b2, acc[3][2]); acc[3][3] = fmaf(a3, b3, acc[3][3]);
        }
        __syncthreads();
    }
#pragma unroll
    for (int i = 0; i < 4; ++i) {
        int m = bm0 + ty * 4 + i;
        if (m < M) {
#pragma unroll
            for (int j = 0; j < 4; ++j) {
                int n = bn0 + tx * 4 + j;
                float o = acc[i][j];
                if (ADD_BIAS) o += bias[n];
                C[(size_t)m * N + n] = o;
            }
        }
    }
}

// ---------------- pooling: z = mu + 0.01*g*exp(0.5*beta*lv); partial max/sum ----------------
__global__ __launch_bounds__(256) void pool_partial(const float* __restrict__ mu,
                                                    const float* __restrict__ lv,
                                                    const uint32_t* __restrict__ beta_p,
                                                    float* __restrict__ pmax,
                                                    float* __restrict__ psum) {
    uint32_t bb = beta_p[0];
    float beta = (bb & 0x7F800000u) ? __uint_as_float(bb) : (float)(int)bb;
    int b = blockIdx.x;
    int r0 = b * 128;
    int r1 = min(r0 + 128, HALF_ROWS);
    int c = threadIdx.x * 2;
    float m0 = -INFINITY, m1 = -INFINITY, s0 = 0.f, s1 = 0.f;
    for (int r = r0; r < r1; ++r) {
#pragma unroll
        for (int q = 0; q < 2; ++q) {
            int cc = c + q;
            uint32_t idx = (uint32_t)r * 512u + (uint32_t)cc;
            uint32_t x0 = idx, x1 = idx + HALF_ELEMS;
            threefry2x32(0u, 42u, x0, x1);
            size_t ia = (size_t)r * HDIM + cc;
            size_t ib = (size_t)(r + HALF_ROWS) * HDIM + cc;
            float za = mu[ia] + 0.01f * jax_normal(x0) * __expf(0.5f * beta * lv[ia]);
            float zb = mu[ib] + 0.01f * jax_normal(x1) * __expf(0.5f * beta * lv[ib]);
            float mx = fmaxf(za, zb);
            float sm = za + zb;
            if (q == 0) { m0 = fmaxf(m0, mx); s0 += sm; }
            else        { m1 = fmaxf(m1, mx); s1 += sm; }
        }
    }
    pmax[(size_t)b * HDIM + c]     = m0;
    pmax[(size_t)b * HDIM + c + 1] = m1;
    psum[(size_t)b * HDIM + c]     = s0;
    psum[(size_t)b * HDIM + c + 1] = s1;
}

__global__ void pool_final(const float* __restrict__ pmax, const float* __restrict__ psum,
                           float* __restrict__ pooled) {
    int c = blockIdx.x * 256 + threadIdx.x;
    if (c < HDIM) {
        float m = -INFINITY, s = 0.f;
        for (int b = 0; b < POOL_BLOCKS; ++b) {
            m = fmaxf(m, pmax[(size_t)b * HDIM + c]);
            s += psum[(size_t)b * HDIM + c];
        }
        pooled[c] = m;
        pooled[HDIM + c] = s / 30000.0f;
    }
}

// ---------------- decoder dense 1024x1024 ----------------
__global__ __launch_bounds__(256) void dense1024(const float* __restrict__ in,
                                                 const float* __restrict__ W,
                                                 const float* __restrict__ bias,
                                                 float* __restrict__ out, int act) {
    __shared__ float sin_[1024];
    for (int i = threadIdx.x; i < 1024; i += 256) sin_[i] = in[i];
    __syncthreads();
    int j = blockIdx.x * 256 + threadIdx.x;
    float acc = bias[j];
    for (int i = 0; i < 1024; ++i) acc = fmaf(sin_[i], W[i * 1024 + j], acc);
    out[j] = act ? (1.0f / (1.0f + __expf(-acc))) : fmaxf(acc, 0.f);
}

// ---------------- launch ----------------
extern "C" void kernel_launch(void* const* d_in, const int* in_sizes, int n_in,
                              void* d_out, int out_size, void* d_ws, size_t ws_size,
                              hipStream_t stream) {
    const float* x   = (const float*)d_in[0];
    const int*   ei  = (const int*)d_in[1];
    const float* ew  = (const float*)d_in[2];
    const uint32_t* beta = (const uint32_t*)d_in[3];
    const float* W1  = (const float*)d_in[4];
    const float* b1  = (const float*)d_in[5];
    const float* W2  = (const float*)d_in[6];
    const float* b2  = (const float*)d_in[7];
    const float* W3  = (const float*)d_in[8];
    const float* b3  = (const float*)d_in[9];
    const float* Wmu = (const float*)d_in[10];
    const float* bmu = (const float*)d_in[11];
    const float* Wlv = (const float*)d_in[12];
    const float* blv = (const float*)d_in[13];
    const float* Wd1 = (const float*)d_in[14];
    const float* bd1 = (const float*)d_in[15];
    const float* Wd2 = (const float*)d_in[16];
    const float* bd2 = (const float*)d_in[17];

    const int E = in_sizes[2];            // 300000
    const int M = NNODE;                  // 30000

    float* out    = (float*)d_out;
    float* mu_out = out + 1024;                           // [30000,512]
    float* lv_out = out + 1024 + (size_t)M * HDIM;        // [30000,512]

    // workspace layout (floats)
    float* ws = (float*)d_ws;
    float* AX    = ws;                                    // 15,360,000 (reused: AX, h2, h3+agg3)
    float* BIG   = ws + (size_t)15360000;                 // 30,720,000 (h1/out1)
    float* deg   = ws + (size_t)46080000;                 // 30,000
    float* dinv  = ws + (size_t)46110000;                 // 30,000
    float* pmax  = ws + (size_t)46140000;                 // 118*512
    float* psum  = ws + (size_t)46200416;                 // 118*512
    float* pooled= ws + (size_t)46260832;                 // 1024
    float* hdec  = ws + (size_t)46261856;                 // 1024

    const int* row = ei;
    const int* col = ei + E;

    // 1) degrees and D^-1/2
    hipMemsetAsync(deg, 0, (size_t)M * sizeof(float), stream);
    deg_kernel<<<(E + 255) / 256, 256, 0, stream>>>(row, ew, deg, E);
    dinv_kernel<<<(M + 255) / 256, 256, 0, stream>>>(deg, dinv, M);

    // 2) layer 1: AX = A_hat @ X   (F=512), then h1 = AX@W1 + b1, normrelu
    {
        size_t total = (size_t)M * FIN;
        spmm_self<<<(int)((total + 255) / 256), 256, 0, stream>>>(x, dinv, AX, 9, total);
        spmm_edges<<<E, 256, 0, stream>>>(row, col, ew, dinv, x, AX, FIN);
        dim3 g(H1DIM / 64, (M + 63) / 64);
        sgemm64<true><<<g, 256, 0, stream>>>(AX, W1, b1, BIG, M, H1DIM, FIN);
        bias_l2norm_relu<<<M, 256, 0, stream>>>(BIG, nullptr, H1DIM);
    }

    // 3) layer 2: h2 = out1@W2 (-> AX region), agg2 = A_hat@h2 (-> mu region), normrelu(+b2)
    {
        float* h2   = AX;
        float* agg2 = mu_out;     // scratch until final mu written
        dim3 g(H2DIM / 64, (M + 63) / 64);
        sgemm64<false><<<g, 256, 0, stream>>>(BIG, W2, nullptr, h2, M, H2DIM, H1DIM);
        size_t total = (size_t)M * H2DIM;
        spmm_self<<<(int)((total + 255) / 256), 256, 0, stream>>>(h2, dinv, agg2, 9, total);
        spmm_edges<<<E, 256, 0, stream>>>(row, col, ew, dinv, h2, agg2, H2DIM);
        bias_l2norm_relu<<<M, 256, 0, stream>>>(agg2, b2, H2DIM);
    }

    // 4) layer 3: h3 = out2@W3 (-> AX), agg3 (-> AX+7.68M), normrelu(+b3)
    float* out3;
    {
        const float* out2 = mu_out;
        float* h3   = AX;
        float* agg3 = AX + (size_t)7680000;
        dim3 g(H3DIM / 64, (M + 63) / 64);
        sgemm64<false><<<g, 256, 0, stream>>>(out2, W3, nullptr, h3, M, H3DIM, H2DIM);
        size_t total = (size_t)M * H3DIM;
        spmm_self<<<(int)((total + 255) / 256), 256, 0, stream>>>(h3, dinv, agg3, 8, total);
        spmm_edges<<<E, 256, 0, stream>>>(row, col, ew, dinv, h3, agg3, H3DIM);
        bias_l2norm_relu<<<M, 256, 0, stream>>>(agg3, b3, H3DIM);
        out3 = agg3;
    }

    // 5) mu / logvar
    {
        dim3 g(HDIM / 64, (M + 63) / 64);
        sgemm64<true><<<g, 256, 0, stream>>>(out3, Wmu, bmu, mu_out, M, HDIM, H3DIM);
        sgemm64<true><<<g, 256, 0, stream>>>(out3, Wlv, blv, lv_out, M, HDIM, H3DIM);
    }

    // 6) pooling with JAX-exact reparameterization noise
    pool_partial<<<POOL_BLOCKS, 256, 0, stream>>>(mu_out, lv_out, beta, pmax, psum);
    pool_final<<<2, 256, 0, stream>>>(pmax, psum, pooled);

    // 7) decoder
    dense1024<<<4, 256, 0, stream>>>(pooled, Wd1, bd1, hdec, 0);
    dense1024<<<4, 256, 0, stream>>>(hdec, Wd2, bd2, out, 1);
}

// Round 2
// 1890.446 us; speedup vs baseline: 1.5194x; 1.5194x over previous
//
#include <hip/hip_runtime.h>
#include <cstdint>
#include <cstddef>

// ---------------- problem constants ----------------
#define NNODE      30000
#define FIN        512
#define H1DIM      1024
#define H2DIM      512
#define H3DIM      256
#define HDIM       512          // mu/logvar width
#define HALF_ROWS  15000
#define HALF_ELEMS 7680000u     // 15000*512 (threefry pair offset)
#define POOL_BLOCKS 118         // ceil(15000/128)

// ---------------- threefry2x32 (JAX-exact) ----------------
__device__ __forceinline__ void threefry2x32(uint32_t k0, uint32_t k1,
                                             uint32_t& x0, uint32_t& x1) {
    uint32_t ks0 = k0, ks1 = k1, ks2 = k0 ^ k1 ^ 0x1BD11BDAu;
    const uint32_t R0[4] = {13u, 15u, 26u, 6u};
    const uint32_t R1[4] = {17u, 29u, 16u, 24u};
    x0 += ks0; x1 += ks1;
#pragma unroll
    for (int g = 0; g < 5; ++g) {
        const uint32_t* R = (g & 1) ? R1 : R0;
#pragma unroll
        for (int r = 0; r < 4; ++r) {
            x0 += x1;
            x1 = (x1 << R[r]) | (x1 >> (32u - R[r]));
            x1 ^= x0;
        }
        uint32_t ks_a = (g % 3 == 0) ? ks1 : (g % 3 == 1 ? ks2 : ks0);   // ks[(g+1)%3]
        uint32_t ks_b = (g % 3 == 0) ? ks2 : (g % 3 == 1 ? ks0 : ks1);   // ks[(g+2)%3]
        x0 += ks_a;
        x1 += ks_b + (uint32_t)(g + 1);
    }
}

// JAX normal from one random word: u ~ U[nextafter(-1,0), 1), n = sqrt(2)*erfinv(u)
__device__ __forceinline__ float jax_normal(uint32_t bits) {
    uint32_t fb = (bits >> 9) | 0x3F800000u;
    float f = __uint_as_float(fb) - 1.0f;        // [0,1)
    const float lo = -0.99999994f;               // nextafter(-1,0)
    float u = fmaf(f, 2.0f, lo);                 // (1 - lo) rounds to 2.0f in fp32
    u = fmaxf(u, lo);
    return 1.41421356237f * erfinvf(u);
}

// ---------------- degree + count ----------------
__global__ void deg_cnt_kernel(const int* __restrict__ row, const float* __restrict__ w,
                               float* __restrict__ deg, int* __restrict__ cnt, int E) {
    int e = blockIdx.x * 256 + threadIdx.x;
    if (e < E) {
        int r = row[e];
        atomicAdd(&deg[r], w[e]);
        atomicAdd(&cnt[r], 1);
    }
}

__global__ void dinv_kernel(const float* __restrict__ deg, float* __restrict__ dinv, int n) {
    int i = blockIdx.x * 256 + threadIdx.x;
    if (i < n) dinv[i] = rsqrtf(deg[i] + 1.0f);  // +1 self loop; always > 0
}

// ---------------- single-block exclusive scan of 30000 counts -> rowptr ----------------
__global__ __launch_bounds__(256) void build_rowptr(const int* __restrict__ cnt,
                                                    int* __restrict__ rowptr) {
    __shared__ int sums[256];
    const int ROWS_PT = 118;                 // 256*118 = 30208 >= 30000
    int t = threadIdx.x;
    int base = t * ROWS_PT;
    int local = 0;
    for (int i = 0; i < ROWS_PT; ++i) {
        int r = base + i;
        if (r < NNODE) local += cnt[r];
    }
    sums[t] = local;
    __syncthreads();
    for (int o = 1; o < 256; o <<= 1) {
        int v = (t >= o) ? sums[t - o] : 0;
        __syncthreads();
        sums[t] += v;
        __syncthreads();
    }
    int off = (t == 0) ? 0 : sums[t - 1];
    for (int i = 0; i < ROWS_PT; ++i) {
        int r = base + i;
        if (r < NNODE) { rowptr[r] = off; off += cnt[r]; }
    }
    if (t == 255) rowptr[NNODE] = off;       // == E
}

// ---------------- scatter edges into CSR with pre-normalized weights ----------------
__global__ void scatter_edges(const int* __restrict__ row, const int* __restrict__ col,
                              const float* __restrict__ w, const float* __restrict__ dinv,
                              const int* __restrict__ rowptr, int* __restrict__ fill,
                              int* __restrict__ ecol, float* __restrict__ eval, int E) {
    int e = blockIdx.x * 256 + threadIdx.x;
    if (e < E) {
        int r = row[e], c = col[e];
        int pos = rowptr[r] + atomicAdd(&fill[r], 1);
        ecol[pos] = c;
        eval[pos] = dinv[r] * w[e] * dinv[c];
    }
}

// ---------------- CSR SpMM, wave-per-row, optional fused bias+L2norm+ReLU ----------------
template <int F, bool FUSE>
__global__ __launch_bounds__(256) void spmm_csr(const int* __restrict__ rowptr,
                                                const int* __restrict__ ecol,
                                                const float* __restrict__ eval,
                                                const float* __restrict__ dinv,
                                                const float* __restrict__ h,
                                                const float* __restrict__ bias,
                                                float* __restrict__ out) {
    constexpr int NV = F / 256;              // float4s per lane: 512->2, 256->1
    int lane = threadIdx.x & 63;
    int r = blockIdx.x * 4 + (threadIdx.x >> 6);
    if (r >= NNODE) return;
    float d = dinv[r];
    float dd = d * d;
    const float4* hr = (const float4*)(h + (size_t)r * F);
    float4 acc[NV];
#pragma unroll
    for (int v = 0; v < NV; ++v) {
        float4 t = hr[v * 64 + lane];
        acc[v] = make_float4(dd * t.x, dd * t.y, dd * t.z, dd * t.w);
    }
    int e0 = rowptr[r], e1 = rowptr[r + 1];
    for (int e = e0; e < e1; ++e) {
        int c = ecol[e];
        float nw = eval[e];
        const float4* hc = (const float4*)(h + (size_t)c * F);
#pragma unroll
        for (int v = 0; v < NV; ++v) {
            float4 t = hc[v * 64 + lane];
            acc[v].x = fmaf(nw, t.x, acc[v].x);
            acc[v].y = fmaf(nw, t.y, acc[v].y);
            acc[v].z = fmaf(nw, t.z, acc[v].z);
            acc[v].w = fmaf(nw, t.w, acc[v].w);
        }
    }
    float4* orow = (float4*)(out + (size_t)r * F);
    if (FUSE) {
        const float4* bv = (const float4*)bias;
        float ss = 0.f;
#pragma unroll
        for (int v = 0; v < NV; ++v) {
            float4 b = bv[v * 64 + lane];
            acc[v].x += b.x; acc[v].y += b.y; acc[v].z += b.z; acc[v].w += b.w;
            ss += acc[v].x * acc[v].x + acc[v].y * acc[v].y
                + acc[v].z * acc[v].z + acc[v].w * acc[v].w;
        }
#pragma unroll
        for (int o = 32; o; o >>= 1) ss += __shfl_xor(ss, o);
        float rinv = 1.0f / fmaxf(sqrtf(ss), 1e-12f);
#pragma unroll
        for (int v = 0; v < NV; ++v) {
            orow[v * 64 + lane] = make_float4(fmaxf(acc[v].x * rinv, 0.f),
                                              fmaxf(acc[v].y * rinv, 0.f),
                                              fmaxf(acc[v].z * rinv, 0.f),
                                              fmaxf(acc[v].w * rinv, 0.f));
        }
    } else {
#pragma unroll
        for (int v = 0; v < NV; ++v) orow[v * 64 + lane] = acc[v];
    }
}

// ---------------- fused (optional bias) + L2 norm + ReLU, in place (layer 1 only) ----------------
__global__ __launch_bounds__(256) void bias_l2norm_relu(float* __restrict__ y,
                                                        const float* __restrict__ bias, int F) {
    int r = blockIdx.x;
    size_t base = (size_t)r * F;
    int cnt = F >> 8;
    float v[4];
    float ss = 0.f;
#pragma unroll 4
    for (int u = 0; u < 4; ++u) {
        if (u < cnt) {
            int f = u * 256 + threadIdx.x;
            float t = y[base + f] + (bias ? bias[f] : 0.f);
            v[u] = t;
            ss += t * t;
        }
    }
#pragma unroll
    for (int o = 32; o; o >>= 1) ss += __shfl_xor(ss, o);
    __shared__ float red[4];
    int lane = threadIdx.x & 63, wid = threadIdx.x >> 6;
    if (lane == 0) red[wid] = ss;
    __syncthreads();
    if (threadIdx.x == 0) {
        float t = red[0] + red[1] + red[2] + red[3];
        red[0] = 1.0f / fmaxf(sqrtf(t), 1e-12f);
    }
    __syncthreads();
    float rinv = red[0];
#pragma unroll 4
    for (int u = 0; u < 4; ++u) {
        if (u < cnt) {
            int f = u * 256 + threadIdx.x;
            y[base + f] = fmaxf(v[u] * rinv, 0.f);
        }
    }
}

// ---------------- fp32 tiled GEMM: C = A[MxK] * B[KxN] (+bias) ----------------
template <bool ADD_BIAS>
__global__ __launch_bounds__(256) void sgemm64(const float* __restrict__ A,
                                               const float* __restrict__ B,
                                               const float* __restrict__ bias,
                                               float* __restrict__ C,
                                               int M, int N, int K) {
    __shared__ float As[16][65];
    __shared__ float Bs[16][64];
    int bm0 = blockIdx.y * 64;
    int bn0 = blockIdx.x * 64;
    int tid = threadIdx.x;
    int ar = tid >> 2;            // 0..63
    int ak = (tid & 3) << 2;      // 0,4,8,12
    int bk = tid >> 4;            // 0..15
    int bc = (tid & 15) << 2;     // 0..60
    int tx = tid & 15, ty = tid >> 4;
    float acc[4][4] = {{0.f}};
    for (int k0 = 0; k0 < K; k0 += 16) {
        int am = bm0 + ar;
        float4 av;
        if (am < M) av = *(const float4*)&A[(size_t)am * K + k0 + ak];
        else        av = make_float4(0.f, 0.f, 0.f, 0.f);
        As[ak + 0][ar] = av.x; As[ak + 1][ar] = av.y;
        As[ak + 2][ar] = av.z; As[ak + 3][ar] = av.w;
        *(float4*)&Bs[bk][bc] = *(const float4*)&B[(size_t)(k0 + bk) * N + bn0 + bc];
        __syncthreads();
#pragma unroll
        for (int k = 0; k < 16; ++k) {
            float a0 = As[k][ty * 4 + 0], a1 = As[k][ty * 4 + 1];
            float a2 = As[k][ty * 4 + 2], a3 = As[k][ty * 4 + 3];
            float b0 = Bs[k][tx * 4 + 0], b1 = Bs[k][tx * 4 + 1];
            float b2 = Bs[k][tx * 4 + 2], b3 = Bs[k][tx * 4 + 3];
            acc[0][0] = fmaf(a0, b0, acc[0][0]); acc[0][1] = fmaf(a0, b1, acc[0][1]);
            acc[0][2] = fmaf(a0, b2, acc[0][2]); acc[0][3] = fmaf(a0, b3, acc[0][3]);
            acc[1][0] = fmaf(a1, b0, acc[1][0]); acc[1][1] = fmaf(a1, b1, acc[1][1]);
            acc[1][2] = fmaf(a1, b2, acc[1][2]); acc[1][3] = fmaf(a1, b3, acc[1][3]);
            acc[2][0] = fmaf(a2, b0, acc[2][0]); acc[2][1] = fmaf(a2, b1, acc[2][1]);
            acc[2][2] = fmaf(a2, b2, acc[2][2]); acc[2][3] = fmaf(a2, b3, acc[2][3]);
            acc[3][0] = fmaf(a3, b0, acc[3][0]); acc[3][1] = fmaf(a3, b1, acc[3][1]);
            acc[3][2] = fmaf(a3, b2, acc[3][2]); acc[3][3] = fmaf(a3, b3, acc[3][3]);
        }
        __syncthreads();
    }
#pragma unroll
    for (int i = 0; i < 4; ++i) {
        int m = bm0 + ty * 4 + i;
        if (m < M) {
#pragma unroll
            for (int j = 0; j < 4; ++j) {
                int n = bn0 + tx * 4 + j;
                float o = acc[i][j];
                if (ADD_BIAS) o += bias[n];
                C[(size_t)m * N + n] = o;
            }
        }
    }
}

// ---------------- pooling: z = mu + 0.01*g*exp(0.5*beta*lv); partial max/sum ----------------
__global__ __launch_bounds__(256) void pool_partial(const float* __restrict__ mu,
                                                    const float* __restrict__ lv,
                                                    const uint32_t* __restrict__ beta_p,
                                                    float* __restrict__ pmax,
                                                    float* __restrict__ psum) {
    uint32_t bb = beta_p[0];
    float beta = (bb & 0x7F800000u) ? __uint_as_float(bb) : (float)(int)bb;
    int b = blockIdx.x;
    int r0 = b * 128;
    int r1 = min(r0 + 128, HALF_ROWS);
    int c = threadIdx.x * 2;
    float m0 = -INFINITY, m1 = -INFINITY, s0 = 0.f, s1 = 0.f;
    for (int r = r0; r < r1; ++r) {
#pragma unroll
        for (int q = 0; q < 2; ++q) {
            int cc = c + q;
            uint32_t idx = (uint32_t)r * 512u + (uint32_t)cc;
            uint32_t x0 = idx, x1 = idx + HALF_ELEMS;
            threefry2x32(0u, 42u, x0, x1);
            size_t ia = (size_t)r * HDIM + cc;
            size_t ib = (size_t)(r + HALF_ROWS) * HDIM + cc;
            float za = mu[ia] + 0.01f * jax_normal(x0) * __expf(0.5f * beta * lv[ia]);
            float zb = mu[ib] + 0.01f * jax_normal(x1) * __expf(0.5f * beta * lv[ib]);
            float mx = fmaxf(za, zb);
            float sm = za + zb;
            if (q == 0) { m0 = fmaxf(m0, mx); s0 += sm; }
            else        { m1 = fmaxf(m1, mx); s1 += sm; }
        }
    }
    pmax[(size_t)b * HDIM + c]     = m0;
    pmax[(size_t)b * HDIM + c + 1] = m1;
    psum[(size_t)b * HDIM + c]     = s0;
    psum[(size_t)b * HDIM + c + 1] = s1;
}

__global__ void pool_final(const float* __restrict__ pmax, const float* __restrict__ psum,
                           float* __restrict__ pooled) {
    int c = blockIdx.x * 256 + threadIdx.x;
    if (c < HDIM) {
        float m = -INFINITY, s = 0.f;
        for (int b = 0; b < POOL_BLOCKS; ++b) {
            m = fmaxf(m, pmax[(size_t)b * HDIM + c]);
            s += psum[(size_t)b * HDIM + c];
        }
        pooled[c] = m;
        pooled[HDIM + c] = s / 30000.0f;
    }
}

// ---------------- decoder dense 1024x1024 ----------------
__global__ __launch_bounds__(256) void dense1024(const float* __restrict__ in,
                                                 const float* __restrict__ W,
                                                 const float* __restrict__ bias,
                                                 float* __restrict__ out, int act) {
    __shared__ float sin_[1024];
    for (int i = threadIdx.x; i < 1024; i += 256) sin_[i] = in[i];
    __syncthreads();
    int j = blockIdx.x * 256 + threadIdx.x;
    float acc = bias[j];
    for (int i = 0; i < 1024; ++i) acc = fmaf(sin_[i], W[i * 1024 + j], acc);
    out[j] = act ? (1.0f / (1.0f + __expf(-acc))) : fmaxf(acc, 0.f);
}

// ---------------- launch ----------------
extern "C" void kernel_launch(void* const* d_in, const int* in_sizes, int n_in,
                              void* d_out, int out_size, void* d_ws, size_t ws_size,
                              hipStream_t stream) {
    const float* x   = (const float*)d_in[0];
    const int*   ei  = (const int*)d_in[1];
    const float* ew  = (const float*)d_in[2];
    const uint32_t* beta = (const uint32_t*)d_in[3];
    const float* W1  = (const float*)d_in[4];
    const float* b1  = (const float*)d_in[5];
    const float* W2  = (const float*)d_in[6];
    const float* b2  = (const float*)d_in[7];
    const float* W3  = (const float*)d_in[8];
    const float* b3  = (const float*)d_in[9];
    const float* Wmu = (const float*)d_in[10];
    const float* bmu = (const float*)d_in[11];
    const float* Wlv = (const float*)d_in[12];
    const float* blv = (const float*)d_in[13];
    const float* Wd1 = (const float*)d_in[14];
    const float* bd1 = (const float*)d_in[15];
    const float* Wd2 = (const float*)d_in[16];
    const float* bd2 = (const float*)d_in[17];

    const int E = in_sizes[2];            // 300000
    const int M = NNODE;                  // 30000

    float* out    = (float*)d_out;
    float* mu_out = out + 1024;                           // [30000,512]
    float* lv_out = out + 1024 + (size_t)M * HDIM;        // [30000,512]

    // workspace layout (floats)
    float* ws = (float*)d_ws;
    float* AX    = ws;                                    // 15,360,000 (reused: AX, h2, h3+agg3)
    float* BIG   = ws + (size_t)15360000;                 // 30,720,000 (h1/out1)
    float* deg   = ws + (size_t)46080000;                 // 30,000
    float* dinv  = ws + (size_t)46110000;                 // 30,000
    float* pmax  = ws + (size_t)46140000;                 // 118*512
    float* psum  = ws + (size_t)46200416;                 // 118*512
    float* pooled= ws + (size_t)46260832;                 // 1024
    float* hdec  = ws + (size_t)46261856;                 // 1024

    // CSR arrays live in the lv_out region of d_out — unused until step 5,
    // at which point the CSR is no longer needed. 690,001 ints << 15.36M floats.
    int*   cnt    = (int*)lv_out;                         // 30,000
    int*   rowptr = (int*)lv_out + 30000;                 // 30,001
    int*   fill   = (int*)lv_out + 60001;                 // 30,000
    int*   ecol   = (int*)lv_out + 90001;                 // E
    float* eval   = (float*)((int*)lv_out + 90001 + E);   // E

    const int* row = ei;
    const int* col = ei + E;

    // 1) degrees, counts, D^-1/2, CSR build
    hipMemsetAsync(deg, 0, (size_t)M * sizeof(float), stream);
    hipMemsetAsync(cnt, 0, (size_t)M * sizeof(int), stream);
    hipMemsetAsync(fill, 0, (size_t)M * sizeof(int), stream);
    deg_cnt_kernel<<<(E + 255) / 256, 256, 0, stream>>>(row, ew, deg, cnt, E);
    dinv_kernel<<<(M + 255) / 256, 256, 0, stream>>>(deg, dinv, M);
    build_rowptr<<<1, 256, 0, stream>>>(cnt, rowptr);
    scatter_edges<<<(E + 255) / 256, 256, 0, stream>>>(row, col, ew, dinv, rowptr, fill,
                                                       ecol, eval, E);

    const int SPMM_GRID = (M + 3) / 4;    // wave per row, 4 waves per block

    // 2) layer 1: AX = A_hat @ X (F=512), h1 = AX@W1 + (norm-relu with no pre-bias? bias=b1)
    {
        spmm_csr<512, false><<<SPMM_GRID, 256, 0, stream>>>(rowptr, ecol, eval, dinv, x,
                                                            nullptr, AX);
        dim3 g(H1DIM / 64, (M + 63) / 64);
        sgemm64<true><<<g, 256, 0, stream>>>(AX, W1, b1, BIG, M, H1DIM, FIN);
        bias_l2norm_relu<<<M, 256, 0, stream>>>(BIG, nullptr, H1DIM);
    }

    // 3) layer 2: h2 = out1@W2 (-> AX), out2 = normrelu(A_hat@h2 + b2) (-> mu region)
    {
        float* h2   = AX;
        float* out2 = mu_out;     // scratch until final mu written
        dim3 g(H2DIM / 64, (M + 63) / 64);
        sgemm64<false><<<g, 256, 0, stream>>>(BIG, W2, nullptr, h2, M, H2DIM, H1DIM);
        spmm_csr<512, true><<<SPMM_GRID, 256, 0, stream>>>(rowptr, ecol, eval, dinv, h2,
                                                           b2, out2);
    }

    // 4) layer 3: h3 = out2@W3 (-> AX), out3 = normrelu(A_hat@h3 + b3) (-> AX+7.68M)
    float* out3;
    {
        const float* out2 = mu_out;
        float* h3 = AX;
        out3 = AX + (size_t)7680000;
        dim3 g(H3DIM / 64, (M + 63) / 64);
        sgemm64<false><<<g, 256, 0, stream>>>(out2, W3, nullptr, h3, M, H3DIM, H2DIM);
        spmm_csr<256, true><<<SPMM_GRID, 256, 0, stream>>>(rowptr, ecol, eval, dinv, h3,
                                                           b3, out3);
    }

    // 5) mu / logvar (overwrites CSR scratch in lv region — CSR no longer needed)
    {
        dim3 g(HDIM / 64, (M + 63) / 64);
        sgemm64<true><<<g, 256, 0, stream>>>(out3, Wmu, bmu, mu_out, M, HDIM, H3DIM);
        sgemm64<true><<<g, 256, 0, stream>>>(out3, Wlv, blv, lv_out, M, HDIM, H3DIM);
    }

    // 6) pooling with JAX-exact reparameterization noise
    pool_partial<<<POOL_BLOCKS, 256, 0, stream>>>(mu_out, lv_out, beta, pmax, psum);
    pool_final<<<2, 256, 0, stream>>>(pmax, psum, pooled);

    // 7) decoder
    dense1024<<<4, 256, 0, stream>>>(pooled, Wd1, bd1, hdec, 0);
    dense1024<<<4, 256, 0, stream>>>(hdec, Wd2, bd2, out, 1);
}

// Round 3
// 855.280 us; speedup vs baseline: 3.3583x; 2.2103x over previous
//
#include <hip/hip_runtime.h>
#include <cstdint>
#include <cstddef>

// ---------------- problem constants ----------------
#define NNODE      30000
#define MPAD       30080        // 235 * 128
#define FIN        512
#define H1DIM      1024
#define H2DIM      512
#define H3DIM      256
#define HDIM       512          // mu/logvar width
#define HALF_ROWS  15000
#define HALF_ELEMS 7680000u     // 15000*512 (threefry pair offset)
#define POOL_BLOCKS 118         // ceil(15000/128)

typedef __attribute__((ext_vector_type(8))) short s16x8;
typedef __attribute__((ext_vector_type(4))) short s16x4;
typedef __attribute__((ext_vector_type(4))) float f32x4;

// bf16 <-> f32 (RNE, matches JAX/torch)
__device__ __forceinline__ short f2bf(float f) {
    uint32_t u = __float_as_uint(f);
    uint32_t r = (u + 0x7FFFu + ((u >> 16) & 1u)) >> 16;
    return (short)r;
}
__device__ __forceinline__ float bf2f(short s) {
    return __uint_as_float(((uint32_t)(uint16_t)s) << 16);
}

// ---------------- threefry2x32 (JAX-exact) ----------------
__device__ __forceinline__ void threefry2x32(uint32_t k0, uint32_t k1,
                                             uint32_t& x0, uint32_t& x1) {
    uint32_t ks0 = k0, ks1 = k1, ks2 = k0 ^ k1 ^ 0x1BD11BDAu;
    const uint32_t R0[4] = {13u, 15u, 26u, 6u};
    const uint32_t R1[4] = {17u, 29u, 16u, 24u};
    x0 += ks0; x1 += ks1;
#pragma unroll
    for (int g = 0; g < 5; ++g) {
        const uint32_t* R = (g & 1) ? R1 : R0;
#pragma unroll
        for (int r = 0; r < 4; ++r) {
            x0 += x1;
            x1 = (x1 << R[r]) | (x1 >> (32u - R[r]));
            x1 ^= x0;
        }
        uint32_t ks_a = (g % 3 == 0) ? ks1 : (g % 3 == 1 ? ks2 : ks0);
        uint32_t ks_b = (g % 3 == 0) ? ks2 : (g % 3 == 1 ? ks0 : ks1);
        x0 += ks_a;
        x1 += ks_b + (uint32_t)(g + 1);
    }
}

__device__ __forceinline__ float jax_normal(uint32_t bits) {
    uint32_t fb = (bits >> 9) | 0x3F800000u;
    float f = __uint_as_float(fb) - 1.0f;
    const float lo = -0.99999994f;
    float u = fmaf(f, 2.0f, lo);
    u = fmaxf(u, lo);
    return 1.41421356237f * erfinvf(u);
}

// ---------------- degree + count ----------------
__global__ void deg_cnt_kernel(const int* __restrict__ row, const float* __restrict__ w,
                               float* __restrict__ deg, int* __restrict__ cnt, int E) {
    int e = blockIdx.x * 256 + threadIdx.x;
    if (e < E) {
        int r = row[e];
        atomicAdd(&deg[r], w[e]);
        atomicAdd(&cnt[r], 1);
    }
}

__global__ void dinv_kernel(const float* __restrict__ deg, float* __restrict__ dinv, int n) {
    int i = blockIdx.x * 256 + threadIdx.x;
    if (i < n) dinv[i] = rsqrtf(deg[i] + 1.0f);
}

// ---------------- single-block exclusive scan -> rowptr ----------------
__global__ __launch_bounds__(256) void build_rowptr(const int* __restrict__ cnt,
                                                    int* __restrict__ rowptr) {
    __shared__ int sums[256];
    const int ROWS_PT = 118;
    int t = threadIdx.x;
    int base = t * ROWS_PT;
    int local = 0;
    for (int i = 0; i < ROWS_PT; ++i) {
        int r = base + i;
        if (r < NNODE) local += cnt[r];
    }
    sums[t] = local;
    __syncthreads();
    for (int o = 1; o < 256; o <<= 1) {
        int v = (t >= o) ? sums[t - o] : 0;
        __syncthreads();
        sums[t] += v;
        __syncthreads();
    }
    int off = (t == 0) ? 0 : sums[t - 1];
    for (int i = 0; i < ROWS_PT; ++i) {
        int r = base + i;
        if (r < NNODE) { rowptr[r] = off; off += cnt[r]; }
    }
    if (t == 255) rowptr[NNODE] = off;
}

// ---------------- scatter edges into CSR with pre-normalized weights ----------------
__global__ void scatter_edges(const int* __restrict__ row, const int* __restrict__ col,
                              const float* __restrict__ w, const float* __restrict__ dinv,
                              const int* __restrict__ rowptr, int* __restrict__ fill,
                              int* __restrict__ ecol, float* __restrict__ eval, int E) {
    int e = blockIdx.x * 256 + threadIdx.x;
    if (e < E) {
        int r = row[e], c = col[e];
        int pos = rowptr[r] + atomicAdd(&fill[r], 1);
        ecol[pos] = c;
        eval[pos] = dinv[r] * w[e] * dinv[c];
    }
}

// ---------------- fp32 -> bf16 elementwise (float4 granularity) ----------------
__global__ void f32_to_bf16(const float* __restrict__ in, short* __restrict__ out, int n4) {
    int i = blockIdx.x * 256 + threadIdx.x;
    if (i < n4) {
        float4 v = ((const float4*)in)[i];
        s16x4 s = { f2bf(v.x), f2bf(v.y), f2bf(v.z), f2bf(v.w) };
        *(s16x4*)(out + (size_t)i * 4) = s;
    }
}

// ---------------- transpose + convert: Wt[n][k] = bf16(W[k][n]) ----------------
__global__ __launch_bounds__(256) void transpose_bf16(const float* __restrict__ W,
                                                      short* __restrict__ Wt, int K, int N) {
    __shared__ float t[32][33];
    int kb = blockIdx.y * 32, nb = blockIdx.x * 32;
    int tx = threadIdx.x & 31, ty = threadIdx.x >> 5;     // 32 x 8
#pragma unroll
    for (int i = 0; i < 32; i += 8)
        if (kb + ty + i < K && nb + tx < N)
            t[ty + i][tx] = W[(size_t)(kb + ty + i) * N + nb + tx];
    __syncthreads();
#pragma unroll
    for (int i = 0; i < 32; i += 8)
        if (nb + ty + i < N && kb + tx < K)
            Wt[(size_t)(nb + ty + i) * K + kb + tx] = f2bf(t[tx][ty + i]);
}

// ---------------- CSR SpMM on bf16 rows, optional fused bias+L2norm+ReLU ----------------
template <int F, bool FUSE>
__global__ __launch_bounds__(256) void spmm_bf16(const int* __restrict__ rowptr,
                                                 const int* __restrict__ ecol,
                                                 const float* __restrict__ eval,
                                                 const float* __restrict__ dinv,
                                                 const short* __restrict__ h,
                                                 const float* __restrict__ bias,
                                                 short* __restrict__ out) {
    constexpr int NE = F / 64;               // 512->8, 256->4
    int lane = threadIdx.x & 63;
    int r = blockIdx.x * 4 + (threadIdx.x >> 6);
    if (r >= NNODE) return;
    float d = dinv[r];
    float dd = d * d;
    float acc[NE];
    {
        const short* p = h + (size_t)r * F + lane * NE;
        if constexpr (NE == 8) {
            s16x8 v = *(const s16x8*)p;
#pragma unroll
            for (int j = 0; j < 8; ++j) acc[j] = dd * bf2f(v[j]);
        } else {
            s16x4 v = *(const s16x4*)p;
#pragma unroll
            for (int j = 0; j < 4; ++j) acc[j] = dd * bf2f(v[j]);
        }
    }
    int e0 = rowptr[r], e1 = rowptr[r + 1];
    for (int e = e0; e < e1; ++e) {
        int c = ecol[e];
        float nw = eval[e];
        const short* p = h + (size_t)c * F + lane * NE;
        if constexpr (NE == 8) {
            s16x8 v = *(const s16x8*)p;
#pragma unroll
            for (int j = 0; j < 8; ++j) acc[j] = fmaf(nw, bf2f(v[j]), acc[j]);
        } else {
            s16x4 v = *(const s16x4*)p;
#pragma unroll
            for (int j = 0; j < 4; ++j) acc[j] = fmaf(nw, bf2f(v[j]), acc[j]);
        }
    }
    short* o = out + (size_t)r * F + lane * NE;
    if (FUSE) {
        const float* bp = bias + lane * NE;
        float ss = 0.f;
#pragma unroll
        for (int j = 0; j < NE; ++j) { acc[j] += bp[j]; ss += acc[j] * acc[j]; }
#pragma unroll
        for (int off = 32; off; off >>= 1) ss += __shfl_xor(ss, off);
        float rinv = 1.0f / fmaxf(sqrtf(ss), 1e-12f);
#pragma unroll
        for (int j = 0; j < NE; ++j) acc[j] = fmaxf(acc[j] * rinv, 0.f);
    }
    if constexpr (NE == 8) {
        s16x8 s;
#pragma unroll
        for (int j = 0; j < 8; ++j) s[j] = f2bf(acc[j]);
        *(s16x8*)o = s;
    } else {
        s16x4 s;
#pragma unroll
        for (int j = 0; j < 4; ++j) s[j] = f2bf(acc[j]);
        *(s16x4*)o = s;
    }
}

// ---------------- L2norm+ReLU for F=1024 bf16 (wave per row) ----------------
__global__ __launch_bounds__(256) void l2norm_relu_1024(const short* __restrict__ in,
                                                        short* __restrict__ out) {
    int lane = threadIdx.x & 63;
    int r = blockIdx.x * 4 + (threadIdx.x >> 6);
    if (r >= NNODE) return;
    const s16x8* p = (const s16x8*)(in + (size_t)r * 1024);
    s16x8 v0 = p[lane], v1 = p[lane + 64];
    float f0[8], f1[8];
    float ss = 0.f;
#pragma unroll
    for (int j = 0; j < 8; ++j) {
        f0[j] = bf2f(v0[j]); ss += f0[j] * f0[j];
        f1[j] = bf2f(v1[j]); ss += f1[j] * f1[j];
    }
#pragma unroll
    for (int off = 32; off; off >>= 1) ss += __shfl_xor(ss, off);
    float rinv = 1.0f / fmaxf(sqrtf(ss), 1e-12f);
    s16x8 o0, o1;
#pragma unroll
    for (int j = 0; j < 8; ++j) {
        o0[j] = f2bf(fmaxf(f0[j] * rinv, 0.f));
        o1[j] = f2bf(fmaxf(f1[j] * rinv, 0.f));
    }
    s16x8* q = (s16x8*)(out + (size_t)r * 1024);
    q[lane] = o0;
    q[lane + 64] = o1;
}

// ---------------- bf16 MFMA GEMM: C[M][N] = A[Mpad][K] * Bt[N][K]^T (+bias) ----------------
// m97 structure: 128x128 tile, BK=64, 4 waves x (64x64), global_load_lds w16, 2 barriers.
template <typename OutT, bool ADD_BIAS>
__global__ __launch_bounds__(256) void gemm_bf16(const short* __restrict__ A,
                                                 const short* __restrict__ Bt,
                                                 const float* __restrict__ bias,
                                                 OutT* __restrict__ C,
                                                 int M, int N, int K) {
    __shared__ short sA[128 * 64];
    __shared__ short sB[128 * 64];
    const int tid = threadIdx.x;
    const int lane = tid & 63;
    const int w = tid >> 6;                 // wave 0..3
    const int wm = w >> 1, wn = w & 1;      // 2x2 wave grid, 64x64 each
    const int m0 = blockIdx.y * 128;
    const int n0 = blockIdx.x * 128;

    const int srow = lane >> 3;             // 0..7
    const int scol = (lane & 7) * 8;        // 0,8,..,56 (bf16 elems)

    f32x4 acc[4][4] = {};

    const int lrow = lane & 15;
    const int lkof = (lane >> 4) * 8;       // k-offset within 32-wide frag

    const int nkt = K >> 6;
    for (int kt = 0; kt < nkt; ++kt) {
        const int k0 = kt << 6;
        // stage A tile [128 rows m][64 k] and B tile [128 rows n][64 k], both linear LDS
#pragma unroll
        for (int i = 0; i < 4; ++i) {
            int c = i * 4 + w;              // chunk 0..15, wave-uniform
            int tr = c * 8 + srow;          // tile row 0..127
            __builtin_amdgcn_global_load_lds(
                (const __attribute__((address_space(1))) void*)(A + (size_t)(m0 + tr) * K + k0 + scol),
                (__attribute__((address_space(3))) void*)(sA + c * 512),
                16, 0, 0);
        }
#pragma unroll
        for (int i = 0; i < 4; ++i) {
            int c = i * 4 + w;
            int tr = c * 8 + srow;
            __builtin_amdgcn_global_load_lds(
                (const __attribute__((address_space(1))) void*)(Bt + (size_t)(n0 + tr) * K + k0 + scol),
                (__attribute__((address_space(3))) void*)(sB + c * 512),
                16, 0, 0);
        }
        __syncthreads();                    // compiler drains vmcnt before barrier

        s16x8 af[4][2], bfr[4][2];
#pragma unroll
        for (int fm = 0; fm < 4; ++fm)
#pragma unroll
            for (int fk = 0; fk < 2; ++fk)
                af[fm][fk] = *(const s16x8*)&sA[(wm * 64 + fm * 16 + lrow) * 64 + fk * 32 + lkof];
#pragma unroll
        for (int fn = 0; fn < 4; ++fn)
#pragma unroll
            for (int fk = 0; fk < 2; ++fk)
                bfr[fn][fk] = *(const s16x8*)&sB[(wn * 64 + fn * 16 + lrow) * 64 + fk * 32 + lkof];
#pragma unroll
        for (int fm = 0; fm < 4; ++fm)
#pragma unroll
            for (int fn = 0; fn < 4; ++fn) {
                acc[fm][fn] = __builtin_amdgcn_mfma_f32_16x16x32_bf16(af[fm][0], bfr[fn][0], acc[fm][fn], 0, 0, 0);
                acc[fm][fn] = __builtin_amdgcn_mfma_f32_16x16x32_bf16(af[fm][1], bfr[fn][1], acc[fm][fn], 0, 0, 0);
            }
        __syncthreads();
    }

    // epilogue: C/D layout col=lane&15, row=(lane>>4)*4+reg  [m89-verified]
    const int crow = (lane >> 4) * 4;
    const int ccol = lane & 15;
#pragma unroll
    for (int fm = 0; fm < 4; ++fm) {
#pragma unroll
        for (int fn = 0; fn < 4; ++fn) {
            int n = n0 + wn * 64 + fn * 16 + ccol;
            float b = ADD_BIAS ? bias[n] : 0.f;
#pragma unroll
            for (int r = 0; r < 4; ++r) {
                int m = m0 + wm * 64 + fm * 16 + crow + r;
                if (m < M) {
                    float o = acc[fm][fn][r] + b;
                    if constexpr (sizeof(OutT) == 2) C[(size_t)m * N + n] = (OutT)f2bf(o);
                    else                             C[(size_t)m * N + n] = o;
                }
            }
        }
    }
}

// ---------------- pooling: z = mu + 0.01*g*exp(0.5*beta*lv) ----------------
__global__ __launch_bounds__(256) void pool_partial(const float* __restrict__ mu,
                                                    const float* __restrict__ lv,
                                                    const uint32_t* __restrict__ beta_p,
                                                    float* __restrict__ pmax,
                                                    float* __restrict__ psum) {
    uint32_t bb = beta_p[0];
    float beta = (bb & 0x7F800000u) ? __uint_as_float(bb) : (float)(int)bb;
    int b = blockIdx.x;
    int r0 = b * 128;
    int r1 = min(r0 + 128, HALF_ROWS);
    int c = threadIdx.x * 2;
    float m0 = -INFINITY, m1 = -INFINITY, s0 = 0.f, s1 = 0.f;
    for (int r = r0; r < r1; ++r) {
#pragma unroll
        for (int q = 0; q < 2; ++q) {
            int cc = c + q;
            uint32_t idx = (uint32_t)r * 512u + (uint32_t)cc;
            uint32_t x0 = idx, x1 = idx + HALF_ELEMS;
            threefry2x32(0u, 42u, x0, x1);
            size_t ia = (size_t)r * HDIM + cc;
            size_t ib = (size_t)(r + HALF_ROWS) * HDIM + cc;
            float za = mu[ia] + 0.01f * jax_normal(x0) * __expf(0.5f * beta * lv[ia]);
            float zb = mu[ib] + 0.01f * jax_normal(x1) * __expf(0.5f * beta * lv[ib]);
            float mx = fmaxf(za, zb);
            float sm = za + zb;
            if (q == 0) { m0 = fmaxf(m0, mx); s0 += sm; }
            else        { m1 = fmaxf(m1, mx); s1 += sm; }
        }
    }
    pmax[(size_t)b * HDIM + c]     = m0;
    pmax[(size_t)b * HDIM + c + 1] = m1;
    psum[(size_t)b * HDIM + c]     = s0;
    psum[(size_t)b * HDIM + c + 1] = s1;
}

__global__ void pool_final(const float* __restrict__ pmax, const float* __restrict__ psum,
                           float* __restrict__ pooled) {
    int c = blockIdx.x * 256 + threadIdx.x;
    if (c < HDIM) {
        float m = -INFINITY, s = 0.f;
        for (int b = 0; b < POOL_BLOCKS; ++b) {
            m = fmaxf(m, pmax[(size_t)b * HDIM + c]);
            s += psum[(size_t)b * HDIM + c];
        }
        pooled[c] = m;
        pooled[HDIM + c] = s / 30000.0f;
    }
}

// ---------------- decoder dense 1024x1024 ----------------
__global__ __launch_bounds__(256) void dense1024(const float* __restrict__ in,
                                                 const float* __restrict__ W,
                                                 const float* __restrict__ bias,
                                                 float* __restrict__ out, int act) {
    __shared__ float sin_[1024];
    for (int i = threadIdx.x; i < 1024; i += 256) sin_[i] = in[i];
    __syncthreads();
    int j = blockIdx.x * 256 + threadIdx.x;
    float acc = bias[j];
    for (int i = 0; i < 1024; ++i) acc = fmaf(sin_[i], W[i * 1024 + j], acc);
    out[j] = act ? (1.0f / (1.0f + __expf(-acc))) : fmaxf(acc, 0.f);
}

// ---------------- launch ----------------
extern "C" void kernel_launch(void* const* d_in, const int* in_sizes, int n_in,
                              void* d_out, int out_size, void* d_ws, size_t ws_size,
                              hipStream_t stream) {
    const float* x   = (const float*)d_in[0];
    const int*   ei  = (const int*)d_in[1];
    const float* ew  = (const float*)d_in[2];
    const uint32_t* beta = (const uint32_t*)d_in[3];
    const float* W1  = (const float*)d_in[4];
    const float* b1  = (const float*)d_in[5];
    const float* W2  = (const float*)d_in[6];
    const float* b2  = (const float*)d_in[7];
    const float* W3  = (const float*)d_in[8];
    const float* b3  = (const float*)d_in[9];
    const float* Wmu = (const float*)d_in[10];
    const float* bmu = (const float*)d_in[11];
    const float* Wlv = (const float*)d_in[12];
    const float* blv = (const float*)d_in[13];
    const float* Wd1 = (const float*)d_in[14];
    const float* bd1 = (const float*)d_in[15];
    const float* Wd2 = (const float*)d_in[16];
    const float* bd2 = (const float*)d_in[17];

    const int E = in_sizes[2];            // 300000
    const int M = NNODE;

    float* out    = (float*)d_out;
    float* mu_out = out + 1024;                           // [30000,512]
    float* lv_out = out + 1024 + (size_t)M * HDIM;        // [30000,512]

    // ---------------- workspace layout (bytes) ----------------
    char* Wp = (char*)d_ws;
    short* slotA  = (short*)(Wp);                         // 61,603,840 B (30080x1024 bf16 max)
    short* slotB  = (short*)(Wp + 61603840);              // 61,603,840 B
    short* xb     = (short*)(Wp + 123207680);             // 30,720,000 B (30000x512 bf16)
    short* W1t    = (short*)(Wp + 154009600);             // 1024x512
    short* W2t    = (short*)(Wp + 155058176);             // 512x1024
    short* W3t    = (short*)(Wp + 156106752);             // 256x512
    short* Wmut   = (short*)(Wp + 156368896);             // 512x256
    short* Wlvt   = (short*)(Wp + 156631040);             // 512x256
    float* deg    = (float*)(Wp + 156893184);
    float* dinv   = (float*)(Wp + 157013184);
    int*   cnt    = (int*)  (Wp + 157133184);
    int*   fill   = (int*)  (Wp + 157253184);
    int*   rowptr = (int*)  (Wp + 157373184);
    int*   ecol   = (int*)  (Wp + 157493188);
    float* eval   = (float*)(Wp + 158693188);
    float* pmax   = (float*)(Wp + 159893188);
    float* psum   = (float*)(Wp + 160134852);
    float* pooled = (float*)(Wp + 160376516);
    float* hdec   = (float*)(Wp + 160380612);

    const int* row = ei;
    const int* col = ei + E;

    // 1) degrees, counts, D^-1/2, CSR build
    hipMemsetAsync(deg, 0, (size_t)M * sizeof(float), stream);
    hipMemsetAsync(cnt, 0, (size_t)M * sizeof(int), stream);
    hipMemsetAsync(fill, 0, (size_t)M * sizeof(int), stream);
    // zero pad rows: AXb pad == out2b pad region [30000*512 .. 30080*512) shorts,
    // and out1b pad region [30000*1024 .. 30080*1024) shorts (untouched until gemm2).
    hipMemsetAsync(slotA + (size_t)30000 * 512, 0, 80 * 512 * sizeof(short), stream);
    hipMemsetAsync(slotA + (size_t)30000 * 1024, 0, 80 * 1024 * sizeof(short), stream);

    deg_cnt_kernel<<<(E + 255) / 256, 256, 0, stream>>>(row, ew, deg, cnt, E);
    dinv_kernel<<<(M + 255) / 256, 256, 0, stream>>>(deg, dinv, M);
    build_rowptr<<<1, 256, 0, stream>>>(cnt, rowptr);
    scatter_edges<<<(E + 255) / 256, 256, 0, stream>>>(row, col, ew, dinv, rowptr, fill,
                                                       ecol, eval, E);

    // 2) conversions: x -> bf16, weights -> transposed bf16 [N][K]
    f32_to_bf16<<<(M * FIN / 4 + 255) / 256, 256, 0, stream>>>(x, xb, M * FIN / 4);
    {
        dim3 b(256);
        transpose_bf16<<<dim3(H1DIM / 32, FIN / 32),  b, 0, stream>>>(W1,  W1t,  FIN,   H1DIM);
        transpose_bf16<<<dim3(H2DIM / 32, H1DIM / 32), b, 0, stream>>>(W2,  W2t,  H1DIM, H2DIM);
        transpose_bf16<<<dim3(H3DIM / 32, H2DIM / 32), b, 0, stream>>>(W3,  W3t,  H2DIM, H3DIM);
        transpose_bf16<<<dim3(HDIM / 32,  H3DIM / 32), b, 0, stream>>>(Wmu, Wmut, H3DIM, HDIM);
        transpose_bf16<<<dim3(HDIM / 32,  H3DIM / 32), b, 0, stream>>>(Wlv, Wlvt, H3DIM, HDIM);
    }

    const int SPMM_GRID = (M + 3) / 4;
    const int GY = (M + 127) / 128;       // 235

    // 3) layer 1: AXb = A_hat @ xb (bf16, slotA); h1b = AXb@W1t + b1 (bf16, slotB); l2norm -> out1b (slotA)
    spmm_bf16<512, false><<<SPMM_GRID, 256, 0, stream>>>(rowptr, ecol, eval, dinv, xb,
                                                         nullptr, slotA);
    gemm_bf16<short, true><<<dim3(H1DIM / 128, GY), 256, 0, stream>>>(slotA, W1t, b1,
                                                                      slotB, M, H1DIM, FIN);
    l2norm_relu_1024<<<SPMM_GRID, 256, 0, stream>>>(slotB, slotA);

    // 4) layer 2: h2b = out1b@W2t (bf16, slotB); out2b = fused spmm (slotA)
    gemm_bf16<short, false><<<dim3(H2DIM / 128, GY), 256, 0, stream>>>(slotA, W2t, nullptr,
                                                                       slotB, M, H2DIM, H1DIM);
    // re-zero out2b pad (was overwritten by out1b data rows 15000-15040)
    hipMemsetAsync(slotA + (size_t)30000 * 512, 0, 80 * 512 * sizeof(short), stream);
    spmm_bf16<512, true><<<SPMM_GRID, 256, 0, stream>>>(rowptr, ecol, eval, dinv, slotB,
                                                        b2, slotA);

    // 5) layer 3: h3b = out2b@W3t (bf16, slotB); out3b = fused spmm (slotA)
    gemm_bf16<short, false><<<dim3(H3DIM / 128, GY), 256, 0, stream>>>(slotA, W3t, nullptr,
                                                                       slotB, M, H3DIM, H2DIM);
    // zero out3b pad [30000*256 .. 30080*256) (held stale out2b data)
    hipMemsetAsync(slotA + (size_t)30000 * 256, 0, 80 * 256 * sizeof(short), stream);
    spmm_bf16<256, true><<<SPMM_GRID, 256, 0, stream>>>(rowptr, ecol, eval, dinv, slotB,
                                                        b3, slotA);

    // 6) mu / logvar (fp32 out to d_out)
    gemm_bf16<float, true><<<dim3(HDIM / 128, GY), 256, 0, stream>>>(slotA, Wmut, bmu,
                                                                     mu_out, M, HDIM, H3DIM);
    gemm_bf16<float, true><<<dim3(HDIM / 128, GY), 256, 0, stream>>>(slotA, Wlvt, blv,
                                                                     lv_out, M, HDIM, H3DIM);

    // 7) pooling with JAX-exact reparameterization noise
    pool_partial<<<POOL_BLOCKS, 256, 0, stream>>>(mu_out, lv_out, beta, pmax, psum);
    pool_final<<<2, 256, 0, stream>>>(pmax, psum, pooled);

    // 8) decoder
    dense1024<<<4, 256, 0, stream>>>(pooled, Wd1, bd1, hdec, 0);
    dense1024<<<4, 256, 0, stream>>>(hdec, Wd2, bd2, out, 1);
}

// Round 4
// 624.299 us; speedup vs baseline: 4.6008x; 1.3700x over previous
//
#include <hip/hip_runtime.h>
#include <cstdint>
#include <cstddef>

// ---------------- problem constants ----------------
#define NNODE      30000
#define MPAD       30080        // 235 * 128
#define FIN        512
#define H1DIM      1024
#define H2DIM      512
#define H3DIM      256
#define HDIM       512          // mu/logvar width
#define HALF_ROWS  15000
#define HALF_ELEMS 7680000u     // 15000*512 (threefry pair offset)
#define PP_ROWS    16
#define PP_BLOCKS  938          // ceil(15000/16)
#define PM_BLOCKS  64           // mid-reduce blocks (15 pp-blocks each)

typedef __attribute__((ext_vector_type(8))) short s16x8;
typedef __attribute__((ext_vector_type(4))) short s16x4;
typedef __attribute__((ext_vector_type(4))) float f32x4;

// bf16 <-> f32 (RNE, matches JAX/torch)
__device__ __forceinline__ short f2bf(float f) {
    uint32_t u = __float_as_uint(f);
    uint32_t r = (u + 0x7FFFu + ((u >> 16) & 1u)) >> 16;
    return (short)r;
}
__device__ __forceinline__ float bf2f(short s) {
    return __uint_as_float(((uint32_t)(uint16_t)s) << 16);
}

// ---------------- threefry2x32 (JAX-exact) ----------------
__device__ __forceinline__ void threefry2x32(uint32_t k0, uint32_t k1,
                                             uint32_t& x0, uint32_t& x1) {
    uint32_t ks0 = k0, ks1 = k1, ks2 = k0 ^ k1 ^ 0x1BD11BDAu;
    const uint32_t R0[4] = {13u, 15u, 26u, 6u};
    const uint32_t R1[4] = {17u, 29u, 16u, 24u};
    x0 += ks0; x1 += ks1;
#pragma unroll
    for (int g = 0; g < 5; ++g) {
        const uint32_t* R = (g & 1) ? R1 : R0;
#pragma unroll
        for (int r = 0; r < 4; ++r) {
            x0 += x1;
            x1 = (x1 << R[r]) | (x1 >> (32u - R[r]));
            x1 ^= x0;
        }
        uint32_t ks_a = (g % 3 == 0) ? ks1 : (g % 3 == 1 ? ks2 : ks0);
        uint32_t ks_b = (g % 3 == 0) ? ks2 : (g % 3 == 1 ? ks0 : ks1);
        x0 += ks_a;
        x1 += ks_b + (uint32_t)(g + 1);
    }
}

__device__ __forceinline__ float jax_normal(uint32_t bits) {
    uint32_t fb = (bits >> 9) | 0x3F800000u;
    float f = __uint_as_float(fb) - 1.0f;
    const float lo = -0.99999994f;
    float u = fmaf(f, 2.0f, lo);
    u = fmaxf(u, lo);
    return 1.41421356237f * erfinvf(u);
}

// ---------------- degree + count ----------------
__global__ void deg_cnt_kernel(const int* __restrict__ row, const float* __restrict__ w,
                               float* __restrict__ deg, int* __restrict__ cnt, int E) {
    int e = blockIdx.x * 256 + threadIdx.x;
    if (e < E) {
        int r = row[e];
        atomicAdd(&deg[r], w[e]);
        atomicAdd(&cnt[r], 1);
    }
}

__global__ void dinv_kernel(const float* __restrict__ deg, float* __restrict__ dinv, int n) {
    int i = blockIdx.x * 256 + threadIdx.x;
    if (i < n) dinv[i] = rsqrtf(deg[i] + 1.0f);
}

// ---------------- single-block exclusive scan -> rowptr ----------------
__global__ __launch_bounds__(256) void build_rowptr(const int* __restrict__ cnt,
                                                    int* __restrict__ rowptr) {
    __shared__ int sums[256];
    const int ROWS_PT = 118;
    int t = threadIdx.x;
    int base = t * ROWS_PT;
    int local = 0;
    for (int i = 0; i < ROWS_PT; ++i) {
        int r = base + i;
        if (r < NNODE) local += cnt[r];
    }
    sums[t] = local;
    __syncthreads();
    for (int o = 1; o < 256; o <<= 1) {
        int v = (t >= o) ? sums[t - o] : 0;
        __syncthreads();
        sums[t] += v;
        __syncthreads();
    }
    int off = (t == 0) ? 0 : sums[t - 1];
    for (int i = 0; i < ROWS_PT; ++i) {
        int r = base + i;
        if (r < NNODE) { rowptr[r] = off; off += cnt[r]; }
    }
    if (t == 255) rowptr[NNODE] = off;
}

// ---------------- scatter edges into CSR with pre-normalized weights ----------------
__global__ void scatter_edges(const int* __restrict__ row, const int* __restrict__ col,
                              const float* __restrict__ w, const float* __restrict__ dinv,
                              const int* __restrict__ rowptr, int* __restrict__ fill,
                              int* __restrict__ ecol, float* __restrict__ eval, int E) {
    int e = blockIdx.x * 256 + threadIdx.x;
    if (e < E) {
        int r = row[e], c = col[e];
        int pos = rowptr[r] + atomicAdd(&fill[r], 1);
        ecol[pos] = c;
        eval[pos] = dinv[r] * w[e] * dinv[c];
    }
}

// ---------------- fp32 -> bf16 elementwise (float4 granularity) ----------------
__global__ void f32_to_bf16(const float* __restrict__ in, short* __restrict__ out, int n4) {
    int i = blockIdx.x * 256 + threadIdx.x;
    if (i < n4) {
        float4 v = ((const float4*)in)[i];
        s16x4 s = { f2bf(v.x), f2bf(v.y), f2bf(v.z), f2bf(v.w) };
        *(s16x4*)(out + (size_t)i * 4) = s;
    }
}

// ---------------- transpose + convert: Wt[n][k] = bf16(W[k][n]) ----------------
__global__ __launch_bounds__(256) void transpose_bf16(const float* __restrict__ W,
                                                      short* __restrict__ Wt, int K, int N) {
    __shared__ float t[32][33];
    int kb = blockIdx.y * 32, nb = blockIdx.x * 32;
    int tx = threadIdx.x & 31, ty = threadIdx.x >> 5;     // 32 x 8
#pragma unroll
    for (int i = 0; i < 32; i += 8)
        if (kb + ty + i < K && nb + tx < N)
            t[ty + i][tx] = W[(size_t)(kb + ty + i) * N + nb + tx];
    __syncthreads();
#pragma unroll
    for (int i = 0; i < 32; i += 8)
        if (nb + ty + i < N && kb + tx < K)
            Wt[(size_t)(nb + ty + i) * K + kb + tx] = f2bf(t[tx][ty + i]);
}

// ---------------- CSR SpMM on bf16 rows, optional fused bias+L2norm+ReLU ----------------
template <int F, bool FUSE>
__global__ __launch_bounds__(256) void spmm_bf16(const int* __restrict__ rowptr,
                                                 const int* __restrict__ ecol,
                                                 const float* __restrict__ eval,
                                                 const float* __restrict__ dinv,
                                                 const short* __restrict__ h,
                                                 const float* __restrict__ bias,
                                                 short* __restrict__ out) {
    constexpr int NE = F / 64;               // 512->8, 256->4
    int lane = threadIdx.x & 63;
    int r = blockIdx.x * 4 + (threadIdx.x >> 6);
    if (r >= NNODE) return;
    float d = dinv[r];
    float dd = d * d;
    float acc[NE];
    {
        const short* p = h + (size_t)r * F + lane * NE;
        if constexpr (NE == 8) {
            s16x8 v = *(const s16x8*)p;
#pragma unroll
            for (int j = 0; j < 8; ++j) acc[j] = dd * bf2f(v[j]);
        } else {
            s16x4 v = *(const s16x4*)p;
#pragma unroll
            for (int j = 0; j < 4; ++j) acc[j] = dd * bf2f(v[j]);
        }
    }
    int e0 = rowptr[r], e1 = rowptr[r + 1];
    for (int e = e0; e < e1; ++e) {
        int c = ecol[e];
        float nw = eval[e];
        const short* p = h + (size_t)c * F + lane * NE;
        if constexpr (NE == 8) {
            s16x8 v = *(const s16x8*)p;
#pragma unroll
            for (int j = 0; j < 8; ++j) acc[j] = fmaf(nw, bf2f(v[j]), acc[j]);
        } else {
            s16x4 v = *(const s16x4*)p;
#pragma unroll
            for (int j = 0; j < 4; ++j) acc[j] = fmaf(nw, bf2f(v[j]), acc[j]);
        }
    }
    short* o = out + (size_t)r * F + lane * NE;
    if (FUSE) {
        const float* bp = bias + lane * NE;
        float ss = 0.f;
#pragma unroll
        for (int j = 0; j < NE; ++j) { acc[j] += bp[j]; ss += acc[j] * acc[j]; }
#pragma unroll
        for (int off = 32; off; off >>= 1) ss += __shfl_xor(ss, off);
        float rinv = 1.0f / fmaxf(sqrtf(ss), 1e-12f);
#pragma unroll
        for (int j = 0; j < NE; ++j) acc[j] = fmaxf(acc[j] * rinv, 0.f);
    }
    if constexpr (NE == 8) {
        s16x8 s;
#pragma unroll
        for (int j = 0; j < 8; ++j) s[j] = f2bf(acc[j]);
        *(s16x8*)o = s;
    } else {
        s16x4 s;
#pragma unroll
        for (int j = 0; j < 4; ++j) s[j] = f2bf(acc[j]);
        *(s16x4*)o = s;
    }
}

// ---------------- L2norm+ReLU for F=1024 bf16 (wave per row) ----------------
__global__ __launch_bounds__(256) void l2norm_relu_1024(const short* __restrict__ in,
                                                        short* __restrict__ out) {
    int lane = threadIdx.x & 63;
    int r = blockIdx.x * 4 + (threadIdx.x >> 6);
    if (r >= NNODE) return;
    const s16x8* p = (const s16x8*)(in + (size_t)r * 1024);
    s16x8 v0 = p[lane], v1 = p[lane + 64];
    float f0[8], f1[8];
    float ss = 0.f;
#pragma unroll
    for (int j = 0; j < 8; ++j) {
        f0[j] = bf2f(v0[j]); ss += f0[j] * f0[j];
        f1[j] = bf2f(v1[j]); ss += f1[j] * f1[j];
    }
#pragma unroll
    for (int off = 32; off; off >>= 1) ss += __shfl_xor(ss, off);
    float rinv = 1.0f / fmaxf(sqrtf(ss), 1e-12f);
    s16x8 o0, o1;
#pragma unroll
    for (int j = 0; j < 8; ++j) {
        o0[j] = f2bf(fmaxf(f0[j] * rinv, 0.f));
        o1[j] = f2bf(fmaxf(f1[j] * rinv, 0.f));
    }
    s16x8* q = (s16x8*)(out + (size_t)r * 1024);
    q[lane] = o0;
    q[lane + 64] = o1;
}

// ---------------- bf16 MFMA GEMM: C[M][N] = A[Mpad][K] * Bt[N][K]^T (+bias) ----------------
template <typename OutT, bool ADD_BIAS>
__global__ __launch_bounds__(256) void gemm_bf16(const short* __restrict__ A,
                                                 const short* __restrict__ Bt,
                                                 const float* __restrict__ bias,
                                                 OutT* __restrict__ C,
                                                 int M, int N, int K) {
    __shared__ short sA[128 * 64];
    __shared__ short sB[128 * 64];
    const int tid = threadIdx.x;
    const int lane = tid & 63;
    const int w = tid >> 6;                 // wave 0..3
    const int wm = w >> 1, wn = w & 1;      // 2x2 wave grid, 64x64 each
    const int m0 = blockIdx.y * 128;
    const int n0 = blockIdx.x * 128;

    const int srow = lane >> 3;             // 0..7
    const int scol = (lane & 7) * 8;        // 0,8,..,56 (bf16 elems)

    f32x4 acc[4][4] = {};

    const int lrow = lane & 15;
    const int lkof = (lane >> 4) * 8;       // k-offset within 32-wide frag

    const int nkt = K >> 6;
    for (int kt = 0; kt < nkt; ++kt) {
        const int k0 = kt << 6;
#pragma unroll
        for (int i = 0; i < 4; ++i) {
            int c = i * 4 + w;
            int tr = c * 8 + srow;
            __builtin_amdgcn_global_load_lds(
                (const __attribute__((address_space(1))) void*)(A + (size_t)(m0 + tr) * K + k0 + scol),
                (__attribute__((address_space(3))) void*)(sA + c * 512),
                16, 0, 0);
        }
#pragma unroll
        for (int i = 0; i < 4; ++i) {
            int c = i * 4 + w;
            int tr = c * 8 + srow;
            __builtin_amdgcn_global_load_lds(
                (const __attribute__((address_space(1))) void*)(Bt + (size_t)(n0 + tr) * K + k0 + scol),
                (__attribute__((address_space(3))) void*)(sB + c * 512),
                16, 0, 0);
        }
        __syncthreads();

        s16x8 af[4][2], bfr[4][2];
#pragma unroll
        for (int fm = 0; fm < 4; ++fm)
#pragma unroll
            for (int fk = 0; fk < 2; ++fk)
                af[fm][fk] = *(const s16x8*)&sA[(wm * 64 + fm * 16 + lrow) * 64 + fk * 32 + lkof];
#pragma unroll
        for (int fn = 0; fn < 4; ++fn)
#pragma unroll
            for (int fk = 0; fk < 2; ++fk)
                bfr[fn][fk] = *(const s16x8*)&sB[(wn * 64 + fn * 16 + lrow) * 64 + fk * 32 + lkof];
#pragma unroll
        for (int fm = 0; fm < 4; ++fm)
#pragma unroll
            for (int fn = 0; fn < 4; ++fn) {
                acc[fm][fn] = __builtin_amdgcn_mfma_f32_16x16x32_bf16(af[fm][0], bfr[fn][0], acc[fm][fn], 0, 0, 0);
                acc[fm][fn] = __builtin_amdgcn_mfma_f32_16x16x32_bf16(af[fm][1], bfr[fn][1], acc[fm][fn], 0, 0, 0);
            }
        __syncthreads();
    }

    const int crow = (lane >> 4) * 4;
    const int ccol = lane & 15;
#pragma unroll
    for (int fm = 0; fm < 4; ++fm) {
#pragma unroll
        for (int fn = 0; fn < 4; ++fn) {
            int n = n0 + wn * 64 + fn * 16 + ccol;
            float b = ADD_BIAS ? bias[n] : 0.f;
#pragma unroll
            for (int r = 0; r < 4; ++r) {
                int m = m0 + wm * 64 + fm * 16 + crow + r;
                if (m < M) {
                    float o = acc[fm][fn][r] + b;
                    if constexpr (sizeof(OutT) == 2) C[(size_t)m * N + n] = (OutT)f2bf(o);
                    else                             C[(size_t)m * N + n] = o;
                }
            }
        }
    }
}

// ---------------- pooling stage 1: 938 blocks x 16 row-pairs ----------------
__global__ __launch_bounds__(256) void pool_partial(const float* __restrict__ mu,
                                                    const float* __restrict__ lv,
                                                    const uint32_t* __restrict__ beta_p,
                                                    float* __restrict__ pmax,
                                                    float* __restrict__ psum) {
    uint32_t bb = beta_p[0];
    float beta = (bb & 0x7F800000u) ? __uint_as_float(bb) : (float)(int)bb;
    int b = blockIdx.x;
    int r0 = b * PP_ROWS;
    int r1 = min(r0 + PP_ROWS, HALF_ROWS);
    int c = threadIdx.x * 2;
    float m0 = -INFINITY, m1 = -INFINITY, s0 = 0.f, s1 = 0.f;
    for (int r = r0; r < r1; ++r) {
        size_t ia = (size_t)r * HDIM + c;
        size_t ib = (size_t)(r + HALF_ROWS) * HDIM + c;
        float2 mua = *(const float2*)&mu[ia];
        float2 lva = *(const float2*)&lv[ia];
        float2 mub = *(const float2*)&mu[ib];
        float2 lvb = *(const float2*)&lv[ib];
        uint32_t idx0 = (uint32_t)r * 512u + (uint32_t)c;
        uint32_t xa0 = idx0,     ya0 = idx0 + HALF_ELEMS;
        uint32_t xa1 = idx0 + 1, ya1 = idx0 + 1 + HALF_ELEMS;
        threefry2x32(0u, 42u, xa0, ya0);
        threefry2x32(0u, 42u, xa1, ya1);
        float za0 = mua.x + 0.01f * jax_normal(xa0) * __expf(0.5f * beta * lva.x);
        float zb0 = mub.x + 0.01f * jax_normal(ya0) * __expf(0.5f * beta * lvb.x);
        float za1 = mua.y + 0.01f * jax_normal(xa1) * __expf(0.5f * beta * lva.y);
        float zb1 = mub.y + 0.01f * jax_normal(ya1) * __expf(0.5f * beta * lvb.y);
        m0 = fmaxf(m0, fmaxf(za0, zb0)); s0 += za0 + zb0;
        m1 = fmaxf(m1, fmaxf(za1, zb1)); s1 += za1 + zb1;
    }
    pmax[(size_t)b * HDIM + c]     = m0;
    pmax[(size_t)b * HDIM + c + 1] = m1;
    psum[(size_t)b * HDIM + c]     = s0;
    psum[(size_t)b * HDIM + c + 1] = s1;
}

// ---------------- pooling stage 2: 938 -> 64 partials ----------------
__global__ __launch_bounds__(256) void pool_mid(const float* __restrict__ pmax,
                                                const float* __restrict__ psum,
                                                float* __restrict__ pmax2,
                                                float* __restrict__ psum2) {
    int g = blockIdx.x;
    int b0 = g * 15;
    int b1 = min(b0 + 15, PP_BLOCKS);
#pragma unroll
    for (int pass = 0; pass < 2; ++pass) {
        int c = threadIdx.x + pass * 256;
        float m = -INFINITY, s = 0.f;
        for (int b = b0; b < b1; ++b) {
            m = fmaxf(m, pmax[(size_t)b * HDIM + c]);
            s += psum[(size_t)b * HDIM + c];
        }
        pmax2[(size_t)g * HDIM + c] = m;
        psum2[(size_t)g * HDIM + c] = s;
    }
}

// ---------------- pooling stage 3: 64 -> pooled[1024] ----------------
__global__ void pool_final(const float* __restrict__ pmax2, const float* __restrict__ psum2,
                           float* __restrict__ pooled) {
    int c = blockIdx.x * 256 + threadIdx.x;
    if (c < HDIM) {
        float m = -INFINITY, s = 0.f;
#pragma unroll
        for (int b = 0; b < PM_BLOCKS; ++b) {
            m = fmaxf(m, pmax2[(size_t)b * HDIM + c]);
            s += psum2[(size_t)b * HDIM + c];
        }
        pooled[c] = m;
        pooled[HDIM + c] = s / 30000.0f;
    }
}

// ---------------- decoder: split-K partial + finalize ----------------
__global__ __launch_bounds__(256) void dense_partial(const float* __restrict__ in,
                                                     const float* __restrict__ W,
                                                     float* __restrict__ part) {
    int by = blockIdx.y;                           // k-slice 0..7 (128 rows each)
    int j = blockIdx.x * 256 + threadIdx.x;        // 0..1023
    __shared__ float sin_[128];
    if (threadIdx.x < 128) sin_[threadIdx.x] = in[by * 128 + threadIdx.x];
    __syncthreads();
    float acc = 0.f;
#pragma unroll 8
    for (int i = 0; i < 128; ++i)
        acc = fmaf(sin_[i], W[(size_t)(by * 128 + i) * 1024 + j], acc);
    part[(size_t)by * 1024 + j] = acc;
}

__global__ void dense_final(const float* __restrict__ part, const float* __restrict__ bias,
                            float* __restrict__ out, int act) {
    int j = blockIdx.x * 256 + threadIdx.x;
    float acc = bias[j];
#pragma unroll
    for (int s = 0; s < 8; ++s) acc += part[(size_t)s * 1024 + j];
    out[j] = act ? (1.0f / (1.0f + __expf(-acc))) : fmaxf(acc, 0.f);
}

// ---------------- launch ----------------
extern "C" void kernel_launch(void* const* d_in, const int* in_sizes, int n_in,
                              void* d_out, int out_size, void* d_ws, size_t ws_size,
                              hipStream_t stream) {
    const float* x   = (const float*)d_in[0];
    const int*   ei  = (const int*)d_in[1];
    const float* ew  = (const float*)d_in[2];
    const uint32_t* beta = (const uint32_t*)d_in[3];
    const float* W1  = (const float*)d_in[4];
    const float* b1  = (const float*)d_in[5];
    const float* W2  = (const float*)d_in[6];
    const float* b2  = (const float*)d_in[7];
    const float* W3  = (const float*)d_in[8];
    const float* b3  = (const float*)d_in[9];
    const float* Wmu = (const float*)d_in[10];
    const float* bmu = (const float*)d_in[11];
    const float* Wlv = (const float*)d_in[12];
    const float* blv = (const float*)d_in[13];
    const float* Wd1 = (const float*)d_in[14];
    const float* bd1 = (const float*)d_in[15];
    const float* Wd2 = (const float*)d_in[16];
    const float* bd2 = (const float*)d_in[17];

    const int E = in_sizes[2];            // 300000
    const int M = NNODE;

    float* out    = (float*)d_out;
    float* mu_out = out + 1024;                           // [30000,512]
    float* lv_out = out + 1024 + (size_t)M * HDIM;        // [30000,512]

    // ---------------- workspace layout (bytes) ----------------
    char* Wp = (char*)d_ws;
    short* slotA  = (short*)(Wp);                         // 61,603,840 B (30080x1024 bf16 max)
    short* slotB  = (short*)(Wp + 61603840);              // 61,603,840 B
    short* xb     = (short*)(Wp + 123207680);             // 30,720,000 B
    short* W1t    = (short*)(Wp + 154009600);
    short* W2t    = (short*)(Wp + 155058176);
    short* W3t    = (short*)(Wp + 156106752);
    short* Wmut   = (short*)(Wp + 156368896);
    short* Wlvt   = (short*)(Wp + 156631040);
    float* deg    = (float*)(Wp + 156893184);
    float* dinv   = (float*)(Wp + 157013184);
    int*   cnt    = (int*)  (Wp + 157133184);
    int*   fill   = (int*)  (Wp + 157253184);
    int*   rowptr = (int*)  (Wp + 157373184);
    int*   ecol   = (int*)  (Wp + 157493188);
    float* eval   = (float*)(Wp + 158693188);
    float* pmax   = (float*)(Wp + 159893188);             // 938*512 = 1,921,024 B
    float* psum   = (float*)(Wp + 161814212);             // 1,921,024 B
    float* pmax2  = (float*)(Wp + 163735236);             // 64*512*4 = 131,072 B
    float* psum2  = (float*)(Wp + 163866308);             // 131,072 B
    float* pooled = (float*)(Wp + 163997380);             // 4,096 B
    float* hdec   = (float*)(Wp + 164001476);             // 4,096 B
    float* dpart  = (float*)(Wp + 164005572);             // 8*1024*4 = 32,768 B

    const int* row = ei;
    const int* col = ei + E;

    // 1) degrees, counts, D^-1/2, CSR build
    hipMemsetAsync(deg, 0, (size_t)M * sizeof(float), stream);
    hipMemsetAsync(cnt, 0, (size_t)M * sizeof(int), stream);
    hipMemsetAsync(fill, 0, (size_t)M * sizeof(int), stream);
    hipMemsetAsync(slotA + (size_t)30000 * 512, 0, 80 * 512 * sizeof(short), stream);
    hipMemsetAsync(slotA + (size_t)30000 * 1024, 0, 80 * 1024 * sizeof(short), stream);

    deg_cnt_kernel<<<(E + 255) / 256, 256, 0, stream>>>(row, ew, deg, cnt, E);
    dinv_kernel<<<(M + 255) / 256, 256, 0, stream>>>(deg, dinv, M);
    build_rowptr<<<1, 256, 0, stream>>>(cnt, rowptr);
    scatter_edges<<<(E + 255) / 256, 256, 0, stream>>>(row, col, ew, dinv, rowptr, fill,
                                                       ecol, eval, E);

    // 2) conversions: x -> bf16, weights -> transposed bf16 [N][K]
    f32_to_bf16<<<(M * FIN / 4 + 255) / 256, 256, 0, stream>>>(x, xb, M * FIN / 4);
    {
        dim3 b(256);
        transpose_bf16<<<dim3(H1DIM / 32, FIN / 32),  b, 0, stream>>>(W1,  W1t,  FIN,   H1DIM);
        transpose_bf16<<<dim3(H2DIM / 32, H1DIM / 32), b, 0, stream>>>(W2,  W2t,  H1DIM, H2DIM);
        transpose_bf16<<<dim3(H3DIM / 32, H2DIM / 32), b, 0, stream>>>(W3,  W3t,  H2DIM, H3DIM);
        transpose_bf16<<<dim3(HDIM / 32,  H3DIM / 32), b, 0, stream>>>(Wmu, Wmut, H3DIM, HDIM);
        transpose_bf16<<<dim3(HDIM / 32,  H3DIM / 32), b, 0, stream>>>(Wlv, Wlvt, H3DIM, HDIM);
    }

    const int SPMM_GRID = (M + 3) / 4;
    const int GY = (M + 127) / 128;       // 235

    // 3) layer 1
    spmm_bf16<512, false><<<SPMM_GRID, 256, 0, stream>>>(rowptr, ecol, eval, dinv, xb,
                                                         nullptr, slotA);
    gemm_bf16<short, true><<<dim3(H1DIM / 128, GY), 256, 0, stream>>>(slotA, W1t, b1,
                                                                      slotB, M, H1DIM, FIN);
    l2norm_relu_1024<<<SPMM_GRID, 256, 0, stream>>>(slotB, slotA);

    // 4) layer 2
    gemm_bf16<short, false><<<dim3(H2DIM / 128, GY), 256, 0, stream>>>(slotA, W2t, nullptr,
                                                                       slotB, M, H2DIM, H1DIM);
    hipMemsetAsync(slotA + (size_t)30000 * 512, 0, 80 * 512 * sizeof(short), stream);
    spmm_bf16<512, true><<<SPMM_GRID, 256, 0, stream>>>(rowptr, ecol, eval, dinv, slotB,
                                                        b2, slotA);

    // 5) layer 3
    gemm_bf16<short, false><<<dim3(H3DIM / 128, GY), 256, 0, stream>>>(slotA, W3t, nullptr,
                                                                       slotB, M, H3DIM, H2DIM);
    hipMemsetAsync(slotA + (size_t)30000 * 256, 0, 80 * 256 * sizeof(short), stream);
    spmm_bf16<256, true><<<SPMM_GRID, 256, 0, stream>>>(rowptr, ecol, eval, dinv, slotB,
                                                        b3, slotA);

    // 6) mu / logvar (fp32 out to d_out)
    gemm_bf16<float, true><<<dim3(HDIM / 128, GY), 256, 0, stream>>>(slotA, Wmut, bmu,
                                                                     mu_out, M, HDIM, H3DIM);
    gemm_bf16<float, true><<<dim3(HDIM / 128, GY), 256, 0, stream>>>(slotA, Wlvt, blv,
                                                                     lv_out, M, HDIM, H3DIM);

    // 7) pooling with JAX-exact reparameterization noise (3-stage tree)
    pool_partial<<<PP_BLOCKS, 256, 0, stream>>>(mu_out, lv_out, beta, pmax, psum);
    pool_mid<<<PM_BLOCKS, 256, 0, stream>>>(pmax, psum, pmax2, psum2);
    pool_final<<<2, 256, 0, stream>>>(pmax2, psum2, pooled);

    // 8) decoder (split-K)
    dense_partial<<<dim3(4, 8), 256, 0, stream>>>(pooled, Wd1, dpart);
    dense_final<<<4, 256, 0, stream>>>(dpart, bd1, hdec, 0);
    dense_partial<<<dim3(4, 8), 256, 0, stream>>>(hdec, Wd2, dpart);
    dense_final<<<4, 256, 0, stream>>>(dpart, bd2, out, 1);
}

// Round 5
// 577.567 us; speedup vs baseline: 4.9731x; 1.0809x over previous
//
#include <hip/hip_runtime.h>
#include <cstdint>
#include <cstddef>

// ---------------- problem constants ----------------
#define NNODE      30000
#define MPAD       30080        // 235 * 128
#define FIN        512
#define H1DIM      1024
#define H2DIM      512
#define H3DIM      256
#define HDIM       512          // mu/logvar width
#define HALF_ROWS  15000
#define HALF_ELEMS 7680000u     // 15000*512 (threefry pair offset)
#define PP_ROWS    16
#define PP_BLOCKS  938          // ceil(15000/16)
#define PM_BLOCKS  64           // mid-reduce blocks (15 pp-blocks each)
#define MPANELS    240          // 235 M-panels padded to 8-multiple for XCD grouping

typedef __attribute__((ext_vector_type(8))) short s16x8;
typedef __attribute__((ext_vector_type(4))) short s16x4;
typedef __attribute__((ext_vector_type(4))) float f32x4;

// bf16 <-> f32 (RNE, matches JAX/torch)
__device__ __forceinline__ short f2bf(float f) {
    uint32_t u = __float_as_uint(f);
    uint32_t r = (u + 0x7FFFu + ((u >> 16) & 1u)) >> 16;
    return (short)r;
}
__device__ __forceinline__ float bf2f(short s) {
    return __uint_as_float(((uint32_t)(uint16_t)s) << 16);
}

// ---------------- threefry2x32 (JAX-exact) ----------------
__device__ __forceinline__ void threefry2x32(uint32_t k0, uint32_t k1,
                                             uint32_t& x0, uint32_t& x1) {
    uint32_t ks0 = k0, ks1 = k1, ks2 = k0 ^ k1 ^ 0x1BD11BDAu;
    const uint32_t R0[4] = {13u, 15u, 26u, 6u};
    const uint32_t R1[4] = {17u, 29u, 16u, 24u};
    x0 += ks0; x1 += ks1;
#pragma unroll
    for (int g = 0; g < 5; ++g) {
        const uint32_t* R = (g & 1) ? R1 : R0;
#pragma unroll
        for (int r = 0; r < 4; ++r) {
            x0 += x1;
            x1 = (x1 << R[r]) | (x1 >> (32u - R[r]));
            x1 ^= x0;
        }
        uint32_t ks_a = (g % 3 == 0) ? ks1 : (g % 3 == 1 ? ks2 : ks0);
        uint32_t ks_b = (g % 3 == 0) ? ks2 : (g % 3 == 1 ? ks0 : ks1);
        x0 += ks_a;
        x1 += ks_b + (uint32_t)(g + 1);
    }
}

__device__ __forceinline__ float jax_normal(uint32_t bits) {
    uint32_t fb = (bits >> 9) | 0x3F800000u;
    float f = __uint_as_float(fb) - 1.0f;
    const float lo = -0.99999994f;
    float u = fmaf(f, 2.0f, lo);
    u = fmaxf(u, lo);
    return 1.41421356237f * erfinvf(u);
}

// ---------------- degree + count ----------------
__global__ void deg_cnt_kernel(const int* __restrict__ row, const float* __restrict__ w,
                               float* __restrict__ deg, int* __restrict__ cnt, int E) {
    int e = blockIdx.x * 256 + threadIdx.x;
    if (e < E) {
        int r = row[e];
        atomicAdd(&deg[r], w[e]);
        atomicAdd(&cnt[r], 1);
    }
}

__global__ void dinv_kernel(const float* __restrict__ deg, float* __restrict__ dinv, int n) {
    int i = blockIdx.x * 256 + threadIdx.x;
    if (i < n) dinv[i] = rsqrtf(deg[i] + 1.0f);
}

// ---------------- single-block exclusive scan -> rowptr ----------------
__global__ __launch_bounds__(256) void build_rowptr(const int* __restrict__ cnt,
                                                    int* __restrict__ rowptr) {
    __shared__ int sums[256];
    const int ROWS_PT = 118;
    int t = threadIdx.x;
    int base = t * ROWS_PT;
    int local = 0;
    for (int i = 0; i < ROWS_PT; ++i) {
        int r = base + i;
        if (r < NNODE) local += cnt[r];
    }
    sums[t] = local;
    __syncthreads();
    for (int o = 1; o < 256; o <<= 1) {
        int v = (t >= o) ? sums[t - o] : 0;
        __syncthreads();
        sums[t] += v;
        __syncthreads();
    }
    int off = (t == 0) ? 0 : sums[t - 1];
    for (int i = 0; i < ROWS_PT; ++i) {
        int r = base + i;
        if (r < NNODE) { rowptr[r] = off; off += cnt[r]; }
    }
    if (t == 255) rowptr[NNODE] = off;
}

// ---------------- scatter edges into CSR with pre-normalized weights ----------------
__global__ void scatter_edges(const int* __restrict__ row, const int* __restrict__ col,
                              const float* __restrict__ w, const float* __restrict__ dinv,
                              const int* __restrict__ rowptr, int* __restrict__ fill,
                              int* __restrict__ ecol, float* __restrict__ eval, int E) {
    int e = blockIdx.x * 256 + threadIdx.x;
    if (e < E) {
        int r = row[e], c = col[e];
        int pos = rowptr[r] + atomicAdd(&fill[r], 1);
        ecol[pos] = c;
        eval[pos] = dinv[r] * w[e] * dinv[c];
    }
}

// ---------------- fp32 -> bf16 elementwise (float4 granularity) ----------------
__global__ void f32_to_bf16(const float* __restrict__ in, short* __restrict__ out, int n4) {
    int i = blockIdx.x * 256 + threadIdx.x;
    if (i < n4) {
        float4 v = ((const float4*)in)[i];
        s16x4 s = { f2bf(v.x), f2bf(v.y), f2bf(v.z), f2bf(v.w) };
        *(s16x4*)(out + (size_t)i * 4) = s;
    }
}

// ---------------- transpose + convert: Wt[n][k] = bf16(W[k][n]) ----------------
__global__ __launch_bounds__(256) void transpose_bf16(const float* __restrict__ W,
                                                      short* __restrict__ Wt, int K, int N) {
    __shared__ float t[32][33];
    int kb = blockIdx.y * 32, nb = blockIdx.x * 32;
    int tx = threadIdx.x & 31, ty = threadIdx.x >> 5;     // 32 x 8
#pragma unroll
    for (int i = 0; i < 32; i += 8)
        if (kb + ty + i < K && nb + tx < N)
            t[ty + i][tx] = W[(size_t)(kb + ty + i) * N + nb + tx];
    __syncthreads();
#pragma unroll
    for (int i = 0; i < 32; i += 8)
        if (nb + ty + i < N && kb + tx < K)
            Wt[(size_t)(nb + ty + i) * K + kb + tx] = f2bf(t[tx][ty + i]);
}

// ---------------- CSR SpMM on bf16 rows, optional fused bias+L2norm+ReLU ----------------
template <int F, bool FUSE>
__global__ __launch_bounds__(256) void spmm_bf16(const int* __restrict__ rowptr,
                                                 const int* __restrict__ ecol,
                                                 const float* __restrict__ eval,
                                                 const float* __restrict__ dinv,
                                                 const short* __restrict__ h,
                                                 const float* __restrict__ bias,
                                                 short* __restrict__ out) {
    constexpr int NE = F / 64;               // 512->8, 256->4
    int lane = threadIdx.x & 63;
    int r = blockIdx.x * 4 + (threadIdx.x >> 6);
    if (r >= NNODE) return;
    float d = dinv[r];
    float dd = d * d;
    float acc[NE];
    {
        const short* p = h + (size_t)r * F + lane * NE;
        if constexpr (NE == 8) {
            s16x8 v = *(const s16x8*)p;
#pragma unroll
            for (int j = 0; j < 8; ++j) acc[j] = dd * bf2f(v[j]);
        } else {
            s16x4 v = *(const s16x4*)p;
#pragma unroll
            for (int j = 0; j < 4; ++j) acc[j] = dd * bf2f(v[j]);
        }
    }
    int e0 = rowptr[r], e1 = rowptr[r + 1];
    for (int e = e0; e < e1; ++e) {
        int c = ecol[e];
        float nw = eval[e];
        const short* p = h + (size_t)c * F + lane * NE;
        if constexpr (NE == 8) {
            s16x8 v = *(const s16x8*)p;
#pragma unroll
            for (int j = 0; j < 8; ++j) acc[j] = fmaf(nw, bf2f(v[j]), acc[j]);
        } else {
            s16x4 v = *(const s16x4*)p;
#pragma unroll
            for (int j = 0; j < 4; ++j) acc[j] = fmaf(nw, bf2f(v[j]), acc[j]);
        }
    }
    short* o = out + (size_t)r * F + lane * NE;
    if (FUSE) {
        const float* bp = bias + lane * NE;
        float ss = 0.f;
#pragma unroll
        for (int j = 0; j < NE; ++j) { acc[j] += bp[j]; ss += acc[j] * acc[j]; }
#pragma unroll
        for (int off = 32; off; off >>= 1) ss += __shfl_xor(ss, off);
        float rinv = 1.0f / fmaxf(sqrtf(ss), 1e-12f);
#pragma unroll
        for (int j = 0; j < NE; ++j) acc[j] = fmaxf(acc[j] * rinv, 0.f);
    }
    if constexpr (NE == 8) {
        s16x8 s;
#pragma unroll
        for (int j = 0; j < 8; ++j) s[j] = f2bf(acc[j]);
        *(s16x8*)o = s;
    } else {
        s16x4 s;
#pragma unroll
        for (int j = 0; j < 4; ++j) s[j] = f2bf(acc[j]);
        *(s16x4*)o = s;
    }
}

// ---------------- L2norm+ReLU for F=1024 bf16 (wave per row) ----------------
__global__ __launch_bounds__(256) void l2norm_relu_1024(const short* __restrict__ in,
                                                        short* __restrict__ out) {
    int lane = threadIdx.x & 63;
    int r = blockIdx.x * 4 + (threadIdx.x >> 6);
    if (r >= NNODE) return;
    const s16x8* p = (const s16x8*)(in + (size_t)r * 1024);
    s16x8 v0 = p[lane], v1 = p[lane + 64];
    float f0[8], f1[8];
    float ss = 0.f;
#pragma unroll
    for (int j = 0; j < 8; ++j) {
        f0[j] = bf2f(v0[j]); ss += f0[j] * f0[j];
        f1[j] = bf2f(v1[j]); ss += f1[j] * f1[j];
    }
#pragma unroll
    for (int off = 32; off; off >>= 1) ss += __shfl_xor(ss, off);
    float rinv = 1.0f / fmaxf(sqrtf(ss), 1e-12f);
    s16x8 o0, o1;
#pragma unroll
    for (int j = 0; j < 8; ++j) {
        o0[j] = f2bf(fmaxf(f0[j] * rinv, 0.f));
        o1[j] = f2bf(fmaxf(f1[j] * rinv, 0.f));
    }
    s16x8* q = (s16x8*)(out + (size_t)r * 1024);
    q[lane] = o0;
    q[lane + 64] = o1;
}

// ---------------- bf16 MFMA GEMM: C[M][N] = A[Mpad][K] * Bt[N][K]^T (+bias) ----------------
// 128x128 tile, BK=64, 4 waves x (64x64), global_load_lds w16.
// T2 LDS swizzle (rule #21): linear LDS dest + inverse-swizzled global source + swizzled read.
//   phys 16B slot p of row r holds logical slot p ^ (r&7)  (involution).
// XCD-grouping grid swizzle: all nx N-blocks of one M-panel share wgid%8 -> one XCD's L2
//   holds the 128KB A-panel once (cuts A re-fetch ~nx-fold).
template <typename OutT, bool ADD_BIAS>
__global__ __launch_bounds__(256) void gemm_bf16(const short* __restrict__ A,
                                                 const short* __restrict__ Bt,
                                                 const float* __restrict__ bias,
                                                 OutT* __restrict__ C,
                                                 int M, int N, int K) {
    __shared__ short sA[128 * 64];
    __shared__ short sB[128 * 64];
    const int tid = threadIdx.x;
    const int lane = tid & 63;
    const int w = tid >> 6;                 // wave 0..3
    const int wm = w >> 1, wn = w & 1;      // 2x2 wave grid, 64x64 each

    // ---- grid decode (XCD grouping): wgid = (pid%8) + 8*(c + nx*(pid/8)) ----
    const int nx = N >> 7;                  // 8/4/2 (power of two)
    const int lg = __builtin_ctz(nx);
    const int lin = blockIdx.x;
    const int low = lin & 7;
    const int t = lin >> 3;
    const int cblk = t & (nx - 1);
    const int pid = ((t >> lg) << 3) + low; // M-panel 0..239
    const int m0 = pid << 7;
    if (m0 >= M) return;                    // padded panels exit
    const int n0 = cblk << 7;

    const int srow = lane >> 3;             // 0..7
    // T2: source pre-swizzle; row&7 == srow for this chunk layout
    const int scol = ((lane & 7) ^ srow) * 8;   // bf16 elems within 64-wide K chunk

    f32x4 acc[4][4] = {};

    const int lrow = lane & 15;
    const int jhi = lane >> 4;              // 0..3

    const int nkt = K >> 6;
    for (int kt = 0; kt < nkt; ++kt) {
        const int k0 = kt << 6;
#pragma unroll
        for (int i = 0; i < 4; ++i) {
            int c = i * 4 + w;
            int tr = c * 8 + srow;
            __builtin_amdgcn_global_load_lds(
                (const __attribute__((address_space(1))) void*)(A + (size_t)(m0 + tr) * K + k0 + scol),
                (__attribute__((address_space(3))) void*)(sA + c * 512),
                16, 0, 0);
        }
#pragma unroll
        for (int i = 0; i < 4; ++i) {
            int c = i * 4 + w;
            int tr = c * 8 + srow;
            __builtin_amdgcn_global_load_lds(
                (const __attribute__((address_space(1))) void*)(Bt + (size_t)(n0 + tr) * K + k0 + scol),
                (__attribute__((address_space(3))) void*)(sB + c * 512),
                16, 0, 0);
        }
        __syncthreads();

        s16x8 af[4][2], bfr[4][2];
#pragma unroll
        for (int fm = 0; fm < 4; ++fm) {
            int lr = wm * 64 + fm * 16 + lrow;
            const short* base = &sA[lr * 64];
            int sl0 = jhi ^ (lr & 7);
            af[fm][0] = *(const s16x8*)&base[sl0 << 3];
            af[fm][1] = *(const s16x8*)&base[(sl0 ^ 4) << 3];
        }
#pragma unroll
        for (int fn = 0; fn < 4; ++fn) {
            int lr = wn * 64 + fn * 16 + lrow;
            const short* base = &sB[lr * 64];
            int sl0 = jhi ^ (lr & 7);
            bfr[fn][0] = *(const s16x8*)&base[sl0 << 3];
            bfr[fn][1] = *(const s16x8*)&base[(sl0 ^ 4) << 3];
        }
#pragma unroll
        for (int fm = 0; fm < 4; ++fm)
#pragma unroll
            for (int fn = 0; fn < 4; ++fn) {
                acc[fm][fn] = __builtin_amdgcn_mfma_f32_16x16x32_bf16(af[fm][0], bfr[fn][0], acc[fm][fn], 0, 0, 0);
                acc[fm][fn] = __builtin_amdgcn_mfma_f32_16x16x32_bf16(af[fm][1], bfr[fn][1], acc[fm][fn], 0, 0, 0);
            }
        __syncthreads();
    }

    const int crow = (lane >> 4) * 4;
    const int ccol = lane & 15;
#pragma unroll
    for (int fm = 0; fm < 4; ++fm) {
#pragma unroll
        for (int fn = 0; fn < 4; ++fn) {
            int n = n0 + wn * 64 + fn * 16 + ccol;
            float b = ADD_BIAS ? bias[n] : 0.f;
#pragma unroll
            for (int r = 0; r < 4; ++r) {
                int m = m0 + wm * 64 + fm * 16 + crow + r;
                if (m < M) {
                    float o = acc[fm][fn][r] + b;
                    if constexpr (sizeof(OutT) == 2) C[(size_t)m * N + n] = (OutT)f2bf(o);
                    else                             C[(size_t)m * N + n] = o;
                }
            }
        }
    }
}

// ---------------- pooling stage 1: 938 blocks x 16 row-pairs ----------------
__global__ __launch_bounds__(256) void pool_partial(const float* __restrict__ mu,
                                                    const float* __restrict__ lv,
                                                    const uint32_t* __restrict__ beta_p,
                                                    float* __restrict__ pmax,
                                                    float* __restrict__ psum) {
    uint32_t bb = beta_p[0];
    float beta = (bb & 0x7F800000u) ? __uint_as_float(bb) : (float)(int)bb;
    int b = blockIdx.x;
    int r0 = b * PP_ROWS;
    int r1 = min(r0 + PP_ROWS, HALF_ROWS);
    int c = threadIdx.x * 2;
    float m0 = -INFINITY, m1 = -INFINITY, s0 = 0.f, s1 = 0.f;
    for (int r = r0; r < r1; ++r) {
        size_t ia = (size_t)r * HDIM + c;
        size_t ib = (size_t)(r + HALF_ROWS) * HDIM + c;
        float2 mua = *(const float2*)&mu[ia];
        float2 lva = *(const float2*)&lv[ia];
        float2 mub = *(const float2*)&mu[ib];
        float2 lvb = *(const float2*)&lv[ib];
        uint32_t idx0 = (uint32_t)r * 512u + (uint32_t)c;
        uint32_t xa0 = idx0,     ya0 = idx0 + HALF_ELEMS;
        uint32_t xa1 = idx0 + 1, ya1 = idx0 + 1 + HALF_ELEMS;
        threefry2x32(0u, 42u, xa0, ya0);
        threefry2x32(0u, 42u, xa1, ya1);
        float za0 = mua.x + 0.01f * jax_normal(xa0) * __expf(0.5f * beta * lva.x);
        float zb0 = mub.x + 0.01f * jax_normal(ya0) * __expf(0.5f * beta * lvb.x);
        float za1 = mua.y + 0.01f * jax_normal(xa1) * __expf(0.5f * beta * lva.y);
        float zb1 = mub.y + 0.01f * jax_normal(ya1) * __expf(0.5f * beta * lvb.y);
        m0 = fmaxf(m0, fmaxf(za0, zb0)); s0 += za0 + zb0;
        m1 = fmaxf(m1, fmaxf(za1, zb1)); s1 += za1 + zb1;
    }
    pmax[(size_t)b * HDIM + c]     = m0;
    pmax[(size_t)b * HDIM + c + 1] = m1;
    psum[(size_t)b * HDIM + c]     = s0;
    psum[(size_t)b * HDIM + c + 1] = s1;
}

// ---------------- pooling stage 2: 938 -> 64 partials ----------------
__global__ __launch_bounds__(256) void pool_mid(const float* __restrict__ pmax,
                                                const float* __restrict__ psum,
                                                float* __restrict__ pmax2,
                                                float* __restrict__ psum2) {
    int g = blockIdx.x;
    int b0 = g * 15;
    int b1 = min(b0 + 15, PP_BLOCKS);
#pragma unroll
    for (int pass = 0; pass < 2; ++pass) {
        int c = threadIdx.x + pass * 256;
        float m = -INFINITY, s = 0.f;
        for (int b = b0; b < b1; ++b) {
            m = fmaxf(m, pmax[(size_t)b * HDIM + c]);
            s += psum[(size_t)b * HDIM + c];
        }
        pmax2[(size_t)g * HDIM + c] = m;
        psum2[(size_t)g * HDIM + c] = s;
    }
}

// ---------------- pooling stage 3: 64 -> pooled[1024] ----------------
__global__ void pool_final(const float* __restrict__ pmax2, const float* __restrict__ psum2,
                           float* __restrict__ pooled) {
    int c = blockIdx.x * 256 + threadIdx.x;
    if (c < HDIM) {
        float m = -INFINITY, s = 0.f;
#pragma unroll
        for (int b = 0; b < PM_BLOCKS; ++b) {
            m = fmaxf(m, pmax2[(size_t)b * HDIM + c]);
            s += psum2[(size_t)b * HDIM + c];
        }
        pooled[c] = m;
        pooled[HDIM + c] = s / 30000.0f;
    }
}

// ---------------- decoder: split-K partial + finalize ----------------
__global__ __launch_bounds__(256) void dense_partial(const float* __restrict__ in,
                                                     const float* __restrict__ W,
                                                     float* __restrict__ part) {
    int by = blockIdx.y;                           // k-slice 0..7 (128 rows each)
    int j = blockIdx.x * 256 + threadIdx.x;        // 0..1023
    __shared__ float sin_[128];
    if (threadIdx.x < 128) sin_[threadIdx.x] = in[by * 128 + threadIdx.x];
    __syncthreads();
    float acc = 0.f;
#pragma unroll 8
    for (int i = 0; i < 128; ++i)
        acc = fmaf(sin_[i], W[(size_t)(by * 128 + i) * 1024 + j], acc);
    part[(size_t)by * 1024 + j] = acc;
}

__global__ void dense_final(const float* __restrict__ part, const float* __restrict__ bias,
                            float* __restrict__ out, int act) {
    int j = blockIdx.x * 256 + threadIdx.x;
    float acc = bias[j];
#pragma unroll
    for (int s = 0; s < 8; ++s) acc += part[(size_t)s * 1024 + j];
    out[j] = act ? (1.0f / (1.0f + __expf(-acc))) : fmaxf(acc, 0.f);
}

// ---------------- launch ----------------
extern "C" void kernel_launch(void* const* d_in, const int* in_sizes, int n_in,
                              void* d_out, int out_size, void* d_ws, size_t ws_size,
                              hipStream_t stream) {
    const float* x   = (const float*)d_in[0];
    const int*   ei  = (const int*)d_in[1];
    const float* ew  = (const float*)d_in[2];
    const uint32_t* beta = (const uint32_t*)d_in[3];
    const float* W1  = (const float*)d_in[4];
    const float* b1  = (const float*)d_in[5];
    const float* W2  = (const float*)d_in[6];
    const float* b2  = (const float*)d_in[7];
    const float* W3  = (const float*)d_in[8];
    const float* b3  = (const float*)d_in[9];
    const float* Wmu = (const float*)d_in[10];
    const float* bmu = (const float*)d_in[11];
    const float* Wlv = (const float*)d_in[12];
    const float* blv = (const float*)d_in[13];
    const float* Wd1 = (const float*)d_in[14];
    const float* bd1 = (const float*)d_in[15];
    const float* Wd2 = (const float*)d_in[16];
    const float* bd2 = (const float*)d_in[17];

    const int E = in_sizes[2];            // 300000
    const int M = NNODE;

    float* out    = (float*)d_out;
    float* mu_out = out + 1024;                           // [30000,512]
    float* lv_out = out + 1024 + (size_t)M * HDIM;        // [30000,512]

    // ---------------- workspace layout (bytes) ----------------
    char* Wp = (char*)d_ws;
    short* slotA  = (short*)(Wp);                         // 61,603,840 B (30080x1024 bf16 max)
    short* slotB  = (short*)(Wp + 61603840);              // 61,603,840 B
    short* xb     = (short*)(Wp + 123207680);             // 30,720,000 B
    short* W1t    = (short*)(Wp + 154009600);
    short* W2t    = (short*)(Wp + 155058176);
    short* W3t    = (short*)(Wp + 156106752);
    short* Wmut   = (short*)(Wp + 156368896);
    short* Wlvt   = (short*)(Wp + 156631040);
    float* deg    = (float*)(Wp + 156893184);
    float* dinv   = (float*)(Wp + 157013184);
    int*   cnt    = (int*)  (Wp + 157133184);
    int*   fill   = (int*)  (Wp + 157253184);
    int*   rowptr = (int*)  (Wp + 157373184);
    int*   ecol   = (int*)  (Wp + 157493188);
    float* eval   = (float*)(Wp + 158693188);
    float* pmax   = (float*)(Wp + 159893188);             // 938*512 = 1,921,024 B
    float* psum   = (float*)(Wp + 161814212);             // 1,921,024 B
    float* pmax2  = (float*)(Wp + 163735236);             // 131,072 B
    float* psum2  = (float*)(Wp + 163866308);             // 131,072 B
    float* pooled = (float*)(Wp + 163997380);             // 4,096 B
    float* hdec   = (float*)(Wp + 164001476);             // 4,096 B
    float* dpart  = (float*)(Wp + 164005572);             // 32,768 B

    const int* row = ei;
    const int* col = ei + E;

    // 1) degrees, counts, D^-1/2, CSR build
    hipMemsetAsync(deg, 0, (size_t)M * sizeof(float), stream);
    hipMemsetAsync(cnt, 0, (size_t)M * sizeof(int), stream);
    hipMemsetAsync(fill, 0, (size_t)M * sizeof(int), stream);
    hipMemsetAsync(slotA + (size_t)30000 * 512, 0, 80 * 512 * sizeof(short), stream);
    hipMemsetAsync(slotA + (size_t)30000 * 1024, 0, 80 * 1024 * sizeof(short), stream);

    deg_cnt_kernel<<<(E + 255) / 256, 256, 0, stream>>>(row, ew, deg, cnt, E);
    dinv_kernel<<<(M + 255) / 256, 256, 0, stream>>>(deg, dinv, M);
    build_rowptr<<<1, 256, 0, stream>>>(cnt, rowptr);
    scatter_edges<<<(E + 255) / 256, 256, 0, stream>>>(row, col, ew, dinv, rowptr, fill,
                                                       ecol, eval, E);

    // 2) conversions: x -> bf16, weights -> transposed bf16 [N][K]
    f32_to_bf16<<<(M * FIN / 4 + 255) / 256, 256, 0, stream>>>(x, xb, M * FIN / 4);
    {
        dim3 b(256);
        transpose_bf16<<<dim3(H1DIM / 32, FIN / 32),  b, 0, stream>>>(W1,  W1t,  FIN,   H1DIM);
        transpose_bf16<<<dim3(H2DIM / 32, H1DIM / 32), b, 0, stream>>>(W2,  W2t,  H1DIM, H2DIM);
        transpose_bf16<<<dim3(H3DIM / 32, H2DIM / 32), b, 0, stream>>>(W3,  W3t,  H2DIM, H3DIM);
        transpose_bf16<<<dim3(HDIM / 32,  H3DIM / 32), b, 0, stream>>>(Wmu, Wmut, H3DIM, HDIM);
        transpose_bf16<<<dim3(HDIM / 32,  H3DIM / 32), b, 0, stream>>>(Wlv, Wlvt, H3DIM, HDIM);
    }

    const int SPMM_GRID = (M + 3) / 4;

    // 3) layer 1
    spmm_bf16<512, false><<<SPMM_GRID, 256, 0, stream>>>(rowptr, ecol, eval, dinv, xb,
                                                         nullptr, slotA);
    gemm_bf16<short, true><<<(H1DIM / 128) * MPANELS, 256, 0, stream>>>(slotA, W1t, b1,
                                                                        slotB, M, H1DIM, FIN);
    l2norm_relu_1024<<<SPMM_GRID, 256, 0, stream>>>(slotB, slotA);

    // 4) layer 2
    gemm_bf16<short, false><<<(H2DIM / 128) * MPANELS, 256, 0, stream>>>(slotA, W2t, nullptr,
                                                                         slotB, M, H2DIM, H1DIM);
    hipMemsetAsync(slotA + (size_t)30000 * 512, 0, 80 * 512 * sizeof(short), stream);
    spmm_bf16<512, true><<<SPMM_GRID, 256, 0, stream>>>(rowptr, ecol, eval, dinv, slotB,
                                                        b2, slotA);

    // 5) layer 3
    gemm_bf16<short, false><<<(H3DIM / 128) * MPANELS, 256, 0, stream>>>(slotA, W3t, nullptr,
                                                                         slotB, M, H3DIM, H2DIM);
    hipMemsetAsync(slotA + (size_t)30000 * 256, 0, 80 * 256 * sizeof(short), stream);
    spmm_bf16<256, true><<<SPMM_GRID, 256, 0, stream>>>(rowptr, ecol, eval, dinv, slotB,
                                                        b3, slotA);

    // 6) mu / logvar (fp32 out to d_out)
    gemm_bf16<float, true><<<(HDIM / 128) * MPANELS, 256, 0, stream>>>(slotA, Wmut, bmu,
                                                                       mu_out, M, HDIM, H3DIM);
    gemm_bf16<float, true><<<(HDIM / 128) * MPANELS, 256, 0, stream>>>(slotA, Wlvt, blv,
                                                                       lv_out, M, HDIM, H3DIM);

    // 7) pooling with JAX-exact reparameterization noise (3-stage tree)
    pool_partial<<<PP_BLOCKS, 256, 0, stream>>>(mu_out, lv_out, beta, pmax, psum);
    pool_mid<<<PM_BLOCKS, 256, 0, stream>>>(pmax, psum, pmax2, psum2);
    pool_final<<<2, 256, 0, stream>>>(pmax2, psum2, pooled);

    // 8) decoder (split-K)
    dense_partial<<<dim3(4, 8), 256, 0, stream>>>(pooled, Wd1, dpart);
    dense_final<<<4, 256, 0, stream>>>(dpart, bd1, hdec, 0);
    dense_partial<<<dim3(4, 8), 256, 0, stream>>>(hdec, Wd2, dpart);
    dense_final<<<4, 256, 0, stream>>>(dpart, bd2, out, 1);
}

// Round 7
// 532.753 us; speedup vs baseline: 5.3914x; 1.0841x over previous
//
#include <hip/hip_runtime.h>
#include <cstdint>
#include <cstddef>

// ---------------- problem constants ----------------
#define NNODE      30000
#define FIN        512
#define H1DIM      1024
#define H2DIM      512
#define H3DIM      256
#define HDIM       512          // mu/logvar width
#define HALF_ROWS  15000
#define HALF_ELEMS 7680000u     // 15000*512 (threefry pair offset)
#define PP_ROWS    16
#define PP_BLOCKS  938          // ceil(15000/16)
#define PM_BLOCKS  64           // mid-reduce blocks (15 pp-blocks each)
#define MPANELS    240          // 235 M-panels padded to 8-multiple for XCD grouping

typedef __attribute__((ext_vector_type(8))) short s16x8;
typedef __attribute__((ext_vector_type(4))) short s16x4;
typedef __attribute__((ext_vector_type(4))) float f32x4;

// bf16 <-> f32 (RNE, matches JAX/torch)
__device__ __forceinline__ short f2bf(float f) {
    uint32_t u = __float_as_uint(f);
    uint32_t r = (u + 0x7FFFu + ((u >> 16) & 1u)) >> 16;
    return (short)r;
}
__device__ __forceinline__ float bf2f(short s) {
    return __uint_as_float(((uint32_t)(uint16_t)s) << 16);
}

// ---------------- threefry2x32 (JAX-exact) ----------------
__device__ __forceinline__ void threefry2x32(uint32_t k0, uint32_t k1,
                                             uint32_t& x0, uint32_t& x1) {
    uint32_t ks0 = k0, ks1 = k1, ks2 = k0 ^ k1 ^ 0x1BD11BDAu;
    const uint32_t R0[4] = {13u, 15u, 26u, 6u};
    const uint32_t R1[4] = {17u, 29u, 16u, 24u};
    x0 += ks0; x1 += ks1;
#pragma unroll
    for (int g = 0; g < 5; ++g) {
        const uint32_t* R = (g & 1) ? R1 : R0;
#pragma unroll
        for (int r = 0; r < 4; ++r) {
            x0 += x1;
            x1 = (x1 << R[r]) | (x1 >> (32u - R[r]));
            x1 ^= x0;
        }
        uint32_t ks_a = (g % 3 == 0) ? ks1 : (g % 3 == 1 ? ks2 : ks0);
        uint32_t ks_b = (g % 3 == 0) ? ks2 : (g % 3 == 1 ? ks0 : ks1);
        x0 += ks_a;
        x1 += ks_b + (uint32_t)(g + 1);
    }
}

__device__ __forceinline__ float jax_normal(uint32_t bits) {
    uint32_t fb = (bits >> 9) | 0x3F800000u;
    float f = __uint_as_float(fb) - 1.0f;
    const float lo = -0.99999994f;
    float u = fmaf(f, 2.0f, lo);
    u = fmaxf(u, lo);
    return 1.41421356237f * erfinvf(u);
}

// ---------------- degree + count ----------------
__global__ void deg_cnt_kernel(const int* __restrict__ row, const float* __restrict__ w,
                               float* __restrict__ deg, int* __restrict__ cnt, int E) {
    int e = blockIdx.x * 256 + threadIdx.x;
    if (e < E) {
        int r = row[e];
        atomicAdd(&deg[r], w[e]);
        atomicAdd(&cnt[r], 1);
    }
}

__global__ void dinv_kernel(const float* __restrict__ deg, float* __restrict__ dinv, int n) {
    int i = blockIdx.x * 256 + threadIdx.x;
    if (i < n) dinv[i] = rsqrtf(deg[i] + 1.0f);
}

// rinv[i] = 1/max(sqrt(ss[i]), 1e-12), in place
__global__ void rsqrt_clamp_kernel(float* __restrict__ ss, int n) {
    int i = blockIdx.x * 256 + threadIdx.x;
    if (i < n) ss[i] = 1.0f / fmaxf(sqrtf(ss[i]), 1e-12f);
}

// ---------------- single-block exclusive scan -> rowptr ----------------
__global__ __launch_bounds__(256) void build_rowptr(const int* __restrict__ cnt,
                                                    int* __restrict__ rowptr) {
    __shared__ int sums[256];
    const int ROWS_PT = 118;
    int t = threadIdx.x;
    int base = t * ROWS_PT;
    int local = 0;
    for (int i = 0; i < ROWS_PT; ++i) {
        int r = base + i;
        if (r < NNODE) local += cnt[r];
    }
    sums[t] = local;
    __syncthreads();
    for (int o = 1; o < 256; o <<= 1) {
        int v = (t >= o) ? sums[t - o] : 0;
        __syncthreads();
        sums[t] += v;
        __syncthreads();
    }
    int off = (t == 0) ? 0 : sums[t - 1];
    for (int i = 0; i < ROWS_PT; ++i) {
        int r = base + i;
        if (r < NNODE) { rowptr[r] = off; off += cnt[r]; }
    }
    if (t == 255) rowptr[NNODE] = off;
}

// ---------------- scatter edges into CSR with pre-normalized weights ----------------
__global__ void scatter_edges(const int* __restrict__ row, const int* __restrict__ col,
                              const float* __restrict__ w, const float* __restrict__ dinv,
                              const int* __restrict__ rowptr, int* __restrict__ fill,
                              int* __restrict__ ecol, float* __restrict__ eval, int E) {
    int e = blockIdx.x * 256 + threadIdx.x;
    if (e < E) {
        int r = row[e], c = col[e];
        int pos = rowptr[r] + atomicAdd(&fill[r], 1);
        ecol[pos] = c;
        eval[pos] = dinv[r] * w[e] * dinv[c];
    }
}

// ---------------- fp32 -> bf16 elementwise ----------------
__global__ void f32_to_bf16(const float* __restrict__ in, short* __restrict__ out, int n4) {
    int i = blockIdx.x * 256 + threadIdx.x;
    if (i < n4) {
        float4 v = ((const float4*)in)[i];
        s16x4 s = { f2bf(v.x), f2bf(v.y), f2bf(v.z), f2bf(v.w) };
        *(s16x4*)(out + (size_t)i * 4) = s;
    }
}

// ---------------- transpose + convert: Wt[n][k] = bf16(W[k][n]) ----------------
__global__ __launch_bounds__(256) void transpose_bf16(const float* __restrict__ W,
                                                      short* __restrict__ Wt, int K, int N) {
    __shared__ float t[32][33];
    int kb = blockIdx.y * 32, nb = blockIdx.x * 32;
    int tx = threadIdx.x & 31, ty = threadIdx.x >> 5;     // 32 x 8
#pragma unroll
    for (int i = 0; i < 32; i += 8)
        if (kb + ty + i < K && nb + tx < N)
            t[ty + i][tx] = W[(size_t)(kb + ty + i) * N + nb + tx];
    __syncthreads();
#pragma unroll
    for (int i = 0; i < 32; i += 8)
        if (nb + ty + i < N && kb + tx < K)
            Wt[(size_t)(nb + ty + i) * K + kb + tx] = f2bf(t[tx][ty + i]);
}

// ---------------- CSR SpMM on bf16 rows, optional fused bias+L2norm+ReLU ----------------
// edge loop unrolled 2x: two independent gathers in flight per iteration
template <int F, bool FUSE>
__global__ __launch_bounds__(256) void spmm_bf16(const int* __restrict__ rowptr,
                                                 const int* __restrict__ ecol,
                                                 const float* __restrict__ eval,
                                                 const float* __restrict__ dinv,
                                                 const short* __restrict__ h,
                                                 const float* __restrict__ bias,
                                                 short* __restrict__ out) {
    constexpr int NE = F / 64;               // 512->8, 256->4
    int lane = threadIdx.x & 63;
    int r = blockIdx.x * 4 + (threadIdx.x >> 6);
    if (r >= NNODE) return;
    float d = dinv[r];
    float dd = d * d;
    float acc[NE];
    {
        const short* p = h + (size_t)r * F + lane * NE;
        if constexpr (NE == 8) {
            s16x8 v = *(const s16x8*)p;
#pragma unroll
            for (int j = 0; j < 8; ++j) acc[j] = dd * bf2f(v[j]);
        } else {
            s16x4 v = *(const s16x4*)p;
#pragma unroll
            for (int j = 0; j < 4; ++j) acc[j] = dd * bf2f(v[j]);
        }
    }
    int e0 = rowptr[r], e1 = rowptr[r + 1];
    int e = e0;
    for (; e + 2 <= e1; e += 2) {
        int c0 = ecol[e], c1 = ecol[e + 1];
        float w0 = eval[e], w1 = eval[e + 1];
        const short* p0 = h + (size_t)c0 * F + lane * NE;
        const short* p1 = h + (size_t)c1 * F + lane * NE;
        if constexpr (NE == 8) {
            s16x8 v0 = *(const s16x8*)p0;
            s16x8 v1 = *(const s16x8*)p1;
#pragma unroll
            for (int j = 0; j < 8; ++j) acc[j] = fmaf(w0, bf2f(v0[j]), acc[j]);
#pragma unroll
            for (int j = 0; j < 8; ++j) acc[j] = fmaf(w1, bf2f(v1[j]), acc[j]);
        } else {
            s16x4 v0 = *(const s16x4*)p0;
            s16x4 v1 = *(const s16x4*)p1;
#pragma unroll
            for (int j = 0; j < 4; ++j) acc[j] = fmaf(w0, bf2f(v0[j]), acc[j]);
#pragma unroll
            for (int j = 0; j < 4; ++j) acc[j] = fmaf(w1, bf2f(v1[j]), acc[j]);
        }
    }
    if (e < e1) {
        int c = ecol[e];
        float nw = eval[e];
        const short* p = h + (size_t)c * F + lane * NE;
        if constexpr (NE == 8) {
            s16x8 v = *(const s16x8*)p;
#pragma unroll
            for (int j = 0; j < 8; ++j) acc[j] = fmaf(nw, bf2f(v[j]), acc[j]);
        } else {
            s16x4 v = *(const s16x4*)p;
#pragma unroll
            for (int j = 0; j < 4; ++j) acc[j] = fmaf(nw, bf2f(v[j]), acc[j]);
        }
    }
    short* o = out + (size_t)r * F + lane * NE;
    if (FUSE) {
        const float* bp = bias + lane * NE;
        float ss = 0.f;
#pragma unroll
        for (int j = 0; j < NE; ++j) { acc[j] += bp[j]; ss += acc[j] * acc[j]; }
#pragma unroll
        for (int off = 32; off; off >>= 1) ss += __shfl_xor(ss, off);
        float rinv = 1.0f / fmaxf(sqrtf(ss), 1e-12f);
#pragma unroll
        for (int j = 0; j < NE; ++j) acc[j] = fmaxf(acc[j] * rinv, 0.f);
    }
    if constexpr (NE == 8) {
        s16x8 s;
#pragma unroll
        for (int j = 0; j < 8; ++j) s[j] = f2bf(acc[j]);
        *(s16x8*)o = s;
    } else {
        s16x4 s;
#pragma unroll
        for (int j = 0; j < 4; ++j) s[j] = f2bf(acc[j]);
        *(s16x4*)o = s;
    }
}

// ---------------- bf16 MFMA GEMM: C[M][N] = A[Mpad][K] * Bt[N][K]^T ----------------
// 128x128 tile, BK=64, 4 waves x (64x64), global_load_lds w16, T2 LDS swizzle,
// XCD-grouping grid decode.
// EPI modes:
//   0: plain (+optional bias)
//   1: bias + ReLU store (bf16) + fp32 row sum-of-squares atomics into ssbuf
//   2: no bias; scale row m by ssbuf[m] (rinv), bf16 store
//   3: dual output split at N/2: n<N/2 -> C/bias, else C2/bias2 (fp32)
template <typename OutT, bool ADD_BIAS, int EPI>
__global__ __launch_bounds__(256) void gemm_bf16(const short* __restrict__ A,
                                                 const short* __restrict__ Bt,
                                                 const float* __restrict__ bias,
                                                 const float* __restrict__ bias2,
                                                 OutT* __restrict__ C,
                                                 float* __restrict__ C2,
                                                 float* __restrict__ ssbuf,
                                                 int M, int N, int K) {
    __shared__ short sA[128 * 64];
    __shared__ short sB[128 * 64];
    const int tid = threadIdx.x;
    const int lane = tid & 63;
    const int w = tid >> 6;                 // wave 0..3
    const int wm = w >> 1, wn = w & 1;      // 2x2 wave grid, 64x64 each

    // ---- grid decode (XCD grouping): all nx N-blocks of one M-panel share wgid%8 ----
    const int nx = N >> 7;
    const int lg = __builtin_ctz(nx);
    const int lin = blockIdx.x;
    const int low = lin & 7;
    const int t = lin >> 3;
    const int cblk = t & (nx - 1);
    const int pid = ((t >> lg) << 3) + low;
    const int m0 = pid << 7;
    if (m0 >= M) return;
    const int n0 = cblk << 7;

    const int srow = lane >> 3;             // 0..7
    const int scol = ((lane & 7) ^ srow) * 8;   // T2 pre-swizzled source

    f32x4 acc[4][4] = {};

    const int lrow = lane & 15;
    const int jhi = lane >> 4;              // 0..3

    const int nkt = K >> 6;
    for (int kt = 0; kt < nkt; ++kt) {
        const int k0 = kt << 6;
#pragma unroll
        for (int i = 0; i < 4; ++i) {
            int c = i * 4 + w;
            int tr = c * 8 + srow;
            __builtin_amdgcn_global_load_lds(
                (const __attribute__((address_space(1))) void*)(A + (size_t)(m0 + tr) * K + k0 + scol),
                (__attribute__((address_space(3))) void*)(sA + c * 512),
                16, 0, 0);
        }
#pragma unroll
        for (int i = 0; i < 4; ++i) {
            int c = i * 4 + w;
            int tr = c * 8 + srow;
            __builtin_amdgcn_global_load_lds(
                (const __attribute__((address_space(1))) void*)(Bt + (size_t)(n0 + tr) * K + k0 + scol),
                (__attribute__((address_space(3))) void*)(sB + c * 512),
                16, 0, 0);
        }
        __syncthreads();

        s16x8 af[4][2], bfr[4][2];
#pragma unroll
        for (int fm = 0; fm < 4; ++fm) {
            int lr = wm * 64 + fm * 16 + lrow;
            const short* base = &sA[lr * 64];
            int sl0 = jhi ^ (lr & 7);
            af[fm][0] = *(const s16x8*)&base[sl0 << 3];
            af[fm][1] = *(const s16x8*)&base[(sl0 ^ 4) << 3];
        }
#pragma unroll
        for (int fn = 0; fn < 4; ++fn) {
            int lr = wn * 64 + fn * 16 + lrow;
            const short* base = &sB[lr * 64];
            int sl0 = jhi ^ (lr & 7);
            bfr[fn][0] = *(const s16x8*)&base[sl0 << 3];
            bfr[fn][1] = *(const s16x8*)&base[(sl0 ^ 4) << 3];
        }
#pragma unroll
        for (int fm = 0; fm < 4; ++fm)
#pragma unroll
            for (int fn = 0; fn < 4; ++fn) {
                acc[fm][fn] = __builtin_amdgcn_mfma_f32_16x16x32_bf16(af[fm][0], bfr[fn][0], acc[fm][fn], 0, 0, 0);
                acc[fm][fn] = __builtin_amdgcn_mfma_f32_16x16x32_bf16(af[fm][1], bfr[fn][1], acc[fm][fn], 0, 0, 0);
            }
        __syncthreads();
    }

    const int crow = (lane >> 4) * 4;
    const int ccol = lane & 15;

    if constexpr (EPI == 1) {
        // bias + relu store + row sum-of-squares (pre-relu, fp32)
        float ssl[4][4] = {};
#pragma unroll
        for (int fm = 0; fm < 4; ++fm) {
#pragma unroll
            for (int fn = 0; fn < 4; ++fn) {
                int n = n0 + wn * 64 + fn * 16 + ccol;
                float b = bias[n];
#pragma unroll
                for (int r = 0; r < 4; ++r) {
                    float o = acc[fm][fn][r] + b;
                    ssl[fm][r] += o * o;
                    int m = m0 + wm * 64 + fm * 16 + crow + r;
                    if (m < M) C[(size_t)m * N + n] = (OutT)f2bf(fmaxf(o, 0.f));
                }
            }
        }
#pragma unroll
        for (int fm = 0; fm < 4; ++fm)
#pragma unroll
            for (int r = 0; r < 4; ++r) {
                float v = ssl[fm][r];
                v += __shfl_xor(v, 1); v += __shfl_xor(v, 2);
                v += __shfl_xor(v, 4); v += __shfl_xor(v, 8);
                int m = m0 + wm * 64 + fm * 16 + crow + r;
                if (ccol == 0 && m < M) atomicAdd(&ssbuf[m], v);
            }
    } else if constexpr (EPI == 2) {
        // per-row scale (rinv) store
#pragma unroll
        for (int fm = 0; fm < 4; ++fm) {
#pragma unroll
            for (int fn = 0; fn < 4; ++fn) {
                int n = n0 + wn * 64 + fn * 16 + ccol;
#pragma unroll
                for (int r = 0; r < 4; ++r) {
                    int m = m0 + wm * 64 + fm * 16 + crow + r;
                    if (m < M) {
                        float sc = ssbuf[m];
                        C[(size_t)m * N + n] = (OutT)f2bf(acc[fm][fn][r] * sc);
                    }
                }
            }
        }
    } else if constexpr (EPI == 3) {
        // split dual fp32 output at N/2
        const int half = N >> 1;
#pragma unroll
        for (int fm = 0; fm < 4; ++fm) {
#pragma unroll
            for (int fn = 0; fn < 4; ++fn) {
                int n = n0 + wn * 64 + fn * 16 + ccol;
                bool hi = n >= half;
                float b = hi ? bias2[n - half] : bias[n];
                float* Cp = hi ? C2 : (float*)C;
                int nc = hi ? (n - half) : n;
#pragma unroll
                for (int r = 0; r < 4; ++r) {
                    int m = m0 + wm * 64 + fm * 16 + crow + r;
                    if (m < M) Cp[(size_t)m * half + nc] = acc[fm][fn][r] + b;
                }
            }
        }
    } else {
#pragma unroll
        for (int fm = 0; fm < 4; ++fm) {
#pragma unroll
            for (int fn = 0; fn < 4; ++fn) {
                int n = n0 + wn * 64 + fn * 16 + ccol;
                float b = ADD_BIAS ? bias[n] : 0.f;
#pragma unroll
                for (int r = 0; r < 4; ++r) {
                    int m = m0 + wm * 64 + fm * 16 + crow + r;
                    if (m < M) {
                        float o = acc[fm][fn][r] + b;
                        if constexpr (sizeof(OutT) == 2) C[(size_t)m * N + n] = (OutT)f2bf(o);
                        else                             C[(size_t)m * N + n] = o;
                    }
                }
            }
        }
    }
}

// ---------------- pooling stage 1: 938 blocks x 16 row-pairs ----------------
__global__ __launch_bounds__(256) void pool_partial(const float* __restrict__ mu,
                                                    const float* __restrict__ lv,
                                                    const uint32_t* __restrict__ beta_p,
                                                    float* __restrict__ pmax,
                                                    float* __restrict__ psum) {
    uint32_t bb = beta_p[0];
    float beta = (bb & 0x7F800000u) ? __uint_as_float(bb) : (float)(int)bb;
    int b = blockIdx.x;
    int r0 = b * PP_ROWS;
    int r1 = min(r0 + PP_ROWS, HALF_ROWS);
    int c = threadIdx.x * 2;
    float m0 = -INFINITY, m1 = -INFINITY, s0 = 0.f, s1 = 0.f;
    for (int r = r0; r < r1; ++r) {
        size_t ia = (size_t)r * HDIM + c;
        size_t ib = (size_t)(r + HALF_ROWS) * HDIM + c;
        float2 mua = *(const float2*)&mu[ia];
        float2 lva = *(const float2*)&lv[ia];
        float2 mub = *(const float2*)&mu[ib];
        float2 lvb = *(const float2*)&lv[ib];
        uint32_t idx0 = (uint32_t)r * 512u + (uint32_t)c;
        uint32_t xa0 = idx0,     ya0 = idx0 + HALF_ELEMS;
        uint32_t xa1 = idx0 + 1, ya1 = idx0 + 1 + HALF_ELEMS;
        threefry2x32(0u, 42u, xa0, ya0);
        threefry2x32(0u, 42u, xa1, ya1);
        float za0 = mua.x + 0.01f * jax_normal(xa0) * __expf(0.5f * beta * lva.x);
        float zb0 = mub.x + 0.01f * jax_normal(ya0) * __expf(0.5f * beta * lvb.x);
        float za1 = mua.y + 0.01f * jax_normal(xa1) * __expf(0.5f * beta * lva.y);
        float zb1 = mub.y + 0.01f * jax_normal(ya1) * __expf(0.5f * beta * lvb.y);
        m0 = fmaxf(m0, fmaxf(za0, zb0)); s0 += za0 + zb0;
        m1 = fmaxf(m1, fmaxf(za1, zb1)); s1 += za1 + zb1;
    }
    pmax[(size_t)b * HDIM + c]     = m0;
    pmax[(size_t)b * HDIM + c + 1] = m1;
    psum[(size_t)b * HDIM + c]     = s0;
    psum[(size_t)b * HDIM + c + 1] = s1;
}

// ---------------- pooling stage 2: 938 -> 64 partials ----------------
__global__ __launch_bounds__(256) void pool_mid(const float* __restrict__ pmax,
                                                const float* __restrict__ psum,
                                                float* __restrict__ pmax2,
                                                float* __restrict__ psum2) {
    int g = blockIdx.x;
    int b0 = g * 15;
    int b1 = min(b0 + 15, PP_BLOCKS);
#pragma unroll
    for (int pass = 0; pass < 2; ++pass) {
        int c = threadIdx.x + pass * 256;
        float m = -INFINITY, s = 0.f;
        for (int b = b0; b < b1; ++b) {
            m = fmaxf(m, pmax[(size_t)b * HDIM + c]);
            s += psum[(size_t)b * HDIM + c];
        }
        pmax2[(size_t)g * HDIM + c] = m;
        psum2[(size_t)g * HDIM + c] = s;
    }
}

// ---------------- pooling stage 3: 64 -> pooled[1024] ----------------
__global__ void pool_final(const float* __restrict__ pmax2, const float* __restrict__ psum2,
                           float* __restrict__ pooled) {
    int c = blockIdx.x * 256 + threadIdx.x;
    if (c < HDIM) {
        float m = -INFINITY, s = 0.f;
#pragma unroll
        for (int b = 0; b < PM_BLOCKS; ++b) {
            m = fmaxf(m, pmax2[(size_t)b * HDIM + c]);
            s += psum2[(size_t)b * HDIM + c];
        }
        pooled[c] = m;
        pooled[HDIM + c] = s / 30000.0f;
    }
}

// ---------------- decoder: split-K partial + finalize ----------------
__global__ __launch_bounds__(256) void dense_partial(const float* __restrict__ in,
                                                     const float* __restrict__ W,
                                                     float* __restrict__ part) {
    int by = blockIdx.y;                           // k-slice 0..7 (128 rows each)
    int j = blockIdx.x * 256 + threadIdx.x;        // 0..1023
    __shared__ float sin_[128];
    if (threadIdx.x < 128) sin_[threadIdx.x] = in[by * 128 + threadIdx.x];
    __syncthreads();
    float acc = 0.f;
#pragma unroll 8
    for (int i = 0; i < 128; ++i)
        acc = fmaf(sin_[i], W[(size_t)(by * 128 + i) * 1024 + j], acc);
    part[(size_t)by * 1024 + j] = acc;
}

__global__ void dense_final(const float* __restrict__ part, const float* __restrict__ bias,
                            float* __restrict__ out, int act) {
    int j = blockIdx.x * 256 + threadIdx.x;
    float acc = bias[j];
#pragma unroll
    for (int s = 0; s < 8; ++s) acc += part[(size_t)s * 1024 + j];
    out[j] = act ? (1.0f / (1.0f + __expf(-acc))) : fmaxf(acc, 0.f);
}

// ---------------- launch ----------------
extern "C" void kernel_launch(void* const* d_in, const int* in_sizes, int n_in,
                              void* d_out, int out_size, void* d_ws, size_t ws_size,
                              hipStream_t stream) {
    const float* x   = (const float*)d_in[0];
    const int*   ei  = (const int*)d_in[1];
    const float* ew  = (const float*)d_in[2];
    const uint32_t* beta = (const uint32_t*)d_in[3];
    const float* W1  = (const float*)d_in[4];
    const float* b1  = (const float*)d_in[5];
    const float* W2  = (const float*)d_in[6];
    const float* b2  = (const float*)d_in[7];
    const float* W3  = (const float*)d_in[8];
    const float* b3  = (const float*)d_in[9];
    const float* Wmu = (const float*)d_in[10];
    const float* bmu = (const float*)d_in[11];
    const float* Wlv = (const float*)d_in[12];
    const float* blv = (const float*)d_in[13];
    const float* Wd1 = (const float*)d_in[14];
    const float* bd1 = (const float*)d_in[15];
    const float* Wd2 = (const float*)d_in[16];
    const float* bd2 = (const float*)d_in[17];

    const int E = in_sizes[2];            // 300000
    const int M = NNODE;

    float* out    = (float*)d_out;
    float* mu_out = out + 1024;                           // [30000,512]
    float* lv_out = out + 1024 + (size_t)M * HDIM;        // [30000,512]

    // ---------------- workspace layout (bytes); no trailing backslashes in comments! ----
    char* Wp = (char*)d_ws;
    short* slotA  = (short*)(Wp);                         // 61,603,840 B (30080x1024 bf16 max)
    short* slotB  = (short*)(Wp + 61603840);              // 61,603,840 B
    short* xb     = (short*)(Wp + 123207680);             // 30,720,000 B
    short* W1t    = (short*)(Wp + 154009600);             // 1024x512
    short* W2t    = (short*)(Wp + 155058176);             // 512x1024
    short* W3t    = (short*)(Wp + 156106752);             // 256x512
    short* Wmut   = (short*)(Wp + 156368896);             // 512x256 (Wlvt MUST follow)
    short* Wlvt   = (short*)(Wp + 156631040);             // 512x256 = Wmut + 262144 B
    float* deg    = (float*)(Wp + 156893184);             // 120,000 B (memset group start)
    float* dinv   = (float*)(Wp + 157013184);             // 120,000 B
    int*   cnt    = (int*)  (Wp + 157133184);             // 120,000 B
    int*   fill   = (int*)  (Wp + 157253184);             // 120,000 B
    float* ssbuf  = (float*)(Wp + 157373184);             // 120,000 B (memset group end)
    int*   rowptr = (int*)  (Wp + 157493184);             // 120,004 B
    int*   ecol   = (int*)  (Wp + 157613188);             // 1,200,000 B
    float* eval   = (float*)(Wp + 158813188);             // 1,200,000 B
    float* pmax   = (float*)(Wp + 160013188);             // 1,921,024 B
    float* psum   = (float*)(Wp + 161934212);             // 1,921,024 B
    float* pmax2  = (float*)(Wp + 163855236);             // 131,072 B
    float* psum2  = (float*)(Wp + 163986308);             // 131,072 B
    float* pooled = (float*)(Wp + 164117380);             // 4,096 B
    float* hdec   = (float*)(Wp + 164121476);             // 4,096 B
    float* dpart  = (float*)(Wp + 164125572);             // 32,768 B

    const int* row = ei;
    const int* col = ei + E;

    // 1) one memset for deg|dinv|cnt|fill|ssbuf (dinv fully overwritten anyway)
    hipMemsetAsync(deg, 0, 600000, stream);

    deg_cnt_kernel<<<(E + 255) / 256, 256, 0, stream>>>(row, ew, deg, cnt, E);
    dinv_kernel<<<(M + 255) / 256, 256, 0, stream>>>(deg, dinv, M);
    build_rowptr<<<1, 256, 0, stream>>>(cnt, rowptr);
    scatter_edges<<<(E + 255) / 256, 256, 0, stream>>>(row, col, ew, dinv, rowptr, fill,
                                                       ecol, eval, E);

    // 2) conversions: x -> bf16, weights -> transposed bf16 [N][K]
    f32_to_bf16<<<(M * FIN / 4 + 255) / 256, 256, 0, stream>>>(x, xb, M * FIN / 4);
    {
        dim3 b(256);
        transpose_bf16<<<dim3(H1DIM / 32, FIN / 32),   b, 0, stream>>>(W1,  W1t,  FIN,   H1DIM);
        transpose_bf16<<<dim3(H2DIM / 32, H1DIM / 32), b, 0, stream>>>(W2,  W2t,  H1DIM, H2DIM);
        transpose_bf16<<<dim3(H3DIM / 32, H2DIM / 32), b, 0, stream>>>(W3,  W3t,  H2DIM, H3DIM);
        transpose_bf16<<<dim3(HDIM / 32,  H3DIM / 32), b, 0, stream>>>(Wmu, Wmut, H3DIM, HDIM);
        transpose_bf16<<<dim3(HDIM / 32,  H3DIM / 32), b, 0, stream>>>(Wlv, Wlvt, H3DIM, HDIM);
    }

    const int SPMM_GRID = (M + 3) / 4;

    // 3) layer 1: AXb = A_hat@xb (slotA); relu_h1 + row-ss = AXb@W1t+b1 (slotB, EPI1)
    spmm_bf16<512, false><<<SPMM_GRID, 256, 0, stream>>>(rowptr, ecol, eval, dinv, xb,
                                                         nullptr, slotA);
    gemm_bf16<short, true, 1><<<(H1DIM / 128) * MPANELS, 256, 0, stream>>>(
        slotA, W1t, b1, nullptr, slotB, nullptr, ssbuf, M, H1DIM, FIN);
    rsqrt_clamp_kernel<<<(M + 255) / 256, 256, 0, stream>>>(ssbuf, M);

    // 4) layer 2: h2 = (relu_h1 @ W2t) * rinv[row] (slotA, EPI2); out2 = fused spmm (slotB)
    gemm_bf16<short, false, 2><<<(H2DIM / 128) * MPANELS, 256, 0, stream>>>(
        slotB, W2t, nullptr, nullptr, slotA, nullptr, ssbuf, M, H2DIM, H1DIM);
    spmm_bf16<512, true><<<SPMM_GRID, 256, 0, stream>>>(rowptr, ecol, eval, dinv, slotA,
                                                        b2, slotB);

    // 5) layer 3: h3 = out2@W3t (slotA); out3 = fused spmm (slotB)
    gemm_bf16<short, false, 0><<<(H3DIM / 128) * MPANELS, 256, 0, stream>>>(
        slotB, W3t, nullptr, nullptr, slotA, nullptr, nullptr, M, H3DIM, H2DIM);
    spmm_bf16<256, true><<<SPMM_GRID, 256, 0, stream>>>(rowptr, ecol, eval, dinv, slotA,
                                                        b3, slotB);

    // 6) mu / logvar in ONE GEMM (Bt = [Wmut;Wlvt] contiguous, N=1024, split epilogue)
    gemm_bf16<float, true, 3><<<((2 * HDIM) / 128) * MPANELS, 256, 0, stream>>>(
        slotB, Wmut, bmu, blv, mu_out, lv_out, nullptr, M, 2 * HDIM, H3DIM);

    // 7) pooling with JAX-exact reparameterization noise (3-stage tree)
    pool_partial<<<PP_BLOCKS, 256, 0, stream>>>(mu_out, lv_out, beta, pmax, psum);
    pool_mid<<<PM_BLOCKS, 256, 0, stream>>>(pmax, psum, pmax2, psum2);
    pool_final<<<2, 256, 0, stream>>>(pmax2, psum2, pooled);

    // 8) decoder (split-K)
    dense_partial<<<dim3(4, 8), 256, 0, stream>>>(pooled, Wd1, dpart);
    dense_final<<<4, 256, 0, stream>>>(dpart, bd1, hdec, 0);
    dense_partial<<<dim3(4, 8), 256, 0, stream>>>(hdec, Wd2, dpart);
    dense_final<<<4, 256, 0, stream>>>(dpart, bd2, out, 1);
}

// Round 8
// 506.525 us; speedup vs baseline: 5.6706x; 1.0518x over previous
//
#include <hip/hip_runtime.h>
#include <cstdint>
#include <cstddef>

// ---------------- problem constants ----------------
#define NNODE      30000
#define FIN        512
#define H1DIM      1024
#define H2DIM      512
#define H3DIM      256
#define HDIM       512          // mu/logvar width
#define HALF_ROWS  15000
#define HALF_ELEMS 7680000u     // 15000*512 (threefry pair offset)
#define PP_ROWS    16
#define PP_BLOCKS  938          // ceil(15000/16)
#define PM_BLOCKS  64           // mid-reduce blocks (15 pp-blocks each)
#define NPANEL     118          // ceil(30000/256) M-panels (BM=256)
#define NSCAN      118          // ceil(30000/256) scan blocks

typedef __attribute__((ext_vector_type(8))) short s16x8;
typedef __attribute__((ext_vector_type(4))) short s16x4;
typedef __attribute__((ext_vector_type(4))) float f32x4;

// bf16 <-> f32 (RNE, matches JAX/torch)
__device__ __forceinline__ short f2bf(float f) {
    uint32_t u = __float_as_uint(f);
    uint32_t r = (u + 0x7FFFu + ((u >> 16) & 1u)) >> 16;
    return (short)r;
}
__device__ __forceinline__ float bf2f(short s) {
    return __uint_as_float(((uint32_t)(uint16_t)s) << 16);
}

// ---------------- threefry2x32 (JAX-exact) ----------------
__device__ __forceinline__ void threefry2x32(uint32_t k0, uint32_t k1,
                                             uint32_t& x0, uint32_t& x1) {
    uint32_t ks0 = k0, ks1 = k1, ks2 = k0 ^ k1 ^ 0x1BD11BDAu;
    const uint32_t R0[4] = {13u, 15u, 26u, 6u};
    const uint32_t R1[4] = {17u, 29u, 16u, 24u};
    x0 += ks0; x1 += ks1;
#pragma unroll
    for (int g = 0; g < 5; ++g) {
        const uint32_t* R = (g & 1) ? R1 : R0;
#pragma unroll
        for (int r = 0; r < 4; ++r) {
            x0 += x1;
            x1 = (x1 << R[r]) | (x1 >> (32u - R[r]));
            x1 ^= x0;
        }
        uint32_t ks_a = (g % 3 == 0) ? ks1 : (g % 3 == 1 ? ks2 : ks0);
        uint32_t ks_b = (g % 3 == 0) ? ks2 : (g % 3 == 1 ? ks0 : ks1);
        x0 += ks_a;
        x1 += ks_b + (uint32_t)(g + 1);
    }
}

__device__ __forceinline__ float jax_normal(uint32_t bits) {
    uint32_t fb = (bits >> 9) | 0x3F800000u;
    float f = __uint_as_float(fb) - 1.0f;
    const float lo = -0.99999994f;
    float u = fmaf(f, 2.0f, lo);
    u = fmaxf(u, lo);
    return 1.41421356237f * erfinvf(u);
}

// ---------------- degree + count ----------------
__global__ void deg_cnt_kernel(const int* __restrict__ row, const float* __restrict__ w,
                               float* __restrict__ deg, int* __restrict__ cnt, int E) {
    int e = blockIdx.x * 256 + threadIdx.x;
    if (e < E) {
        int r = row[e];
        atomicAdd(&deg[r], w[e]);
        atomicAdd(&cnt[r], 1);
    }
}

__global__ void dinv_kernel(const float* __restrict__ deg, float* __restrict__ dinv, int n) {
    int i = blockIdx.x * 256 + threadIdx.x;
    if (i < n) dinv[i] = rsqrtf(deg[i] + 1.0f);
}

// rinv[i] = 1/max(sqrt(ss[i]), 1e-12), in place
__global__ void rsqrt_clamp_kernel(float* __restrict__ ss, int n) {
    int i = blockIdx.x * 256 + threadIdx.x;
    if (i < n) ss[i] = 1.0f / fmaxf(sqrtf(ss[i]), 1e-12f);
}

// ---------------- parallel rowptr build: blocksum -> scan -> write ----------------
__global__ __launch_bounds__(256) void rp_blocksum(const int* __restrict__ cnt,
                                                   int* __restrict__ bsum) {
    __shared__ int sh[256];
    int i = blockIdx.x * 256 + threadIdx.x;
    sh[threadIdx.x] = (i < NNODE) ? cnt[i] : 0;
    __syncthreads();
    for (int o = 128; o; o >>= 1) {
        if (threadIdx.x < o) sh[threadIdx.x] += sh[threadIdx.x + o];
        __syncthreads();
    }
    if (threadIdx.x == 0) bsum[blockIdx.x] = sh[0];
}

__global__ __launch_bounds__(128) void rp_scan(int* __restrict__ bsum, int nb) {
    __shared__ int sh[128];
    int t = threadIdx.x;
    sh[t] = (t < nb) ? bsum[t] : 0;
    __syncthreads();
    for (int o = 1; o < 128; o <<= 1) {
        int v = (t >= o) ? sh[t - o] : 0;
        __syncthreads();
        sh[t] += v;
        __syncthreads();
    }
    if (t < nb) bsum[t] = (t == 0) ? 0 : sh[t - 1];   // exclusive
}

__global__ __launch_bounds__(256) void rp_write(const int* __restrict__ cnt,
                                                const int* __restrict__ bsum,
                                                int* __restrict__ rowptr, int E) {
    __shared__ int sh[256];
    int i = blockIdx.x * 256 + threadIdx.x;
    int v = (i < NNODE) ? cnt[i] : 0;
    sh[threadIdx.x] = v;
    __syncthreads();
    for (int o = 1; o < 256; o <<= 1) {
        int x = (threadIdx.x >= o) ? sh[threadIdx.x - o] : 0;
        __syncthreads();
        sh[threadIdx.x] += x;
        __syncthreads();
    }
    if (i < NNODE) rowptr[i] = bsum[blockIdx.x] + sh[threadIdx.x] - v;  // exclusive
    if (i == NNODE - 1) rowptr[NNODE] = E;
}

// ---------------- scatter edges into CSR with pre-normalized weights ----------------
__global__ void scatter_edges(const int* __restrict__ row, const int* __restrict__ col,
                              const float* __restrict__ w, const float* __restrict__ dinv,
                              const int* __restrict__ rowptr, int* __restrict__ fill,
                              int* __restrict__ ecol, float* __restrict__ eval, int E) {
    int e = blockIdx.x * 256 + threadIdx.x;
    if (e < E) {
        int r = row[e], c = col[e];
        int pos = rowptr[r] + atomicAdd(&fill[r], 1);
        ecol[pos] = c;
        eval[pos] = dinv[r] * w[e] * dinv[c];
    }
}

// ---------------- fp32 -> bf16 elementwise ----------------
__global__ void f32_to_bf16(const float* __restrict__ in, short* __restrict__ out, int n4) {
    int i = blockIdx.x * 256 + threadIdx.x;
    if (i < n4) {
        float4 v = ((const float4*)in)[i];
        s16x4 s = { f2bf(v.x), f2bf(v.y), f2bf(v.z), f2bf(v.w) };
        *(s16x4*)(out + (size_t)i * 4) = s;
    }
}

// ---------------- transpose + convert: Wt[n][k] = bf16(W[k][n]) ----------------
__global__ __launch_bounds__(256) void transpose_bf16(const float* __restrict__ W,
                                                      short* __restrict__ Wt, int K, int N) {
    __shared__ float t[32][33];
    int kb = blockIdx.y * 32, nb = blockIdx.x * 32;
    int tx = threadIdx.x & 31, ty = threadIdx.x >> 5;     // 32 x 8
#pragma unroll
    for (int i = 0; i < 32; i += 8)
        if (kb + ty + i < K && nb + tx < N)
            t[ty + i][tx] = W[(size_t)(kb + ty + i) * N + nb + tx];
    __syncthreads();
#pragma unroll
    for (int i = 0; i < 32; i += 8)
        if (nb + ty + i < N && kb + tx < K)
            Wt[(size_t)(nb + ty + i) * K + kb + tx] = f2bf(t[tx][ty + i]);
}

// ---------------- CSR SpMM on bf16 rows, optional fused bias+L2norm+ReLU ----------------
template <int F, bool FUSE>
__global__ __launch_bounds__(256) void spmm_bf16(const int* __restrict__ rowptr,
                                                 const int* __restrict__ ecol,
                                                 const float* __restrict__ eval,
                                                 const float* __restrict__ dinv,
                                                 const short* __restrict__ h,
                                                 const float* __restrict__ bias,
                                                 short* __restrict__ out) {
    constexpr int NE = F / 64;               // 512->8, 256->4
    int lane = threadIdx.x & 63;
    int r = blockIdx.x * 4 + (threadIdx.x >> 6);
    if (r >= NNODE) return;
    float d = dinv[r];
    float dd = d * d;
    float acc[NE];
    {
        const short* p = h + (size_t)r * F + lane * NE;
        if constexpr (NE == 8) {
            s16x8 v = *(const s16x8*)p;
#pragma unroll
            for (int j = 0; j < 8; ++j) acc[j] = dd * bf2f(v[j]);
        } else {
            s16x4 v = *(const s16x4*)p;
#pragma unroll
            for (int j = 0; j < 4; ++j) acc[j] = dd * bf2f(v[j]);
        }
    }
    int e0 = rowptr[r], e1 = rowptr[r + 1];
    int e = e0;
    for (; e + 2 <= e1; e += 2) {
        int c0 = ecol[e], c1 = ecol[e + 1];
        float w0 = eval[e], w1 = eval[e + 1];
        const short* p0 = h + (size_t)c0 * F + lane * NE;
        const short* p1 = h + (size_t)c1 * F + lane * NE;
        if constexpr (NE == 8) {
            s16x8 v0 = *(const s16x8*)p0;
            s16x8 v1 = *(const s16x8*)p1;
#pragma unroll
            for (int j = 0; j < 8; ++j) acc[j] = fmaf(w0, bf2f(v0[j]), acc[j]);
#pragma unroll
            for (int j = 0; j < 8; ++j) acc[j] = fmaf(w1, bf2f(v1[j]), acc[j]);
        } else {
            s16x4 v0 = *(const s16x4*)p0;
            s16x4 v1 = *(const s16x4*)p1;
#pragma unroll
            for (int j = 0; j < 4; ++j) acc[j] = fmaf(w0, bf2f(v0[j]), acc[j]);
#pragma unroll
            for (int j = 0; j < 4; ++j) acc[j] = fmaf(w1, bf2f(v1[j]), acc[j]);
        }
    }
    if (e < e1) {
        int c = ecol[e];
        float nw = eval[e];
        const short* p = h + (size_t)c * F + lane * NE;
        if constexpr (NE == 8) {
            s16x8 v = *(const s16x8*)p;
#pragma unroll
            for (int j = 0; j < 8; ++j) acc[j] = fmaf(nw, bf2f(v[j]), acc[j]);
        } else {
            s16x4 v = *(const s16x4*)p;
#pragma unroll
            for (int j = 0; j < 4; ++j) acc[j] = fmaf(nw, bf2f(v[j]), acc[j]);
        }
    }
    short* o = out + (size_t)r * F + lane * NE;
    if (FUSE) {
        const float* bp = bias + lane * NE;
        float ss = 0.f;
#pragma unroll
        for (int j = 0; j < NE; ++j) { acc[j] += bp[j]; ss += acc[j] * acc[j]; }
#pragma unroll
        for (int off = 32; off; off >>= 1) ss += __shfl_xor(ss, off);
        float rinv = 1.0f / fmaxf(sqrtf(ss), 1e-12f);
#pragma unroll
        for (int j = 0; j < NE; ++j) acc[j] = fmaxf(acc[j] * rinv, 0.f);
    }
    if constexpr (NE == 8) {
        s16x8 s;
#pragma unroll
        for (int j = 0; j < 8; ++j) s[j] = f2bf(acc[j]);
        *(s16x8*)o = s;
    } else {
        s16x4 s;
#pragma unroll
        for (int j = 0; j < 4; ++j) s[j] = f2bf(acc[j]);
        *(s16x4*)o = s;
    }
}

// ---------------- stage one 64-wide K-tile into LDS (linear dest, T2 pre-swizzled src) ---
#define STAGE_TILE(buf_, kt_)                                                              \
  {                                                                                        \
    const int k0_ = (kt_) << 6;                                                            \
    _Pragma("unroll")                                                                      \
    for (int i_ = 0; i_ < 4; ++i_) {                                                       \
      int c_ = i_ * 8 + w;                                                                 \
      int tr_ = c_ * 8 + srow;                                                             \
      __builtin_amdgcn_global_load_lds(                                                    \
          (const __attribute__((address_space(1))) void*)(A + (size_t)(m0 + tr_) * K + k0_ + scol), \
          (__attribute__((address_space(3))) void*)(&sA[buf_][c_ * 512]), 16, 0, 0);       \
    }                                                                                      \
    _Pragma("unroll")                                                                      \
    for (int i_ = 0; i_ < 2; ++i_) {                                                       \
      int c_ = i_ * 8 + w;                                                                 \
      int tr_ = c_ * 8 + srow;                                                             \
      __builtin_amdgcn_global_load_lds(                                                    \
          (const __attribute__((address_space(1))) void*)(Bt + (size_t)(n0 + tr_) * K + k0_ + scol), \
          (__attribute__((address_space(3))) void*)(&sB[buf_][c_ * 512]), 16, 0, 0);       \
    }                                                                                      \
  }

// ---------------- bf16 MFMA GEMM: C[M][N] = A[Mpanels*256][K] * Bt[N][K]^T --------------
// 256x128 tile, BK=64, 512 threads = 8 waves (4M x 2N), per-wave 64x64 output.
// Double-buffered LDS (96KB); T3-minimum 2-phase: issue next-tile stage BEFORE
// ds_read+MFMA of current tile, ONE barrier per K-step (its vmcnt/lgkmcnt drain
// makes the staged buffer ready and retires this tile's ds_reads).
// m204 bijective XCD-chunked swizzle; pid=wgid/nx keeps an M-panel's N-blocks adjacent.
// EPI modes: 0 plain(+bias) | 1 bias+ReLU+row-SS atomics | 2 row-scale by ssbuf | 3 dual split
template <typename OutT, bool ADD_BIAS, int EPI>
__global__ __launch_bounds__(512) void gemm_bf16(const short* __restrict__ A,
                                                 const short* __restrict__ Bt,
                                                 const float* __restrict__ bias,
                                                 const float* __restrict__ bias2,
                                                 OutT* __restrict__ C,
                                                 float* __restrict__ C2,
                                                 float* __restrict__ ssbuf,
                                                 int M, int N, int K) {
    __shared__ short sA[2][256 * 64];
    __shared__ short sB[2][128 * 64];
    const int tid = threadIdx.x;
    const int lane = tid & 63;
    const int w = tid >> 6;                 // wave 0..7
    const int wm = w >> 1, wn = w & 1;      // 4M x 2N, 64x64 per wave

    // ---- m204 bijective XCD swizzle over nwg blocks ----
    const int nwg = gridDim.x;
    const int orig = blockIdx.x;
    const int q = nwg >> 3, rr = nwg & 7;
    const int xcd = orig & 7;
    const int base = (xcd < rr) ? xcd * (q + 1) : rr * (q + 1) + (xcd - rr) * q;
    const int wgid = base + (orig >> 3);
    const int nx = N >> 7;                  // N-blocks of 128
    const int lg = __builtin_ctz(nx);
    const int pid = wgid >> lg;             // M-panel (256 rows)
    const int cblk = wgid & (nx - 1);
    const int m0 = pid << 8;
    const int n0 = cblk << 7;

    const int srow = lane >> 3;             // 0..7
    const int scol = ((lane & 7) ^ srow) * 8;   // T2 pre-swizzled source col

    f32x4 acc[4][4] = {};

    const int lrow = lane & 15;
    const int jhi = lane >> 4;              // 0..3

    const int nkt = K >> 6;
    int cur = 0;
    STAGE_TILE(0, 0);
    __syncthreads();                        // drains vmcnt(0): buf0 ready

    for (int kt = 0; kt < nkt; ++kt) {
        if (kt + 1 < nkt) STAGE_TILE(cur ^ 1, kt + 1);   // overlap with compute below

        s16x8 bfr[4][2];
#pragma unroll
        for (int fn = 0; fn < 4; ++fn) {
            int lr = wn * 64 + fn * 16 + lrow;
            const short* bptr = &sB[cur][lr * 64];
            int sl0 = jhi ^ (lr & 7);
            bfr[fn][0] = *(const s16x8*)&bptr[sl0 << 3];
            bfr[fn][1] = *(const s16x8*)&bptr[(sl0 ^ 4) << 3];
        }
#pragma unroll
        for (int fm = 0; fm < 4; ++fm) {
            int lr = wm * 64 + fm * 16 + lrow;
            const short* aptr = &sA[cur][lr * 64];
            int sl0 = jhi ^ (lr & 7);
            s16x8 a0 = *(const s16x8*)&aptr[sl0 << 3];
            s16x8 a1 = *(const s16x8*)&aptr[(sl0 ^ 4) << 3];
#pragma unroll
            for (int fn = 0; fn < 4; ++fn) {
                acc[fm][fn] = __builtin_amdgcn_mfma_f32_16x16x32_bf16(a0, bfr[fn][0], acc[fm][fn], 0, 0, 0);
                acc[fm][fn] = __builtin_amdgcn_mfma_f32_16x16x32_bf16(a1, bfr[fn][1], acc[fm][fn], 0, 0, 0);
            }
        }
        __syncthreads();                    // retires ds_reads of cur + drains stage of cur^1
        cur ^= 1;
    }

    const int crow = (lane >> 4) * 4;
    const int ccol = lane & 15;

    if constexpr (EPI == 1) {
        float ssl[4][4] = {};
#pragma unroll
        for (int fm = 0; fm < 4; ++fm) {
#pragma unroll
            for (int fn = 0; fn < 4; ++fn) {
                int n = n0 + wn * 64 + fn * 16 + ccol;
                float b = bias[n];
#pragma unroll
                for (int r = 0; r < 4; ++r) {
                    float o = acc[fm][fn][r] + b;
                    ssl[fm][r] += o * o;
                    int m = m0 + wm * 64 + fm * 16 + crow + r;
                    if (m < M) C[(size_t)m * N + n] = (OutT)f2bf(fmaxf(o, 0.f));
                }
            }
        }
#pragma unroll
        for (int fm = 0; fm < 4; ++fm)
#pragma unroll
            for (int r = 0; r < 4; ++r) {
                float v = ssl[fm][r];
                v += __shfl_xor(v, 1); v += __shfl_xor(v, 2);
                v += __shfl_xor(v, 4); v += __shfl_xor(v, 8);
                int m = m0 + wm * 64 + fm * 16 + crow + r;
                if (ccol == 0 && m < M) atomicAdd(&ssbuf[m], v);
            }
    } else if constexpr (EPI == 2) {
#pragma unroll
        for (int fm = 0; fm < 4; ++fm) {
#pragma unroll
            for (int fn = 0; fn < 4; ++fn) {
                int n = n0 + wn * 64 + fn * 16 + ccol;
#pragma unroll
                for (int r = 0; r < 4; ++r) {
                    int m = m0 + wm * 64 + fm * 16 + crow + r;
                    if (m < M) {
                        float sc = ssbuf[m];
                        C[(size_t)m * N + n] = (OutT)f2bf(acc[fm][fn][r] * sc);
                    }
                }
            }
        }
    } else if constexpr (EPI == 3) {
        const int half = N >> 1;
#pragma unroll
        for (int fm = 0; fm < 4; ++fm) {
#pragma unroll
            for (int fn = 0; fn < 4; ++fn) {
                int n = n0 + wn * 64 + fn * 16 + ccol;
                bool hi = n >= half;
                float b = hi ? bias2[n - half] : bias[n];
                float* Cp = hi ? C2 : (float*)C;
                int nc = hi ? (n - half) : n;
#pragma unroll
                for (int r = 0; r < 4; ++r) {
                    int m = m0 + wm * 64 + fm * 16 + crow + r;
                    if (m < M) Cp[(size_t)m * half + nc] = acc[fm][fn][r] + b;
                }
            }
        }
    } else {
#pragma unroll
        for (int fm = 0; fm < 4; ++fm) {
#pragma unroll
            for (int fn = 0; fn < 4; ++fn) {
                int n = n0 + wn * 64 + fn * 16 + ccol;
                float b = ADD_BIAS ? bias[n] : 0.f;
#pragma unroll
                for (int r = 0; r < 4; ++r) {
                    int m = m0 + wm * 64 + fm * 16 + crow + r;
                    if (m < M) {
                        float o = acc[fm][fn][r] + b;
                        if constexpr (sizeof(OutT) == 2) C[(size_t)m * N + n] = (OutT)f2bf(o);
                        else                             C[(size_t)m * N + n] = o;
                    }
                }
            }
        }
    }
}

// ---------------- pooling stage 1: 938 blocks x 16 row-pairs ----------------
__global__ __launch_bounds__(256) void pool_partial(const float* __restrict__ mu,
                                                    const float* __restrict__ lv,
                                                    const uint32_t* __restrict__ beta_p,
                                                    float* __restrict__ pmax,
                                                    float* __restrict__ psum) {
    uint32_t bb = beta_p[0];
    float beta = (bb & 0x7F800000u) ? __uint_as_float(bb) : (float)(int)bb;
    int b = blockIdx.x;
    int r0 = b * PP_ROWS;
    int r1 = min(r0 + PP_ROWS, HALF_ROWS);
    int c = threadIdx.x * 2;
    float m0 = -INFINITY, m1 = -INFINITY, s0 = 0.f, s1 = 0.f;
    for (int r = r0; r < r1; ++r) {
        size_t ia = (size_t)r * HDIM + c;
        size_t ib = (size_t)(r + HALF_ROWS) * HDIM + c;
        float2 mua = *(const float2*)&mu[ia];
        float2 lva = *(const float2*)&lv[ia];
        float2 mub = *(const float2*)&mu[ib];
        float2 lvb = *(const float2*)&lv[ib];
        uint32_t idx0 = (uint32_t)r * 512u + (uint32_t)c;
        uint32_t xa0 = idx0,     ya0 = idx0 + HALF_ELEMS;
        uint32_t xa1 = idx0 + 1, ya1 = idx0 + 1 + HALF_ELEMS;
        threefry2x32(0u, 42u, xa0, ya0);
        threefry2x32(0u, 42u, xa1, ya1);
        float za0 = mua.x + 0.01f * jax_normal(xa0) * __expf(0.5f * beta * lva.x);
        float zb0 = mub.x + 0.01f * jax_normal(ya0) * __expf(0.5f * beta * lvb.x);
        float za1 = mua.y + 0.01f * jax_normal(xa1) * __expf(0.5f * beta * lva.y);
        float zb1 = mub.y + 0.01f * jax_normal(ya1) * __expf(0.5f * beta * lvb.y);
        m0 = fmaxf(m0, fmaxf(za0, zb0)); s0 += za0 + zb0;
        m1 = fmaxf(m1, fmaxf(za1, zb1)); s1 += za1 + zb1;
    }
    pmax[(size_t)b * HDIM + c]     = m0;
    pmax[(size_t)b * HDIM + c + 1] = m1;
    psum[(size_t)b * HDIM + c]     = s0;
    psum[(size_t)b * HDIM + c + 1] = s1;
}

// ---------------- pooling stage 2: 938 -> 64 partials ----------------
__global__ __launch_bounds__(256) void pool_mid(const float* __restrict__ pmax,
                                                const float* __restrict__ psum,
                                                float* __restrict__ pmax2,
                                                float* __restrict__ psum2) {
    int g = blockIdx.x;
    int b0 = g * 15;
    int b1 = min(b0 + 15, PP_BLOCKS);
#pragma unroll
    for (int pass = 0; pass < 2; ++pass) {
        int c = threadIdx.x + pass * 256;
        float m = -INFINITY, s = 0.f;
        for (int b = b0; b < b1; ++b) {
            m = fmaxf(m, pmax[(size_t)b * HDIM + c]);
            s += psum[(size_t)b * HDIM + c];
        }
        pmax2[(size_t)g * HDIM + c] = m;
        psum2[(size_t)g * HDIM + c] = s;
    }
}

// ---------------- pooling stage 3: 64 -> pooled[1024] ----------------
__global__ void pool_final(const float* __restrict__ pmax2, const float* __restrict__ psum2,
                           float* __restrict__ pooled) {
    int c = blockIdx.x * 256 + threadIdx.x;
    if (c < HDIM) {
        float m = -INFINITY, s = 0.f;
#pragma unroll
        for (int b = 0; b < PM_BLOCKS; ++b) {
            m = fmaxf(m, pmax2[(size_t)b * HDIM + c]);
            s += psum2[(size_t)b * HDIM + c];
        }
        pooled[c] = m;
        pooled[HDIM + c] = s / 30000.0f;
    }
}

// ---------------- decoder: split-K partial + finalize ----------------
__global__ __launch_bounds__(256) void dense_partial(const float* __restrict__ in,
                                                     const float* __restrict__ W,
                                                     float* __restrict__ part) {
    int by = blockIdx.y;                           // k-slice 0..7 (128 rows each)
    int j = blockIdx.x * 256 + threadIdx.x;        // 0..1023
    __shared__ float sin_[128];
    if (threadIdx.x < 128) sin_[threadIdx.x] = in[by * 128 + threadIdx.x];
    __syncthreads();
    float acc = 0.f;
#pragma unroll 8
    for (int i = 0; i < 128; ++i)
        acc = fmaf(sin_[i], W[(size_t)(by * 128 + i) * 1024 + j], acc);
    part[(size_t)by * 1024 + j] = acc;
}

__global__ void dense_final(const float* __restrict__ part, const float* __restrict__ bias,
                            float* __restrict__ out, int act) {
    int j = blockIdx.x * 256 + threadIdx.x;
    float acc = bias[j];
#pragma unroll
    for (int s = 0; s < 8; ++s) acc += part[(size_t)s * 1024 + j];
    out[j] = act ? (1.0f / (1.0f + __expf(-acc))) : fmaxf(acc, 0.f);
}

// ---------------- launch ----------------
extern "C" void kernel_launch(void* const* d_in, const int* in_sizes, int n_in,
                              void* d_out, int out_size, void* d_ws, size_t ws_size,
                              hipStream_t stream) {
    const float* x   = (const float*)d_in[0];
    const int*   ei  = (const int*)d_in[1];
    const float* ew  = (const float*)d_in[2];
    const uint32_t* beta = (const uint32_t*)d_in[3];
    const float* W1  = (const float*)d_in[4];
    const float* b1  = (const float*)d_in[5];
    const float* W2  = (const float*)d_in[6];
    const float* b2  = (const float*)d_in[7];
    const float* W3  = (const float*)d_in[8];
    const float* b3  = (const float*)d_in[9];
    const float* Wmu = (const float*)d_in[10];
    const float* bmu = (const float*)d_in[11];
    const float* Wlv = (const float*)d_in[12];
    const float* blv = (const float*)d_in[13];
    const float* Wd1 = (const float*)d_in[14];
    const float* bd1 = (const float*)d_in[15];
    const float* Wd2 = (const float*)d_in[16];
    const float* bd2 = (const float*)d_in[17];

    const int E = in_sizes[2];            // 300000
    const int M = NNODE;

    float* out    = (float*)d_out;
    float* mu_out = out + 1024;                           // [30000,512]
    float* lv_out = out + 1024 + (size_t)M * HDIM;        // [30000,512]

    // ---------------- workspace layout (bytes); no trailing backslashes in comments ----
    char* Wp = (char*)d_ws;
    short* slotA  = (short*)(Wp);                         // 61,603,840 B
    short* slotB  = (short*)(Wp + 61603840);              // 61,603,840 B
    short* xb     = (short*)(Wp + 123207680);             // 30,720,000 B
    short* W1t    = (short*)(Wp + 154009600);             // 1024x512
    short* W2t    = (short*)(Wp + 155058176);             // 512x1024
    short* W3t    = (short*)(Wp + 156106752);             // 256x512
    short* Wmut   = (short*)(Wp + 156368896);             // 512x256 (Wlvt MUST follow)
    short* Wlvt   = (short*)(Wp + 156631040);             // 512x256 = Wmut + 262144 B
    float* deg    = (float*)(Wp + 156893184);             // 120,000 B (memset group start)
    float* dinv   = (float*)(Wp + 157013184);             // 120,000 B
    int*   cnt    = (int*)  (Wp + 157133184);             // 120,000 B
    int*   fill   = (int*)  (Wp + 157253184);             // 120,000 B
    float* ssbuf  = (float*)(Wp + 157373184);             // 120,000 B (memset group end)
    int*   rowptr = (int*)  (Wp + 157493184);             // 120,004 B
    int*   ecol   = (int*)  (Wp + 157613188);             // 1,200,000 B
    float* eval   = (float*)(Wp + 158813188);             // 1,200,000 B
    float* pmax   = (float*)(Wp + 160013188);             // 1,921,024 B
    float* psum   = (float*)(Wp + 161934212);             // 1,921,024 B
    float* pmax2  = (float*)(Wp + 163855236);             // 131,072 B
    float* psum2  = (float*)(Wp + 163986308);             // 131,072 B
    float* pooled = (float*)(Wp + 164117380);             // 4,096 B
    float* hdec   = (float*)(Wp + 164121476);             // 4,096 B
    float* dpart  = (float*)(Wp + 164125572);             // 32,768 B
    int*   bsum   = (int*)pmax;                           // scan scratch; pmax unused until pooling

    const int* row = ei;
    const int* col = ei + E;

    // 1) one memset for deg|dinv|cnt|fill|ssbuf
    hipMemsetAsync(deg, 0, 600000, stream);

    deg_cnt_kernel<<<(E + 255) / 256, 256, 0, stream>>>(row, ew, deg, cnt, E);
    dinv_kernel<<<(M + 255) / 256, 256, 0, stream>>>(deg, dinv, M);
    rp_blocksum<<<NSCAN, 256, 0, stream>>>(cnt, bsum);
    rp_scan<<<1, 128, 0, stream>>>(bsum, NSCAN);
    rp_write<<<NSCAN, 256, 0, stream>>>(cnt, bsum, rowptr, E);
    scatter_edges<<<(E + 255) / 256, 256, 0, stream>>>(row, col, ew, dinv, rowptr, fill,
                                                       ecol, eval, E);

    // 2) conversions: x -> bf16, weights -> transposed bf16 [N][K]
    f32_to_bf16<<<(M * FIN / 4 + 255) / 256, 256, 0, stream>>>(x, xb, M * FIN / 4);
    {
        dim3 b(256);
        transpose_bf16<<<dim3(H1DIM / 32, FIN / 32),   b, 0, stream>>>(W1,  W1t,  FIN,   H1DIM);
        transpose_bf16<<<dim3(H2DIM / 32, H1DIM / 32), b, 0, stream>>>(W2,  W2t,  H1DIM, H2DIM);
        transpose_bf16<<<dim3(H3DIM / 32, H2DIM / 32), b, 0, stream>>>(W3,  W3t,  H2DIM, H3DIM);
        transpose_bf16<<<dim3(HDIM / 32,  H3DIM / 32), b, 0, stream>>>(Wmu, Wmut, H3DIM, HDIM);
        transpose_bf16<<<dim3(HDIM / 32,  H3DIM / 32), b, 0, stream>>>(Wlv, Wlvt, H3DIM, HDIM);
    }

    const int SPMM_GRID = (M + 3) / 4;

    // 3) layer 1: AXb = A_hat@xb (slotA); relu_h1 + row-ss = AXb@W1t+b1 (slotB, EPI1)
    spmm_bf16<512, false><<<SPMM_GRID, 256, 0, stream>>>(rowptr, ecol, eval, dinv, xb,
                                                         nullptr, slotA);
    gemm_bf16<short, true, 1><<<(H1DIM / 128) * NPANEL, 512, 0, stream>>>(
        slotA, W1t, b1, nullptr, slotB, nullptr, ssbuf, M, H1DIM, FIN);
    rsqrt_clamp_kernel<<<(M + 255) / 256, 256, 0, stream>>>(ssbuf, M);

    // 4) layer 2: h2 = (relu_h1 @ W2t) * rinv[row] (slotA, EPI2); out2 = fused spmm (slotB)
    gemm_bf16<short, false, 2><<<(H2DIM / 128) * NPANEL, 512, 0, stream>>>(
        slotB, W2t, nullptr, nullptr, slotA, nullptr, ssbuf, M, H2DIM, H1DIM);
    spmm_bf16<512, true><<<SPMM_GRID, 256, 0, stream>>>(rowptr, ecol, eval, dinv, slotA,
                                                        b2, slotB);

    // 5) layer 3: h3 = out2@W3t (slotA); out3 = fused spmm (slotB)
    gemm_bf16<short, false, 0><<<(H3DIM / 128) * NPANEL, 512, 0, stream>>>(
        slotB, W3t, nullptr, nullptr, slotA, nullptr, nullptr, M, H3DIM, H2DIM);
    spmm_bf16<256, true><<<SPMM_GRID, 256, 0, stream>>>(rowptr, ecol, eval, dinv, slotA,
                                                        b3, slotB);

    // 6) mu / logvar in ONE GEMM (Bt = [Wmut;Wlvt] contiguous, N=1024, split epilogue)
    gemm_bf16<float, true, 3><<<((2 * HDIM) / 128) * NPANEL, 512, 0, stream>>>(
        slotB, Wmut, bmu, blv, mu_out, lv_out, nullptr, M, 2 * HDIM, H3DIM);

    // 7) pooling with JAX-exact reparameterization noise (3-stage tree)
    pool_partial<<<PP_BLOCKS, 256, 0, stream>>>(mu_out, lv_out, beta, pmax, psum);
    pool_mid<<<PM_BLOCKS, 256, 0, stream>>>(pmax, psum, pmax2, psum2);
    pool_final<<<2, 256, 0, stream>>>(pmax2, psum2, pooled);

    // 8) decoder (split-K)
    dense_partial<<<dim3(4, 8), 256, 0, stream>>>(pooled, Wd1, dpart);
    dense_final<<<4, 256, 0, stream>>>(dpart, bd1, hdec, 0);
    dense_partial<<<dim3(4, 8), 256, 0, stream>>>(hdec, Wd2, dpart);
    dense_final<<<4, 256, 0, stream>>>(dpart, bd2, out, 1);
}

// Round 9
// 491.963 us; speedup vs baseline: 5.8385x; 1.0296x over previous
//
#include <hip/hip_runtime.h>
#include <cstdint>
#include <cstddef>

// ---------------- problem constants ----------------
#define NNODE      30000
#define FIN        512
#define H1DIM      1024
#define H2DIM      512
#define H3DIM      256
#define HDIM       512          // mu/logvar width
#define HALF_ROWS  15000
#define HALF_ELEMS 7680000u     // 15000*512 (threefry pair offset)
#define PP_ROWS    16
#define PP_BLOCKS  938          // ceil(15000/16)
#define PM_BLOCKS  64           // mid-reduce blocks (15 pp-blocks each)
#define NPANEL     118          // ceil(30000/256) M-panels (BM=256)
#define NSCAN      118          // ceil(30000/256) scan blocks

typedef __attribute__((ext_vector_type(8))) short s16x8;
typedef __attribute__((ext_vector_type(4))) short s16x4;
typedef __attribute__((ext_vector_type(4))) float f32x4;

// bf16 <-> f32 (RNE, matches JAX/torch)
__device__ __forceinline__ short f2bf(float f) {
    uint32_t u = __float_as_uint(f);
    uint32_t r = (u + 0x7FFFu + ((u >> 16) & 1u)) >> 16;
    return (short)r;
}
__device__ __forceinline__ float bf2f(short s) {
    return __uint_as_float(((uint32_t)(uint16_t)s) << 16);
}

// ---------------- threefry2x32 (JAX-exact) ----------------
__device__ __forceinline__ void threefry2x32(uint32_t k0, uint32_t k1,
                                             uint32_t& x0, uint32_t& x1) {
    uint32_t ks0 = k0, ks1 = k1, ks2 = k0 ^ k1 ^ 0x1BD11BDAu;
    const uint32_t R0[4] = {13u, 15u, 26u, 6u};
    const uint32_t R1[4] = {17u, 29u, 16u, 24u};
    x0 += ks0; x1 += ks1;
#pragma unroll
    for (int g = 0; g < 5; ++g) {
        const uint32_t* R = (g & 1) ? R1 : R0;
#pragma unroll
        for (int r = 0; r < 4; ++r) {
            x0 += x1;
            x1 = (x1 << R[r]) | (x1 >> (32u - R[r]));
            x1 ^= x0;
        }
        uint32_t ks_a = (g % 3 == 0) ? ks1 : (g % 3 == 1 ? ks2 : ks0);
        uint32_t ks_b = (g % 3 == 0) ? ks2 : (g % 3 == 1 ? ks0 : ks1);
        x0 += ks_a;
        x1 += ks_b + (uint32_t)(g + 1);
    }
}

__device__ __forceinline__ float jax_normal(uint32_t bits) {
    uint32_t fb = (bits >> 9) | 0x3F800000u;
    float f = __uint_as_float(fb) - 1.0f;
    const float lo = -0.99999994f;
    float u = fmaf(f, 2.0f, lo);
    u = fmaxf(u, lo);
    return 1.41421356237f * erfinvf(u);
}

// ---------------- degree + count ----------------
__global__ void deg_cnt_kernel(const int* __restrict__ row, const float* __restrict__ w,
                               float* __restrict__ deg, int* __restrict__ cnt, int E) {
    int e = blockIdx.x * 256 + threadIdx.x;
    if (e < E) {
        int r = row[e];
        atomicAdd(&deg[r], w[e]);
        atomicAdd(&cnt[r], 1);
    }
}

__global__ void dinv_kernel(const float* __restrict__ deg, float* __restrict__ dinv, int n) {
    int i = blockIdx.x * 256 + threadIdx.x;
    if (i < n) dinv[i] = rsqrtf(deg[i] + 1.0f);
}

// rinv[i] = 1/max(sqrt(ss[i]), 1e-12), in place
__global__ void rsqrt_clamp_kernel(float* __restrict__ ss, int n) {
    int i = blockIdx.x * 256 + threadIdx.x;
    if (i < n) ss[i] = 1.0f / fmaxf(sqrtf(ss[i]), 1e-12f);
}

// ---------------- parallel rowptr build: blocksum -> scan -> write ----------------
__global__ __launch_bounds__(256) void rp_blocksum(const int* __restrict__ cnt,
                                                   int* __restrict__ bsum) {
    __shared__ int sh[256];
    int i = blockIdx.x * 256 + threadIdx.x;
    sh[threadIdx.x] = (i < NNODE) ? cnt[i] : 0;
    __syncthreads();
    for (int o = 128; o; o >>= 1) {
        if (threadIdx.x < o) sh[threadIdx.x] += sh[threadIdx.x + o];
        __syncthreads();
    }
    if (threadIdx.x == 0) bsum[blockIdx.x] = sh[0];
}

__global__ __launch_bounds__(128) void rp_scan(int* __restrict__ bsum, int nb) {
    __shared__ int sh[128];
    int t = threadIdx.x;
    sh[t] = (t < nb) ? bsum[t] : 0;
    __syncthreads();
    for (int o = 1; o < 128; o <<= 1) {
        int v = (t >= o) ? sh[t - o] : 0;
        __syncthreads();
        sh[t] += v;
        __syncthreads();
    }
    if (t < nb) bsum[t] = (t == 0) ? 0 : sh[t - 1];   // exclusive
}

__global__ __launch_bounds__(256) void rp_write(const int* __restrict__ cnt,
                                                const int* __restrict__ bsum,
                                                int* __restrict__ rowptr, int E) {
    __shared__ int sh[256];
    int i = blockIdx.x * 256 + threadIdx.x;
    int v = (i < NNODE) ? cnt[i] : 0;
    sh[threadIdx.x] = v;
    __syncthreads();
    for (int o = 1; o < 256; o <<= 1) {
        int x = (threadIdx.x >= o) ? sh[threadIdx.x - o] : 0;
        __syncthreads();
        sh[threadIdx.x] += x;
        __syncthreads();
    }
    if (i < NNODE) rowptr[i] = bsum[blockIdx.x] + sh[threadIdx.x] - v;  // exclusive
    if (i == NNODE - 1) rowptr[NNODE] = E;
}

// ---------------- scatter edges into CSR with pre-normalized weights ----------------
__global__ void scatter_edges(const int* __restrict__ row, const int* __restrict__ col,
                              const float* __restrict__ w, const float* __restrict__ dinv,
                              const int* __restrict__ rowptr, int* __restrict__ fill,
                              int* __restrict__ ecol, float* __restrict__ eval, int E) {
    int e = blockIdx.x * 256 + threadIdx.x;
    if (e < E) {
        int r = row[e], c = col[e];
        int pos = rowptr[r] + atomicAdd(&fill[r], 1);
        ecol[pos] = c;
        eval[pos] = dinv[r] * w[e] * dinv[c];
    }
}

// ---------------- fp32 -> bf16 elementwise ----------------
__global__ void f32_to_bf16(const float* __restrict__ in, short* __restrict__ out, int n4) {
    int i = blockIdx.x * 256 + threadIdx.x;
    if (i < n4) {
        float4 v = ((const float4*)in)[i];
        s16x4 s = { f2bf(v.x), f2bf(v.y), f2bf(v.z), f2bf(v.w) };
        *(s16x4*)(out + (size_t)i * 4) = s;
    }
}

// ---------------- transpose + convert: Wt[n][k] = bf16(W[k][n]) ----------------
__global__ __launch_bounds__(256) void transpose_bf16(const float* __restrict__ W,
                                                      short* __restrict__ Wt, int K, int N) {
    __shared__ float t[32][33];
    int kb = blockIdx.y * 32, nb = blockIdx.x * 32;
    int tx = threadIdx.x & 31, ty = threadIdx.x >> 5;     // 32 x 8
#pragma unroll
    for (int i = 0; i < 32; i += 8)
        if (kb + ty + i < K && nb + tx < N)
            t[ty + i][tx] = W[(size_t)(kb + ty + i) * N + nb + tx];
    __syncthreads();
#pragma unroll
    for (int i = 0; i < 32; i += 8)
        if (nb + ty + i < N && kb + tx < K)
            Wt[(size_t)(nb + ty + i) * K + kb + tx] = f2bf(t[tx][ty + i]);
}

// ---------------- CSR SpMM on bf16 rows, optional fused bias+L2norm+ReLU ----------------
template <int F, bool FUSE>
__global__ __launch_bounds__(256) void spmm_bf16(const int* __restrict__ rowptr,
                                                 const int* __restrict__ ecol,
                                                 const float* __restrict__ eval,
                                                 const float* __restrict__ dinv,
                                                 const short* __restrict__ h,
                                                 const float* __restrict__ bias,
                                                 short* __restrict__ out) {
    constexpr int NE = F / 64;               // 512->8, 256->4
    int lane = threadIdx.x & 63;
    int r = blockIdx.x * 4 + (threadIdx.x >> 6);
    if (r >= NNODE) return;
    float d = dinv[r];
    float dd = d * d;
    float acc[NE];
    {
        const short* p = h + (size_t)r * F + lane * NE;
        if constexpr (NE == 8) {
            s16x8 v = *(const s16x8*)p;
#pragma unroll
            for (int j = 0; j < 8; ++j) acc[j] = dd * bf2f(v[j]);
        } else {
            s16x4 v = *(const s16x4*)p;
#pragma unroll
            for (int j = 0; j < 4; ++j) acc[j] = dd * bf2f(v[j]);
        }
    }
    int e0 = rowptr[r], e1 = rowptr[r + 1];
    int e = e0;
    for (; e + 2 <= e1; e += 2) {
        int c0 = ecol[e], c1 = ecol[e + 1];
        float w0 = eval[e], w1 = eval[e + 1];
        const short* p0 = h + (size_t)c0 * F + lane * NE;
        const short* p1 = h + (size_t)c1 * F + lane * NE;
        if constexpr (NE == 8) {
            s16x8 v0 = *(const s16x8*)p0;
            s16x8 v1 = *(const s16x8*)p1;
#pragma unroll
            for (int j = 0; j < 8; ++j) acc[j] = fmaf(w0, bf2f(v0[j]), acc[j]);
#pragma unroll
            for (int j = 0; j < 8; ++j) acc[j] = fmaf(w1, bf2f(v1[j]), acc[j]);
        } else {
            s16x4 v0 = *(const s16x4*)p0;
            s16x4 v1 = *(const s16x4*)p1;
#pragma unroll
            for (int j = 0; j < 4; ++j) acc[j] = fmaf(w0, bf2f(v0[j]), acc[j]);
#pragma unroll
            for (int j = 0; j < 4; ++j) acc[j] = fmaf(w1, bf2f(v1[j]), acc[j]);
        }
    }
    if (e < e1) {
        int c = ecol[e];
        float nw = eval[e];
        const short* p = h + (size_t)c * F + lane * NE;
        if constexpr (NE == 8) {
            s16x8 v = *(const s16x8*)p;
#pragma unroll
            for (int j = 0; j < 8; ++j) acc[j] = fmaf(nw, bf2f(v[j]), acc[j]);
        } else {
            s16x4 v = *(const s16x4*)p;
#pragma unroll
            for (int j = 0; j < 4; ++j) acc[j] = fmaf(nw, bf2f(v[j]), acc[j]);
        }
    }
    short* o = out + (size_t)r * F + lane * NE;
    if (FUSE) {
        const float* bp = bias + lane * NE;
        float ss = 0.f;
#pragma unroll
        for (int j = 0; j < NE; ++j) { acc[j] += bp[j]; ss += acc[j] * acc[j]; }
#pragma unroll
        for (int off = 32; off; off >>= 1) ss += __shfl_xor(ss, off);
        float rinv = 1.0f / fmaxf(sqrtf(ss), 1e-12f);
#pragma unroll
        for (int j = 0; j < NE; ++j) acc[j] = fmaxf(acc[j] * rinv, 0.f);
    }
    if constexpr (NE == 8) {
        s16x8 s;
#pragma unroll
        for (int j = 0; j < 8; ++j) s[j] = f2bf(acc[j]);
        *(s16x8*)o = s;
    } else {
        s16x4 s;
#pragma unroll
        for (int j = 0; j < 4; ++j) s[j] = f2bf(acc[j]);
        *(s16x4*)o = s;
    }
}

// ---------------- stage one 64-wide K-tile (256 A-rows + 256 B-rows) into LDS ----------
// linear LDS dest (rule #21), T2 pre-swizzled global source column.
#define STAGE_TILE(buf_, kt_)                                                              \
  {                                                                                        \
    const int k0_ = (kt_) << 6;                                                            \
    _Pragma("unroll")                                                                      \
    for (int i_ = 0; i_ < 4; ++i_) {                                                       \
      int c_ = i_ * 8 + w;                                                                 \
      int tr_ = c_ * 8 + srow;                                                             \
      __builtin_amdgcn_global_load_lds(                                                    \
          (const __attribute__((address_space(1))) void*)(A + (size_t)(m0 + tr_) * K + k0_ + scol), \
          (__attribute__((address_space(3))) void*)(&sA[buf_][c_ * 512]), 16, 0, 0);       \
    }                                                                                      \
    _Pragma("unroll")                                                                      \
    for (int i_ = 0; i_ < 4; ++i_) {                                                       \
      int c_ = i_ * 8 + w;                                                                 \
      int tr_ = c_ * 8 + srow;                                                             \
      __builtin_amdgcn_global_load_lds(                                                    \
          (const __attribute__((address_space(1))) void*)(Bt + (size_t)(n0 + tr_) * K + k0_ + scol), \
          (__attribute__((address_space(3))) void*)(&sB[buf_][c_ * 512]), 16, 0, 0);       \
    }                                                                                      \
  }

// ---------------- bf16 MFMA GEMM: C[M][N] = A[118*256][K] * Bt[N][K]^T ------------------
// 256x256 tile (m201 geometry), BK=64, 512 threads = 8 waves as 2M x 4N; per-wave output
// 128x64 -> 24 ds_read_b128 per 64 MFMA per K-step (2.67 MFMA/read vs 2.0 at 64x64/wave).
// Double-buffered LDS 128KB; 2-phase: STAGE(next) -> compute(cur) -> one __syncthreads
// (its vmcnt/lgkm drain readies next buf and retires cur reads). T2 swizzle; m204
// bijective XCD swizzle; setprio(1) around MFMA cluster (T5).
// EPI: 0 plain(+bias) | 1 bias+ReLU+row-SS atomics | 2 row-scale by ssbuf | 3 dual split
template <typename OutT, bool ADD_BIAS, int EPI>
__global__ __launch_bounds__(512) void gemm_bf16(const short* __restrict__ A,
                                                 const short* __restrict__ Bt,
                                                 const float* __restrict__ bias,
                                                 const float* __restrict__ bias2,
                                                 OutT* __restrict__ C,
                                                 float* __restrict__ C2,
                                                 float* __restrict__ ssbuf,
                                                 int M, int N, int K) {
    __shared__ short sA[2][256 * 64];
    __shared__ short sB[2][256 * 64];
    const int tid = threadIdx.x;
    const int lane = tid & 63;
    const int w = tid >> 6;                 // wave 0..7
    const int wm = w >> 2, wn = w & 3;      // 2M x 4N; per-wave 128 rows x 64 cols

    // ---- m204 bijective XCD swizzle over nwg blocks ----
    const int nwg = gridDim.x;
    const int orig = blockIdx.x;
    const int q = nwg >> 3, rr = nwg & 7;
    const int xcd = orig & 7;
    const int base = (xcd < rr) ? xcd * (q + 1) : rr * (q + 1) + (xcd - rr) * q;
    const int wgid = base + (orig >> 3);
    const int nx = N >> 8;                  // N-blocks of 256
    const int lg = __builtin_ctz(nx);
    const int pid = wgid >> lg;             // M-panel (256 rows)
    const int cblk = wgid & (nx - 1);
    const int m0 = pid << 8;
    const int n0 = cblk << 8;

    const int srow = lane >> 3;             // 0..7
    const int scol = ((lane & 7) ^ srow) * 8;   // T2 pre-swizzled source col

    f32x4 acc[8][4] = {};

    const int lrow = lane & 15;
    const int jhi = lane >> 4;              // 0..3

    const int nkt = K >> 6;
    int cur = 0;
    STAGE_TILE(0, 0);
    __syncthreads();                        // drains vmcnt(0): buf0 ready

    for (int kt = 0; kt < nkt; ++kt) {
        if (kt + 1 < nkt) STAGE_TILE(cur ^ 1, kt + 1);   // overlaps compute below

        s16x8 bfr[4][2];
#pragma unroll
        for (int fn = 0; fn < 4; ++fn) {
            int lr = wn * 64 + fn * 16 + lrow;
            const short* bptr = &sB[cur][lr * 64];
            int sl0 = jhi ^ (lr & 7);
            bfr[fn][0] = *(const s16x8*)&bptr[sl0 << 3];
            bfr[fn][1] = *(const s16x8*)&bptr[(sl0 ^ 4) << 3];
        }
        __builtin_amdgcn_s_setprio(1);
#pragma unroll
        for (int fm = 0; fm < 8; ++fm) {
            int lr = wm * 128 + fm * 16 + lrow;
            const short* aptr = &sA[cur][lr * 64];
            int sl0 = jhi ^ (lr & 7);
            s16x8 a0 = *(const s16x8*)&aptr[sl0 << 3];
            s16x8 a1 = *(const s16x8*)&aptr[(sl0 ^ 4) << 3];
#pragma unroll
            for (int fn = 0; fn < 4; ++fn) {
                acc[fm][fn] = __builtin_amdgcn_mfma_f32_16x16x32_bf16(a0, bfr[fn][0], acc[fm][fn], 0, 0, 0);
                acc[fm][fn] = __builtin_amdgcn_mfma_f32_16x16x32_bf16(a1, bfr[fn][1], acc[fm][fn], 0, 0, 0);
            }
        }
        __builtin_amdgcn_s_setprio(0);
        __syncthreads();                    // retires cur reads + drains stage of cur^1
        cur ^= 1;
    }

    const int crow = (lane >> 4) * 4;
    const int ccol = lane & 15;

    if constexpr (EPI == 1) {
        float ssl[8][4] = {};
#pragma unroll
        for (int fm = 0; fm < 8; ++fm) {
#pragma unroll
            for (int fn = 0; fn < 4; ++fn) {
                int n = n0 + wn * 64 + fn * 16 + ccol;
                float b = bias[n];
#pragma unroll
                for (int r = 0; r < 4; ++r) {
                    float o = acc[fm][fn][r] + b;
                    ssl[fm][r] += o * o;
                    int m = m0 + wm * 128 + fm * 16 + crow + r;
                    if (m < M) C[(size_t)m * N + n] = (OutT)f2bf(fmaxf(o, 0.f));
                }
            }
        }
#pragma unroll
        for (int fm = 0; fm < 8; ++fm)
#pragma unroll
            for (int r = 0; r < 4; ++r) {
                float v = ssl[fm][r];
                v += __shfl_xor(v, 1); v += __shfl_xor(v, 2);
                v += __shfl_xor(v, 4); v += __shfl_xor(v, 8);
                int m = m0 + wm * 128 + fm * 16 + crow + r;
                if (ccol == 0 && m < M) atomicAdd(&ssbuf[m], v);
            }
    } else if constexpr (EPI == 2) {
#pragma unroll
        for (int fm = 0; fm < 8; ++fm) {
#pragma unroll
            for (int fn = 0; fn < 4; ++fn) {
                int n = n0 + wn * 64 + fn * 16 + ccol;
#pragma unroll
                for (int r = 0; r < 4; ++r) {
                    int m = m0 + wm * 128 + fm * 16 + crow + r;
                    if (m < M) {
                        float sc = ssbuf[m];
                        C[(size_t)m * N + n] = (OutT)f2bf(acc[fm][fn][r] * sc);
                    }
                }
            }
        }
    } else if constexpr (EPI == 3) {
        const int half = N >> 1;
#pragma unroll
        for (int fm = 0; fm < 8; ++fm) {
#pragma unroll
            for (int fn = 0; fn < 4; ++fn) {
                int n = n0 + wn * 64 + fn * 16 + ccol;
                bool hi = n >= half;
                float b = hi ? bias2[n - half] : bias[n];
                float* Cp = hi ? C2 : (float*)C;
                int nc = hi ? (n - half) : n;
#pragma unroll
                for (int r = 0; r < 4; ++r) {
                    int m = m0 + wm * 128 + fm * 16 + crow + r;
                    if (m < M) Cp[(size_t)m * half + nc] = acc[fm][fn][r] + b;
                }
            }
        }
    } else {
#pragma unroll
        for (int fm = 0; fm < 8; ++fm) {
#pragma unroll
            for (int fn = 0; fn < 4; ++fn) {
                int n = n0 + wn * 64 + fn * 16 + ccol;
                float b = ADD_BIAS ? bias[n] : 0.f;
#pragma unroll
                for (int r = 0; r < 4; ++r) {
                    int m = m0 + wm * 128 + fm * 16 + crow + r;
                    if (m < M) {
                        float o = acc[fm][fn][r] + b;
                        if constexpr (sizeof(OutT) == 2) C[(size_t)m * N + n] = (OutT)f2bf(o);
                        else                             C[(size_t)m * N + n] = o;
                    }
                }
            }
        }
    }
}

// ---------------- pooling stage 1: 938 blocks x 16 row-pairs ----------------
__global__ __launch_bounds__(256) void pool_partial(const float* __restrict__ mu,
                                                    const float* __restrict__ lv,
                                                    const uint32_t* __restrict__ beta_p,
                                                    float* __restrict__ pmax,
                                                    float* __restrict__ psum) {
    uint32_t bb = beta_p[0];
    float beta = (bb & 0x7F800000u) ? __uint_as_float(bb) : (float)(int)bb;
    int b = blockIdx.x;
    int r0 = b * PP_ROWS;
    int r1 = min(r0 + PP_ROWS, HALF_ROWS);
    int c = threadIdx.x * 2;
    float m0 = -INFINITY, m1 = -INFINITY, s0 = 0.f, s1 = 0.f;
    for (int r = r0; r < r1; ++r) {
        size_t ia = (size_t)r * HDIM + c;
        size_t ib = (size_t)(r + HALF_ROWS) * HDIM + c;
        float2 mua = *(const float2*)&mu[ia];
        float2 lva = *(const float2*)&lv[ia];
        float2 mub = *(const float2*)&mu[ib];
        float2 lvb = *(const float2*)&lv[ib];
        uint32_t idx0 = (uint32_t)r * 512u + (uint32_t)c;
        uint32_t xa0 = idx0,     ya0 = idx0 + HALF_ELEMS;
        uint32_t xa1 = idx0 + 1, ya1 = idx0 + 1 + HALF_ELEMS;
        threefry2x32(0u, 42u, xa0, ya0);
        threefry2x32(0u, 42u, xa1, ya1);
        float za0 = mua.x + 0.01f * jax_normal(xa0) * __expf(0.5f * beta * lva.x);
        float zb0 = mub.x + 0.01f * jax_normal(ya0) * __expf(0.5f * beta * lvb.x);
        float za1 = mua.y + 0.01f * jax_normal(xa1) * __expf(0.5f * beta * lva.y);
        float zb1 = mub.y + 0.01f * jax_normal(ya1) * __expf(0.5f * beta * lvb.y);
        m0 = fmaxf(m0, fmaxf(za0, zb0)); s0 += za0 + zb0;
        m1 = fmaxf(m1, fmaxf(za1, zb1)); s1 += za1 + zb1;
    }
    pmax[(size_t)b * HDIM + c]     = m0;
    pmax[(size_t)b * HDIM + c + 1] = m1;
    psum[(size_t)b * HDIM + c]     = s0;
    psum[(size_t)b * HDIM + c + 1] = s1;
}

// ---------------- pooling stage 2: 938 -> 64 partials ----------------
__global__ __launch_bounds__(256) void pool_mid(const float* __restrict__ pmax,
                                                const float* __restrict__ psum,
                                                float* __restrict__ pmax2,
                                                float* __restrict__ psum2) {
    int g = blockIdx.x;
    int b0 = g * 15;
    int b1 = min(b0 + 15, PP_BLOCKS);
#pragma unroll
    for (int pass = 0; pass < 2; ++pass) {
        int c = threadIdx.x + pass * 256;
        float m = -INFINITY, s = 0.f;
        for (int b = b0; b < b1; ++b) {
            m = fmaxf(m, pmax[(size_t)b * HDIM + c]);
            s += psum[(size_t)b * HDIM + c];
        }
        pmax2[(size_t)g * HDIM + c] = m;
        psum2[(size_t)g * HDIM + c] = s;
    }
}

// ---------------- pooling stage 3: 64 -> pooled[1024] ----------------
__global__ void pool_final(const float* __restrict__ pmax2, const float* __restrict__ psum2,
                           float* __restrict__ pooled) {
    int c = blockIdx.x * 256 + threadIdx.x;
    if (c < HDIM) {
        float m = -INFINITY, s = 0.f;
#pragma unroll
        for (int b = 0; b < PM_BLOCKS; ++b) {
            m = fmaxf(m, pmax2[(size_t)b * HDIM + c]);
            s += psum2[(size_t)b * HDIM + c];
        }
        pooled[c] = m;
        pooled[HDIM + c] = s / 30000.0f;
    }
}

// ---------------- decoder: split-K partial + finalize ----------------
__global__ __launch_bounds__(256) void dense_partial(const float* __restrict__ in,
                                                     const float* __restrict__ W,
                                                     float* __restrict__ part) {
    int by = blockIdx.y;                           // k-slice 0..7 (128 rows each)
    int j = blockIdx.x * 256 + threadIdx.x;        // 0..1023
    __shared__ float sin_[128];
    if (threadIdx.x < 128) sin_[threadIdx.x] = in[by * 128 + threadIdx.x];
    __syncthreads();
    float acc = 0.f;
#pragma unroll 8
    for (int i = 0; i < 128; ++i)
        acc = fmaf(sin_[i], W[(size_t)(by * 128 + i) * 1024 + j], acc);
    part[(size_t)by * 1024 + j] = acc;
}

__global__ void dense_final(const float* __restrict__ part, const float* __restrict__ bias,
                            float* __restrict__ out, int act) {
    int j = blockIdx.x * 256 + threadIdx.x;
    float acc = bias[j];
#pragma unroll
    for (int s = 0; s < 8; ++s) acc += part[(size_t)s * 1024 + j];
    out[j] = act ? (1.0f / (1.0f + __expf(-acc))) : fmaxf(acc, 0.f);
}

// ---------------- launch ----------------
extern "C" void kernel_launch(void* const* d_in, const int* in_sizes, int n_in,
                              void* d_out, int out_size, void* d_ws, size_t ws_size,
                              hipStream_t stream) {
    const float* x   = (const float*)d_in[0];
    const int*   ei  = (const int*)d_in[1];
    const float* ew  = (const float*)d_in[2];
    const uint32_t* beta = (const uint32_t*)d_in[3];
    const float* W1  = (const float*)d_in[4];
    const float* b1  = (const float*)d_in[5];
    const float* W2  = (const float*)d_in[6];
    const float* b2  = (const float*)d_in[7];
    const float* W3  = (const float*)d_in[8];
    const float* b3  = (const float*)d_in[9];
    const float* Wmu = (const float*)d_in[10];
    const float* bmu = (const float*)d_in[11];
    const float* Wlv = (const float*)d_in[12];
    const float* blv = (const float*)d_in[13];
    const float* Wd1 = (const float*)d_in[14];
    const float* bd1 = (const float*)d_in[15];
    const float* Wd2 = (const float*)d_in[16];
    const float* bd2 = (const float*)d_in[17];

    const int E = in_sizes[2];            // 300000
    const int M = NNODE;

    float* out    = (float*)d_out;
    float* mu_out = out + 1024;                           // [30000,512]
    float* lv_out = out + 1024 + (size_t)M * HDIM;        // [30000,512]

    // ---------------- workspace layout (bytes); no trailing backslashes in comments ----
    char* Wp = (char*)d_ws;
    short* slotA  = (short*)(Wp);                         // 61,603,840 B
    short* slotB  = (short*)(Wp + 61603840);              // 61,603,840 B
    short* xb     = (short*)(Wp + 123207680);             // 30,720,000 B
    short* W1t    = (short*)(Wp + 154009600);             // 1024x512
    short* W2t    = (short*)(Wp + 155058176);             // 512x1024
    short* W3t    = (short*)(Wp + 156106752);             // 256x512
    short* Wmut   = (short*)(Wp + 156368896);             // 512x256 (Wlvt MUST follow)
    short* Wlvt   = (short*)(Wp + 156631040);             // 512x256 = Wmut + 262144 B
    float* deg    = (float*)(Wp + 156893184);             // 120,000 B (memset group start)
    float* dinv   = (float*)(Wp + 157013184);             // 120,000 B
    int*   cnt    = (int*)  (Wp + 157133184);             // 120,000 B
    int*   fill   = (int*)  (Wp + 157253184);             // 120,000 B
    float* ssbuf  = (float*)(Wp + 157373184);             // 120,000 B (memset group end)
    int*   rowptr = (int*)  (Wp + 157493184);             // 120,004 B
    int*   ecol   = (int*)  (Wp + 157613188);             // 1,200,000 B
    float* eval   = (float*)(Wp + 158813188);             // 1,200,000 B
    float* pmax   = (float*)(Wp + 160013188);             // 1,921,024 B
    float* psum   = (float*)(Wp + 161934212);             // 1,921,024 B
    float* pmax2  = (float*)(Wp + 163855236);             // 131,072 B
    float* psum2  = (float*)(Wp + 163986308);             // 131,072 B
    float* pooled = (float*)(Wp + 164117380);             // 4,096 B
    float* hdec   = (float*)(Wp + 164121476);             // 4,096 B
    float* dpart  = (float*)(Wp + 164125572);             // 32,768 B
    int*   bsum   = (int*)pmax;                           // scan scratch; pmax unused until pooling

    const int* row = ei;
    const int* col = ei + E;

    // 1) one memset for deg|dinv|cnt|fill|ssbuf
    hipMemsetAsync(deg, 0, 600000, stream);

    deg_cnt_kernel<<<(E + 255) / 256, 256, 0, stream>>>(row, ew, deg, cnt, E);
    dinv_kernel<<<(M + 255) / 256, 256, 0, stream>>>(deg, dinv, M);
    rp_blocksum<<<NSCAN, 256, 0, stream>>>(cnt, bsum);
    rp_scan<<<1, 128, 0, stream>>>(bsum, NSCAN);
    rp_write<<<NSCAN, 256, 0, stream>>>(cnt, bsum, rowptr, E);
    scatter_edges<<<(E + 255) / 256, 256, 0, stream>>>(row, col, ew, dinv, rowptr, fill,
                                                       ecol, eval, E);

    // 2) conversions: x -> bf16, weights -> transposed bf16 [N][K]
    f32_to_bf16<<<(M * FIN / 4 + 255) / 256, 256, 0, stream>>>(x, xb, M * FIN / 4);
    {
        dim3 b(256);
        transpose_bf16<<<dim3(H1DIM / 32, FIN / 32),   b, 0, stream>>>(W1,  W1t,  FIN,   H1DIM);
        transpose_bf16<<<dim3(H2DIM / 32, H1DIM / 32), b, 0, stream>>>(W2,  W2t,  H1DIM, H2DIM);
        transpose_bf16<<<dim3(H3DIM / 32, H2DIM / 32), b, 0, stream>>>(W3,  W3t,  H2DIM, H3DIM);
        transpose_bf16<<<dim3(HDIM / 32,  H3DIM / 32), b, 0, stream>>>(Wmu, Wmut, H3DIM, HDIM);
        transpose_bf16<<<dim3(HDIM / 32,  H3DIM / 32), b, 0, stream>>>(Wlv, Wlvt, H3DIM, HDIM);
    }

    const int SPMM_GRID = (M + 3) / 4;

    // 3) layer 1: AXb = A_hat@xb (slotA); relu_h1 + row-ss = AXb@W1t+b1 (slotB, EPI1)
    spmm_bf16<512, false><<<SPMM_GRID, 256, 0, stream>>>(rowptr, ecol, eval, dinv, xb,
                                                         nullptr, slotA);
    gemm_bf16<short, true, 1><<<(H1DIM / 256) * NPANEL, 512, 0, stream>>>(
        slotA, W1t, b1, nullptr, slotB, nullptr, ssbuf, M, H1DIM, FIN);
    rsqrt_clamp_kernel<<<(M + 255) / 256, 256, 0, stream>>>(ssbuf, M);

    // 4) layer 2: h2 = (relu_h1 @ W2t) * rinv[row] (slotA, EPI2); out2 = fused spmm (slotB)
    gemm_bf16<short, false, 2><<<(H2DIM / 256) * NPANEL, 512, 0, stream>>>(
        slotB, W2t, nullptr, nullptr, slotA, nullptr, ssbuf, M, H2DIM, H1DIM);
    spmm_bf16<512, true><<<SPMM_GRID, 256, 0, stream>>>(rowptr, ecol, eval, dinv, slotA,
                                                        b2, slotB);

    // 5) layer 3: h3 = out2@W3t (slotA); out3 = fused spmm (slotB)
    gemm_bf16<short, false, 0><<<(H3DIM / 256) * NPANEL, 512, 0, stream>>>(
        slotB, W3t, nullptr, nullptr, slotA, nullptr, nullptr, M, H3DIM, H2DIM);
    spmm_bf16<256, true><<<SPMM_GRID, 256, 0, stream>>>(rowptr, ecol, eval, dinv, slotA,
                                                        b3, slotB);

    // 6) mu / logvar in ONE GEMM (Bt = [Wmut;Wlvt] contiguous, N=1024, split epilogue)
    gemm_bf16<float, true, 3><<<((2 * HDIM) / 256) * NPANEL, 512, 0, stream>>>(
        slotB, Wmut, bmu, blv, mu_out, lv_out, nullptr, M, 2 * HDIM, H3DIM);

    // 7) pooling with JAX-exact reparameterization noise (3-stage tree)
    pool_partial<<<PP_BLOCKS, 256, 0, stream>>>(mu_out, lv_out, beta, pmax, psum);
    pool_mid<<<PM_BLOCKS, 256, 0, stream>>>(pmax, psum, pmax2, psum2);
    pool_final<<<2, 256, 0, stream>>>(pmax2, psum2, pooled);

    // 8) decoder (split-K)
    dense_partial<<<dim3(4, 8), 256, 0, stream>>>(pooled, Wd1, dpart);
    dense_final<<<4, 256, 0, stream>>>(dpart, bd1, hdec, 0);
    dense_partial<<<dim3(4, 8), 256, 0, stream>>>(hdec, Wd2, dpart);
    dense_final<<<4, 256, 0, stream>>>(dpart, bd2, out, 1);
}